// Round 2
// baseline (1951.568 us; speedup 1.0000x reference)
//
#include <hip/hip_runtime.h>
#include <hip/hip_bf16.h>

#define N_USERS    50000
#define N_ENTITIES 150000
#define N_NODES_C  200000
#define BATCH_C    4096

// Workspace layout (total 76.8 MB — keep small: overrunning ws_size corrupts
// the harness's pristine input copies => first call right, replays wrong):
//   hn : f32  [200000*64]  51.2 MB   (aggregation target, reused both layers)
//   h1 : bf16 [200000*64]  25.6 MB   (layer-1 output, bf16 to halve footprint)
// h2 is never materialized: only ~12K rows are needed, computed inline in score.

__device__ __forceinline__ float feat0_at(const float* __restrict__ uw,
                                          const float* __restrict__ ew,
                                          int node, int k) {
    return (node < N_USERS) ? uw[node * 64 + k] : ew[(node - N_USERS) * 64 + k];
}

// one wave per edge; lane = feature dim; coalesced 256B gather, f32 atomic scatter
__global__ __launch_bounds__(256) void aggregate_embed_k(
    const float* __restrict__ uw, const float* __restrict__ ew,
    const int* __restrict__ target, const int* __restrict__ neighbor,
    const float* __restrict__ values, float* __restrict__ hn, int n_edges)
{
    int gid  = blockIdx.x * 256 + threadIdx.x;
    int e    = gid >> 6;
    int lane = threadIdx.x & 63;
    if (e >= n_edges) return;
    int   t  = target[e];
    int   nb = neighbor[e];
    float v  = values[e];
    float f  = feat0_at(uw, ew, nb, lane);
    atomicAdd(&hn[(size_t)t * 64 + lane], v * f);
}

// second aggregation: gathers bf16 h1 rows (128B/row)
__global__ __launch_bounds__(256) void aggregate_h1_k(
    const __hip_bfloat16* __restrict__ h1,
    const int* __restrict__ target, const int* __restrict__ neighbor,
    const float* __restrict__ values, float* __restrict__ hn, int n_edges)
{
    int gid  = blockIdx.x * 256 + threadIdx.x;
    int e    = gid >> 6;
    int lane = threadIdx.x & 63;
    if (e >= n_edges) return;
    int   t  = target[e];
    int   nb = neighbor[e];
    float v  = values[e];
    float f  = __bfloat162float(h1[(size_t)nb * 64 + lane]);
    atomicAdd(&hn[(size_t)t * 64 + lane], v * f);
}

// layer1: h1 = l2norm(leaky((f+hn)@W1a + b1a + (f*hn)@W2a + b2a)); 64->64, bf16 out
__global__ __launch_bounds__(256) void layer1_k(
    const float* __restrict__ uw, const float* __restrict__ ew,
    const float* __restrict__ hn,
    const float* __restrict__ W1, const float* __restrict__ b1,
    const float* __restrict__ W2, const float* __restrict__ b2,
    __hip_bfloat16* __restrict__ h1out, int n_nodes)
{
    __shared__ float sW1[64 * 64];
    __shared__ float sW2[64 * 64];
    __shared__ float sb[64];
    for (int i = threadIdx.x; i < 64 * 64; i += 256) { sW1[i] = W1[i]; sW2[i] = W2[i]; }
    if (threadIdx.x < 64) sb[threadIdx.x] = b1[threadIdx.x] + b2[threadIdx.x];
    __syncthreads();

    int wave = threadIdx.x >> 6;
    int lane = threadIdx.x & 63;
    int node = blockIdx.x * 4 + wave;
    if (node >= n_nodes) return;

    float f   = feat0_at(uw, ew, node, lane);
    float hnv = hn[(size_t)node * 64 + lane];
    float s   = f + hnv;
    float p   = f * hnv;

    float acc = sb[lane];
    #pragma unroll
    for (int k = 0; k < 64; k++) {
        float sk = __shfl(s, k);
        float pk = __shfl(p, k);
        acc += sk * sW1[k * 64 + lane] + pk * sW2[k * 64 + lane];
    }
    acc = (acc > 0.f) ? acc : 0.01f * acc;

    float sq = acc * acc;
    #pragma unroll
    for (int m = 1; m < 64; m <<= 1) sq += __shfl_xor(sq, m);
    float nrm = fmaxf(sqrtf(sq), 1e-12f);
    h1out[(size_t)node * 64 + lane] = __float2bfloat16(acc / nrm);
}

// inline layer2 (64->32) for one node row; every lane returns h2[node][lane&31]
__device__ __forceinline__ float layer2_row(
    const __hip_bfloat16* __restrict__ h1, const float* __restrict__ hn,
    const float* sW1, const float* sW2, const float* sb,
    int node, int lane)
{
    float f = __bfloat162float(h1[(size_t)node * 64 + lane]);
    float g = hn[(size_t)node * 64 + lane];
    float s = f + g;
    float p = f * g;
    int j = lane & 31;
    float acc = sb[j];
    #pragma unroll
    for (int k = 0; k < 64; k++) {
        float sk = __shfl(s, k);
        float pk = __shfl(p, k);
        acc += sk * sW1[k * 32 + j] + pk * sW2[k * 32 + j];
    }
    acc = (acc > 0.f) ? acc : 0.01f * acc;
    float sq = acc * acc;
    #pragma unroll
    for (int m = 1; m < 32; m <<= 1) sq += __shfl_xor(sq, m);  // within 32-half
    return acc / fmaxf(sqrtf(sq), 1e-12f);
}

// one wave per batch element: seg0 = raw embed dot, seg1 = h1 dot,
// seg2 = inline-layer2 h2 dot (computed on the fly, never materialized)
__global__ __launch_bounds__(256) void score_k(
    const float* __restrict__ uw, const float* __restrict__ ew,
    const __hip_bfloat16* __restrict__ h1, const float* __restrict__ hn,
    const float* __restrict__ W1b, const float* __restrict__ b1b,
    const float* __restrict__ W2b, const float* __restrict__ b2b,
    const int* __restrict__ uid, const int* __restrict__ pid,
    const int* __restrict__ nid, float* __restrict__ out)
{
    __shared__ float sW1[64 * 32];
    __shared__ float sW2[64 * 32];
    __shared__ float sb[32];
    for (int i = threadIdx.x; i < 64 * 32; i += 256) { sW1[i] = W1b[i]; sW2[i] = W2b[i]; }
    if (threadIdx.x < 32) sb[threadIdx.x] = b1b[threadIdx.x] + b2b[threadIdx.x];
    __syncthreads();

    int wave = threadIdx.x >> 6;
    int lane = threadIdx.x & 63;
    int i = blockIdx.x * 4 + wave;
    if (i >= BATCH_C) return;

    int un = uid[i];
    int pe = pid[i];
    int ne = nid[i];
    int pn = N_USERS + pe;
    int nn = N_USERS + ne;

    // segments 0+1: one dim per lane across all 64 lanes
    float acc01p, acc01n;
    {
        float u  = uw[(size_t)un * 64 + lane];
        float pv = ew[(size_t)pe * 64 + lane];
        float nv = ew[(size_t)ne * 64 + lane];
        acc01p = u * pv;
        acc01n = u * nv;
        float u1 = __bfloat162float(h1[(size_t)un * 64 + lane]);
        acc01p += u1 * __bfloat162float(h1[(size_t)pn * 64 + lane]);
        acc01n += u1 * __bfloat162float(h1[(size_t)nn * 64 + lane]);
    }

    // segment 2: compute h2 rows inline (each lane holds dim lane&31, duplicated per half)
    float h2u = layer2_row(h1, hn, sW1, sW2, sb, un, lane);
    float h2p = layer2_row(h1, hn, sW1, sW2, sb, pn, lane);
    float h2n = layer2_row(h1, hn, sW1, sW2, sb, nn, lane);
    float p2 = h2u * h2p;
    float n2 = h2u * h2n;
    #pragma unroll
    for (int m = 1; m < 32; m <<= 1) { p2 += __shfl_xor(p2, m); n2 += __shfl_xor(n2, m); }

    #pragma unroll
    for (int m = 1; m < 64; m <<= 1) { acc01p += __shfl_xor(acc01p, m); acc01n += __shfl_xor(acc01n, m); }

    if (lane == 0) {
        out[i]           = acc01p + p2;
        out[BATCH_C + i] = acc01n + n2;
    }
}

extern "C" void kernel_launch(void* const* d_in, const int* in_sizes, int n_in,
                              void* d_out, int out_size, void* d_ws, size_t ws_size,
                              hipStream_t stream) {
    const float* uw   = (const float*)d_in[0];
    const float* ew   = (const float*)d_in[1];
    const float* W1a  = (const float*)d_in[2];
    const float* b1a  = (const float*)d_in[3];
    const float* W2a  = (const float*)d_in[4];
    const float* b2a  = (const float*)d_in[5];
    const float* W1b  = (const float*)d_in[6];
    const float* b1b  = (const float*)d_in[7];
    const float* W2b  = (const float*)d_in[8];
    const float* b2b  = (const float*)d_in[9];
    const float* values   = (const float*)d_in[10];
    const int*   target   = (const int*)d_in[11];
    const int*   neighbor = (const int*)d_in[12];
    const int*   uid  = (const int*)d_in[13];
    const int*   pid  = (const int*)d_in[14];
    const int*   nid  = (const int*)d_in[15];

    const int n_edges = in_sizes[10];

    const size_t hn_bytes = (size_t)N_NODES_C * 64 * sizeof(float);   // 51.2 MB
    float* hn = (float*)d_ws;
    __hip_bfloat16* h1 = (__hip_bfloat16*)((char*)d_ws + hn_bytes);   // +25.6 MB

    const int agg_blocks   = (int)(((long long)n_edges * 64 + 255) / 256);
    const int layer_blocks = (N_NODES_C + 3) / 4;

    // ----- layer 1 -----
    hipMemsetAsync(hn, 0, hn_bytes, stream);
    aggregate_embed_k<<<agg_blocks, 256, 0, stream>>>(uw, ew, target, neighbor, values, hn, n_edges);
    layer1_k<<<layer_blocks, 256, 0, stream>>>(uw, ew, hn, W1a, b1a, W2a, b2a, h1, N_NODES_C);

    // ----- layer 2 aggregation (dense transform fused into score) -----
    hipMemsetAsync(hn, 0, hn_bytes, stream);
    aggregate_h1_k<<<agg_blocks, 256, 0, stream>>>(h1, target, neighbor, values, hn, n_edges);

    // ----- scoring (includes inline layer-2 transform for the ~12K needed rows) -----
    score_k<<<BATCH_C / 4, 256, 0, stream>>>(uw, ew, h1, hn, W1b, b1b, W2b, b2b,
                                             uid, pid, nid, (float*)d_out);
}

// Round 3
// 1629.613 us; speedup vs baseline: 1.1976x; 1.1976x over previous
//
#include <hip/hip_runtime.h>
#include <hip/hip_bf16.h>

#define N_USERS    50000
#define N_ENTITIES 150000
#define N_NODES_C  200000
#define BATCH_C    4096
#define N_EDGES_C  3200000

// Workspace layout (~54 MB; keep well under ws_size — overrun corrupts the
// harness's pristine copies => first call right, replays wrong):
//   counts   : int  [200000]      0.8 MB
//   row_ptr  : int  [200001]      0.8 MB (padded)
//   cursor   : int  [200000]      0.8 MB
//   edges    : int2 [3.2M]       25.6 MB  (nb, val-bits) sorted by target
//   h1       : bf16 [200000*64]  25.6 MB

__device__ __forceinline__ float feat0_at(const float* __restrict__ uw,
                                          const float* __restrict__ ew,
                                          int node, int k) {
    return (node < N_USERS) ? uw[node * 64 + k] : ew[(node - N_USERS) * 64 + k];
}

// ---------- CSR build ----------
__global__ __launch_bounds__(256) void hist_k(const int* __restrict__ target,
                                              int* __restrict__ counts, int n_edges)
{
    int e = blockIdx.x * 256 + threadIdx.x;
    if (e < n_edges) atomicAdd(&counts[target[e]], 1);
}

// single-workgroup scan of 200K counts -> exclusive prefix in row_ptr & cursor
__global__ __launch_bounds__(1024) void scan_k(const int* __restrict__ counts,
                                               int* __restrict__ row_ptr,
                                               int* __restrict__ cursor)
{
    __shared__ int part[1024];
    int t = threadIdx.x;
    const int CH = (N_NODES_C + 1023) / 1024;           // 196
    int s = t * CH;
    int e = min(s + CH, N_NODES_C);
    int sum = 0;
    for (int i = s; i < e; i++) sum += counts[i];
    part[t] = sum;
    __syncthreads();
    for (int off = 1; off < 1024; off <<= 1) {
        int v = (t >= off) ? part[t - off] : 0;
        __syncthreads();
        part[t] += v;
        __syncthreads();
    }
    int run = (t == 0) ? 0 : part[t - 1];
    for (int i = s; i < e; i++) {
        row_ptr[i] = run;
        cursor[i]  = run;
        run += counts[i];
    }
    if (t == 1023) row_ptr[N_NODES_C] = part[1023];
}

__global__ __launch_bounds__(256) void scatter_k(
    const int* __restrict__ target, const int* __restrict__ neighbor,
    const float* __restrict__ values, int* __restrict__ cursor,
    int2* __restrict__ edges, int n_edges)
{
    int e = blockIdx.x * 256 + threadIdx.x;
    if (e >= n_edges) return;
    int t   = target[e];
    int pos = atomicAdd(&cursor[t], 1);
    int2 ev;
    ev.x = neighbor[e];
    ev.y = __float_as_int(values[e]);
    edges[pos] = ev;
}

// ---------- layer 1: CSR pull + dense transform fused ----------
// one wave per node; lane = feature dim. hn stays in a register.
__global__ __launch_bounds__(256) void layer1_pull_k(
    const float* __restrict__ uw, const float* __restrict__ ew,
    const int* __restrict__ row_ptr, const int2* __restrict__ edges,
    const float* __restrict__ W1, const float* __restrict__ b1,
    const float* __restrict__ W2, const float* __restrict__ b2,
    __hip_bfloat16* __restrict__ h1out, int n_nodes)
{
    __shared__ float sW1[64 * 64];
    __shared__ float sW2[64 * 64];
    __shared__ float sb[64];
    for (int i = threadIdx.x; i < 64 * 64; i += 256) { sW1[i] = W1[i]; sW2[i] = W2[i]; }
    if (threadIdx.x < 64) sb[threadIdx.x] = b1[threadIdx.x] + b2[threadIdx.x];
    __syncthreads();

    int wave = threadIdx.x >> 6;
    int lane = threadIdx.x & 63;
    int node = blockIdx.x * 4 + wave;
    if (node >= n_nodes) return;

    int es = row_ptr[node];
    int ee = row_ptr[node + 1];

    float hn = 0.f;
    for (int base = es; base < ee; base += 64) {
        int cnt = min(64, ee - base);
        int2 ev = (base + lane < ee) ? edges[base + lane] : make_int2(0, 0);
        for (int j = 0; j < cnt; j++) {
            int   nb = __shfl(ev.x, j);
            float v  = __shfl(__int_as_float(ev.y), j);
            hn += v * feat0_at(uw, ew, nb, lane);
        }
    }

    float f = feat0_at(uw, ew, node, lane);
    float s = f + hn;
    float p = f * hn;

    float acc = sb[lane];
    #pragma unroll
    for (int k = 0; k < 64; k++) {
        float sk = __shfl(s, k);
        float pk = __shfl(p, k);
        acc += sk * sW1[k * 64 + lane] + pk * sW2[k * 64 + lane];
    }
    acc = (acc > 0.f) ? acc : 0.01f * acc;

    float sq = acc * acc;
    #pragma unroll
    for (int m = 1; m < 64; m <<= 1) sq += __shfl_xor(sq, m);
    float nrm = fmaxf(sqrtf(sq), 1e-12f);
    h1out[(size_t)node * 64 + lane] = __float2bfloat16(acc / nrm);
}

// ---------- inline layer2 (64->32) for one node, aggregation pulled on the fly ----------
__device__ __forceinline__ float layer2_row(
    const __hip_bfloat16* __restrict__ h1,
    const int* __restrict__ row_ptr, const int2* __restrict__ edges,
    const float* sW1, const float* sW2, const float* sb,
    int node, int lane)
{
    // hn2[node][lane] = sum over incoming edges of v * h1[nb][lane]
    int es = row_ptr[node];
    int ee = row_ptr[node + 1];
    float g = 0.f;
    for (int base = es; base < ee; base += 64) {
        int cnt = min(64, ee - base);
        int2 ev = (base + lane < ee) ? edges[base + lane] : make_int2(0, 0);
        for (int j = 0; j < cnt; j++) {
            int   nb = __shfl(ev.x, j);
            float v  = __shfl(__int_as_float(ev.y), j);
            g += v * __bfloat162float(h1[(size_t)nb * 64 + lane]);
        }
    }
    float f = __bfloat162float(h1[(size_t)node * 64 + lane]);
    float s = f + g;
    float p = f * g;
    int j = lane & 31;
    float acc = sb[j];
    #pragma unroll
    for (int k = 0; k < 64; k++) {
        float sk = __shfl(s, k);
        float pk = __shfl(p, k);
        acc += sk * sW1[k * 32 + j] + pk * sW2[k * 32 + j];
    }
    acc = (acc > 0.f) ? acc : 0.01f * acc;
    float sq = acc * acc;
    #pragma unroll
    for (int m = 1; m < 32; m <<= 1) sq += __shfl_xor(sq, m);  // stays within each 32-half
    return acc / fmaxf(sqrtf(sq), 1e-12f);
}

// one wave per batch element
__global__ __launch_bounds__(256) void score_k(
    const float* __restrict__ uw, const float* __restrict__ ew,
    const __hip_bfloat16* __restrict__ h1,
    const int* __restrict__ row_ptr, const int2* __restrict__ edges,
    const float* __restrict__ W1b, const float* __restrict__ b1b,
    const float* __restrict__ W2b, const float* __restrict__ b2b,
    const int* __restrict__ uid, const int* __restrict__ pid,
    const int* __restrict__ nid, float* __restrict__ out)
{
    __shared__ float sW1[64 * 32];
    __shared__ float sW2[64 * 32];
    __shared__ float sb[32];
    for (int i = threadIdx.x; i < 64 * 32; i += 256) { sW1[i] = W1b[i]; sW2[i] = W2b[i]; }
    if (threadIdx.x < 32) sb[threadIdx.x] = b1b[threadIdx.x] + b2b[threadIdx.x];
    __syncthreads();

    int wave = threadIdx.x >> 6;
    int lane = threadIdx.x & 63;
    int i = blockIdx.x * 4 + wave;
    if (i >= BATCH_C) return;

    int un = uid[i];
    int pe = pid[i];
    int ne = nid[i];
    int pn = N_USERS + pe;
    int nn = N_USERS + ne;

    // segments 0+1
    float acc01p, acc01n;
    {
        float u  = uw[(size_t)un * 64 + lane];
        float pv = ew[(size_t)pe * 64 + lane];
        float nv = ew[(size_t)ne * 64 + lane];
        acc01p = u * pv;
        acc01n = u * nv;
        float u1 = __bfloat162float(h1[(size_t)un * 64 + lane]);
        acc01p += u1 * __bfloat162float(h1[(size_t)pn * 64 + lane]);
        acc01n += u1 * __bfloat162float(h1[(size_t)nn * 64 + lane]);
    }

    // segment 2: h2 rows computed fully on the fly (CSR pull + transform)
    float h2u = layer2_row(h1, row_ptr, edges, sW1, sW2, sb, un, lane);
    float h2p = layer2_row(h1, row_ptr, edges, sW1, sW2, sb, pn, lane);
    float h2n = layer2_row(h1, row_ptr, edges, sW1, sW2, sb, nn, lane);
    float p2 = h2u * h2p;
    float n2 = h2u * h2n;
    #pragma unroll
    for (int m = 1; m < 32; m <<= 1) { p2 += __shfl_xor(p2, m); n2 += __shfl_xor(n2, m); }

    #pragma unroll
    for (int m = 1; m < 64; m <<= 1) { acc01p += __shfl_xor(acc01p, m); acc01n += __shfl_xor(acc01n, m); }

    if (lane == 0) {
        out[i]           = acc01p + p2;
        out[BATCH_C + i] = acc01n + n2;
    }
}

extern "C" void kernel_launch(void* const* d_in, const int* in_sizes, int n_in,
                              void* d_out, int out_size, void* d_ws, size_t ws_size,
                              hipStream_t stream) {
    const float* uw   = (const float*)d_in[0];
    const float* ew   = (const float*)d_in[1];
    const float* W1a  = (const float*)d_in[2];
    const float* b1a  = (const float*)d_in[3];
    const float* W2a  = (const float*)d_in[4];
    const float* b2a  = (const float*)d_in[5];
    const float* W1b  = (const float*)d_in[6];
    const float* b1b  = (const float*)d_in[7];
    const float* W2b  = (const float*)d_in[8];
    const float* b2b  = (const float*)d_in[9];
    const float* values   = (const float*)d_in[10];
    const int*   target   = (const int*)d_in[11];
    const int*   neighbor = (const int*)d_in[12];
    const int*   uid  = (const int*)d_in[13];
    const int*   pid  = (const int*)d_in[14];
    const int*   nid  = (const int*)d_in[15];

    const int n_edges = in_sizes[10];

    char* ws = (char*)d_ws;
    int*  counts  = (int*)ws;                                   ws += 800256;
    int*  row_ptr = (int*)ws;                                   ws += 800256;
    int*  cursor  = (int*)ws;                                   ws += 800256;
    int2* edges   = (int2*)ws;                                  ws += (size_t)N_EDGES_C * 8;
    __hip_bfloat16* h1 = (__hip_bfloat16*)ws;                   // 25.6 MB

    const int edge_blocks  = (n_edges + 255) / 256;
    const int layer_blocks = (N_NODES_C + 3) / 4;

    // ----- CSR build (shared by both layers) -----
    hipMemsetAsync(counts, 0, (size_t)N_NODES_C * sizeof(int), stream);
    hist_k<<<edge_blocks, 256, 0, stream>>>(target, counts, n_edges);
    scan_k<<<1, 1024, 0, stream>>>(counts, row_ptr, cursor);
    scatter_k<<<edge_blocks, 256, 0, stream>>>(target, neighbor, values, cursor, edges, n_edges);

    // ----- layer 1 (pull + transform fused) -----
    layer1_pull_k<<<layer_blocks, 256, 0, stream>>>(uw, ew, row_ptr, edges,
                                                    W1a, b1a, W2a, b2a, h1, N_NODES_C);

    // ----- scoring (layer-2 aggregation + transform inline, only ~12K nodes) -----
    score_k<<<BATCH_C / 4, 256, 0, stream>>>(uw, ew, h1, row_ptr, edges,
                                             W1b, b1b, W2b, b2b,
                                             uid, pid, nid, (float*)d_out);
}

// Round 4
// 1409.940 us; speedup vs baseline: 1.3841x; 1.1558x over previous
//
#include <hip/hip_runtime.h>
#include <hip/hip_bf16.h>

#define N_USERS    50000
#define N_ENTITIES 150000
#define N_NODES_C  200000
#define BATCH_C    4096
#define N_EDGES_C  3200000

// Workspace layout (~53.6 MB; ws overrun corrupts harness pristine copies):
//   counts   : int  [200000]      0.8 MB
//   row_ptr  : int  [200001]      0.8 MB
//   cursor   : int  [200000]      0.8 MB
//   edges    : int2 [3.2M]       25.6 MB  (nb, val-bits) sorted by target
//   h1       : bf16 [200000*64]  25.6 MB

__device__ __forceinline__ float feat0_at(const float* __restrict__ uw,
                                          const float* __restrict__ ew,
                                          int node, int k) {
    return (node < N_USERS) ? uw[node * 64 + k] : ew[(node - N_USERS) * 64 + k];
}

__device__ __forceinline__ unsigned short f32_to_bf16_bits(float x) {
    unsigned u = __float_as_uint(x);
    unsigned r = (u + 0x7fffu + ((u >> 16) & 1u)) >> 16;   // RNE
    return (unsigned short)r;
}

// ---------- CSR build ----------
__global__ __launch_bounds__(256) void hist_k(const int* __restrict__ target,
                                              int* __restrict__ counts, int n_edges)
{
    int e = blockIdx.x * 256 + threadIdx.x;
    if (e < n_edges) atomicAdd(&counts[target[e]], 1);
}

__global__ __launch_bounds__(1024) void scan_k(const int* __restrict__ counts,
                                               int* __restrict__ row_ptr,
                                               int* __restrict__ cursor)
{
    __shared__ int part[1024];
    int t = threadIdx.x;
    const int CH = (N_NODES_C + 1023) / 1024;
    int s = t * CH;
    int e = min(s + CH, N_NODES_C);
    int sum = 0;
    for (int i = s; i < e; i++) sum += counts[i];
    part[t] = sum;
    __syncthreads();
    for (int off = 1; off < 1024; off <<= 1) {
        int v = (t >= off) ? part[t - off] : 0;
        __syncthreads();
        part[t] += v;
        __syncthreads();
    }
    int run = (t == 0) ? 0 : part[t - 1];
    for (int i = s; i < e; i++) {
        row_ptr[i] = run;
        cursor[i]  = run;
        run += counts[i];
    }
    if (t == 1023) row_ptr[N_NODES_C] = part[1023];
}

__global__ __launch_bounds__(256) void scatter_k(
    const int* __restrict__ target, const int* __restrict__ neighbor,
    const float* __restrict__ values, int* __restrict__ cursor,
    int2* __restrict__ edges, int n_edges)
{
    int e = blockIdx.x * 256 + threadIdx.x;
    if (e >= n_edges) return;
    int t   = target[e];
    int pos = atomicAdd(&cursor[t], 1);
    int2 ev;
    ev.x = neighbor[e];
    ev.y = __float_as_int(values[e]);
    edges[pos] = ev;
}

// ---------- layer 1: CSR pull + dense transform fused ----------
// one wave per node; lane = feature dim. Weights packed bf16x2 in LDS (16.6 KB
// total -> 8 blocks/CU -> 32 waves/CU). Edge pull unrolled x4 for MLP.
__global__ __launch_bounds__(256, 8) void layer1_pull_k(
    const float* __restrict__ uw, const float* __restrict__ ew,
    const int* __restrict__ row_ptr, const int2* __restrict__ edges,
    const float* __restrict__ W1, const float* __restrict__ b1,
    const float* __restrict__ W2, const float* __restrict__ b2,
    __hip_bfloat16* __restrict__ h1out, int n_nodes)
{
    __shared__ unsigned int sW[64 * 64];   // lo16 = W1 bf16, hi16 = W2 bf16
    __shared__ float sb[64];
    for (int i = threadIdx.x; i < 64 * 64; i += 256) {
        unsigned a = f32_to_bf16_bits(W1[i]);
        unsigned b = f32_to_bf16_bits(W2[i]);
        sW[i] = (b << 16) | a;
    }
    if (threadIdx.x < 64) sb[threadIdx.x] = b1[threadIdx.x] + b2[threadIdx.x];
    __syncthreads();

    int wave = threadIdx.x >> 6;
    int lane = threadIdx.x & 63;
    int node = blockIdx.x * 4 + wave;
    if (node >= n_nodes) return;

    int es = row_ptr[node];
    int ee = row_ptr[node + 1];

    float hn = 0.f;
    for (int base = es; base < ee; base += 64) {
        int cnt = min(64, ee - base);
        int2 ev = (lane < cnt) ? edges[base + lane] : make_int2(0, 0);
        int j = 0;
        for (; j + 4 <= cnt; j += 4) {
            int   nb0 = __shfl(ev.x, j);     float v0 = __shfl(__int_as_float(ev.y), j);
            int   nb1 = __shfl(ev.x, j + 1); float v1 = __shfl(__int_as_float(ev.y), j + 1);
            int   nb2 = __shfl(ev.x, j + 2); float v2 = __shfl(__int_as_float(ev.y), j + 2);
            int   nb3 = __shfl(ev.x, j + 3); float v3 = __shfl(__int_as_float(ev.y), j + 3);
            float f0 = feat0_at(uw, ew, nb0, lane);
            float f1 = feat0_at(uw, ew, nb1, lane);
            float f2 = feat0_at(uw, ew, nb2, lane);
            float f3 = feat0_at(uw, ew, nb3, lane);
            hn += v0 * f0 + v1 * f1 + v2 * f2 + v3 * f3;
        }
        for (; j < cnt; j++) {
            int   nb = __shfl(ev.x, j);
            float v  = __shfl(__int_as_float(ev.y), j);
            hn += v * feat0_at(uw, ew, nb, lane);
        }
    }

    float f = feat0_at(uw, ew, node, lane);
    float s = f + hn;
    float p = f * hn;

    float acc = sb[lane];
    #pragma unroll
    for (int k = 0; k < 64; k++) {
        float sk = __shfl(s, k);
        float pk = __shfl(p, k);
        unsigned wpk = sW[k * 64 + lane];
        float w1 = __uint_as_float(wpk << 16);
        float w2 = __uint_as_float(wpk & 0xffff0000u);
        acc += sk * w1 + pk * w2;
    }
    acc = (acc > 0.f) ? acc : 0.01f * acc;

    float sq = acc * acc;
    #pragma unroll
    for (int m = 1; m < 64; m <<= 1) sq += __shfl_xor(sq, m);
    float nrm = fmaxf(sqrtf(sq), 1e-12f);
    h1out[(size_t)node * 64 + lane] = __float2bfloat16(acc / nrm);
}

// ---------- inline layer2 (64->32) for one node, aggregation pulled on the fly ----------
__device__ __forceinline__ float layer2_row(
    const __hip_bfloat16* __restrict__ h1,
    const int* __restrict__ row_ptr, const int2* __restrict__ edges,
    const float* sW1, const float* sW2, const float* sb,
    int node, int lane)
{
    int es = row_ptr[node];
    int ee = row_ptr[node + 1];
    float g = 0.f;
    for (int base = es; base < ee; base += 64) {
        int cnt = min(64, ee - base);
        int2 ev = (lane < cnt) ? edges[base + lane] : make_int2(0, 0);
        int j = 0;
        for (; j + 4 <= cnt; j += 4) {
            int   nb0 = __shfl(ev.x, j);     float v0 = __shfl(__int_as_float(ev.y), j);
            int   nb1 = __shfl(ev.x, j + 1); float v1 = __shfl(__int_as_float(ev.y), j + 1);
            int   nb2 = __shfl(ev.x, j + 2); float v2 = __shfl(__int_as_float(ev.y), j + 2);
            int   nb3 = __shfl(ev.x, j + 3); float v3 = __shfl(__int_as_float(ev.y), j + 3);
            float f0 = __bfloat162float(h1[(size_t)nb0 * 64 + lane]);
            float f1 = __bfloat162float(h1[(size_t)nb1 * 64 + lane]);
            float f2 = __bfloat162float(h1[(size_t)nb2 * 64 + lane]);
            float f3 = __bfloat162float(h1[(size_t)nb3 * 64 + lane]);
            g += v0 * f0 + v1 * f1 + v2 * f2 + v3 * f3;
        }
        for (; j < cnt; j++) {
            int   nb = __shfl(ev.x, j);
            float v  = __shfl(__int_as_float(ev.y), j);
            g += v * __bfloat162float(h1[(size_t)nb * 64 + lane]);
        }
    }
    float f = __bfloat162float(h1[(size_t)node * 64 + lane]);
    float s = f + g;
    float p = f * g;
    int j = lane & 31;
    float acc = sb[j];
    #pragma unroll
    for (int k = 0; k < 64; k++) {
        float sk = __shfl(s, k);
        float pk = __shfl(p, k);
        acc += sk * sW1[k * 32 + j] + pk * sW2[k * 32 + j];
    }
    acc = (acc > 0.f) ? acc : 0.01f * acc;
    float sq = acc * acc;
    #pragma unroll
    for (int m = 1; m < 32; m <<= 1) sq += __shfl_xor(sq, m);  // within 32-half
    return acc / fmaxf(sqrtf(sq), 1e-12f);
}

__global__ __launch_bounds__(256) void score_k(
    const float* __restrict__ uw, const float* __restrict__ ew,
    const __hip_bfloat16* __restrict__ h1,
    const int* __restrict__ row_ptr, const int2* __restrict__ edges,
    const float* __restrict__ W1b, const float* __restrict__ b1b,
    const float* __restrict__ W2b, const float* __restrict__ b2b,
    const int* __restrict__ uid, const int* __restrict__ pid,
    const int* __restrict__ nid, float* __restrict__ out)
{
    __shared__ float sW1[64 * 32];
    __shared__ float sW2[64 * 32];
    __shared__ float sb[32];
    for (int i = threadIdx.x; i < 64 * 32; i += 256) { sW1[i] = W1b[i]; sW2[i] = W2b[i]; }
    if (threadIdx.x < 32) sb[threadIdx.x] = b1b[threadIdx.x] + b2b[threadIdx.x];
    __syncthreads();

    int wave = threadIdx.x >> 6;
    int lane = threadIdx.x & 63;
    int i = blockIdx.x * 4 + wave;
    if (i >= BATCH_C) return;

    int un = uid[i];
    int pe = pid[i];
    int ne = nid[i];
    int pn = N_USERS + pe;
    int nn = N_USERS + ne;

    float acc01p, acc01n;
    {
        float u  = uw[(size_t)un * 64 + lane];
        float pv = ew[(size_t)pe * 64 + lane];
        float nv = ew[(size_t)ne * 64 + lane];
        acc01p = u * pv;
        acc01n = u * nv;
        float u1 = __bfloat162float(h1[(size_t)un * 64 + lane]);
        acc01p += u1 * __bfloat162float(h1[(size_t)pn * 64 + lane]);
        acc01n += u1 * __bfloat162float(h1[(size_t)nn * 64 + lane]);
    }

    float h2u = layer2_row(h1, row_ptr, edges, sW1, sW2, sb, un, lane);
    float h2p = layer2_row(h1, row_ptr, edges, sW1, sW2, sb, pn, lane);
    float h2n = layer2_row(h1, row_ptr, edges, sW1, sW2, sb, nn, lane);
    float p2 = h2u * h2p;
    float n2 = h2u * h2n;
    #pragma unroll
    for (int m = 1; m < 32; m <<= 1) { p2 += __shfl_xor(p2, m); n2 += __shfl_xor(n2, m); }

    #pragma unroll
    for (int m = 1; m < 64; m <<= 1) { acc01p += __shfl_xor(acc01p, m); acc01n += __shfl_xor(acc01n, m); }

    if (lane == 0) {
        out[i]           = acc01p + p2;
        out[BATCH_C + i] = acc01n + n2;
    }
}

extern "C" void kernel_launch(void* const* d_in, const int* in_sizes, int n_in,
                              void* d_out, int out_size, void* d_ws, size_t ws_size,
                              hipStream_t stream) {
    const float* uw   = (const float*)d_in[0];
    const float* ew   = (const float*)d_in[1];
    const float* W1a  = (const float*)d_in[2];
    const float* b1a  = (const float*)d_in[3];
    const float* W2a  = (const float*)d_in[4];
    const float* b2a  = (const float*)d_in[5];
    const float* W1b  = (const float*)d_in[6];
    const float* b1b  = (const float*)d_in[7];
    const float* W2b  = (const float*)d_in[8];
    const float* b2b  = (const float*)d_in[9];
    const float* values   = (const float*)d_in[10];
    const int*   target   = (const int*)d_in[11];
    const int*   neighbor = (const int*)d_in[12];
    const int*   uid  = (const int*)d_in[13];
    const int*   pid  = (const int*)d_in[14];
    const int*   nid  = (const int*)d_in[15];

    const int n_edges = in_sizes[10];

    char* ws = (char*)d_ws;
    int*  counts  = (int*)ws;                                   ws += 800256;
    int*  row_ptr = (int*)ws;                                   ws += 800256;
    int*  cursor  = (int*)ws;                                   ws += 800256;
    int2* edges   = (int2*)ws;                                  ws += (size_t)N_EDGES_C * 8;
    __hip_bfloat16* h1 = (__hip_bfloat16*)ws;                   // 25.6 MB

    const int edge_blocks  = (n_edges + 255) / 256;
    const int layer_blocks = (N_NODES_C + 3) / 4;

    // ----- CSR build (shared by both layers) -----
    hipMemsetAsync(counts, 0, (size_t)N_NODES_C * sizeof(int), stream);
    hist_k<<<edge_blocks, 256, 0, stream>>>(target, counts, n_edges);
    scan_k<<<1, 1024, 0, stream>>>(counts, row_ptr, cursor);
    scatter_k<<<edge_blocks, 256, 0, stream>>>(target, neighbor, values, cursor, edges, n_edges);

    // ----- layer 1 (pull + transform fused) -----
    layer1_pull_k<<<layer_blocks, 256, 0, stream>>>(uw, ew, row_ptr, edges,
                                                    W1a, b1a, W2a, b2a, h1, N_NODES_C);

    // ----- scoring (layer-2 aggregation + transform inline, only ~12K nodes) -----
    score_k<<<BATCH_C / 4, 256, 0, stream>>>(uw, ew, h1, row_ptr, edges,
                                             W1b, b1b, W2b, b2b,
                                             uid, pid, nid, (float*)d_out);
}

// Round 5
// 936.547 us; speedup vs baseline: 2.0838x; 1.5055x over previous
//
#include <hip/hip_runtime.h>
#include <hip/hip_bf16.h>

#define N_USERS    50000
#define N_ENTITIES 150000
#define N_NODES_C  200000
#define BATCH_C    4096
#define N_EDGES_C  3200000
#define SCAN_BLK   782          // ceil(200000/256)

// Workspace layout (~54 MB; ws overrun corrupts harness pristine copies):
//   counts     : int  [200192]      0.8 MB
//   row_ptr    : int  [200001+pad]  0.8 MB
//   cursor     : int  [200192]      0.8 MB
//   block_sums : int  [1024]        4 KB
//   block_offs : int  [1024]        4 KB
//   edges      : int2 [3.2M]       25.6 MB  (nb, val-bits) sorted by target
//   h1         : bf16 [200000*64]  25.6 MB

__device__ __forceinline__ float feat0_at(const float* __restrict__ uw,
                                          const float* __restrict__ ew,
                                          int node, int k) {
    return (node < N_USERS) ? uw[node * 64 + k] : ew[(node - N_USERS) * 64 + k];
}

__device__ __forceinline__ unsigned short f32_to_bf16_bits(float x) {
    unsigned u = __float_as_uint(x);
    unsigned r = (u + 0x7fffu + ((u >> 16) & 1u)) >> 16;   // RNE
    return (unsigned short)r;
}

// ---------- CSR build ----------
__global__ __launch_bounds__(256) void hist_k(const int* __restrict__ target,
                                              int* __restrict__ counts, int n_edges)
{
    int e = blockIdx.x * 256 + threadIdx.x;
    if (e < n_edges) atomicAdd(&counts[target[e]], 1);
}

// 1) per-block sums of counts (coalesced)
__global__ __launch_bounds__(256) void partial_k(const int* __restrict__ counts,
                                                 int* __restrict__ block_sums)
{
    __shared__ int red[256];
    int gid = blockIdx.x * 256 + threadIdx.x;
    int c = (gid < N_NODES_C) ? counts[gid] : 0;
    red[threadIdx.x] = c;
    __syncthreads();
    for (int off = 128; off > 0; off >>= 1) {
        if (threadIdx.x < off) red[threadIdx.x] += red[threadIdx.x + off];
        __syncthreads();
    }
    if (threadIdx.x == 0) block_sums[blockIdx.x] = red[0];
}

// 2) single-block exclusive scan of the 782 block sums
__global__ __launch_bounds__(1024) void scansums_k(const int* __restrict__ block_sums,
                                                   int* __restrict__ block_offs)
{
    __shared__ int part[1024];
    int t = threadIdx.x;
    int v = (t < SCAN_BLK) ? block_sums[t] : 0;
    part[t] = v;
    __syncthreads();
    for (int off = 1; off < 1024; off <<= 1) {
        int w = (t >= off) ? part[t - off] : 0;
        __syncthreads();
        part[t] += w;
        __syncthreads();
    }
    if (t < SCAN_BLK) block_offs[t] = part[t] - v;   // exclusive
}

// 3) per-element exclusive prefix: wave shuffle-scan + cross-wave LDS fixup
__global__ __launch_bounds__(256) void finalize_k(const int* __restrict__ counts,
                                                  const int* __restrict__ block_offs,
                                                  int* __restrict__ row_ptr,
                                                  int* __restrict__ cursor, int n_edges)
{
    __shared__ int wsum[4];
    int gid  = blockIdx.x * 256 + threadIdx.x;
    int lane = threadIdx.x & 63;
    int wave = threadIdx.x >> 6;
    int c = (gid < N_NODES_C) ? counts[gid] : 0;

    // inclusive scan within wave
    int s = c;
    #pragma unroll
    for (int off = 1; off < 64; off <<= 1) {
        int v = __shfl_up(s, off);
        if (lane >= off) s += v;
    }
    if (lane == 63) wsum[wave] = s;
    __syncthreads();
    int woff = 0;
    #pragma unroll
    for (int w = 0; w < 4; w++) woff += (w < wave) ? wsum[w] : 0;

    int excl = block_offs[blockIdx.x] + woff + (s - c);
    if (gid < N_NODES_C) {
        row_ptr[gid] = excl;
        cursor[gid]  = excl;
    }
    if (gid == 0) row_ptr[N_NODES_C] = n_edges;
}

__global__ __launch_bounds__(256) void scatter_k(
    const int* __restrict__ target, const int* __restrict__ neighbor,
    const float* __restrict__ values, int* __restrict__ cursor,
    int2* __restrict__ edges, int n_edges)
{
    int e = blockIdx.x * 256 + threadIdx.x;
    if (e >= n_edges) return;
    int t   = target[e];
    int pos = atomicAdd(&cursor[t], 1);
    int2 ev;
    ev.x = neighbor[e];
    ev.y = __float_as_int(values[e]);
    edges[pos] = ev;
}

// ---------- layer 1: CSR pull + dense transform fused ----------
__global__ __launch_bounds__(256, 8) void layer1_pull_k(
    const float* __restrict__ uw, const float* __restrict__ ew,
    const int* __restrict__ row_ptr, const int2* __restrict__ edges,
    const float* __restrict__ W1, const float* __restrict__ b1,
    const float* __restrict__ W2, const float* __restrict__ b2,
    __hip_bfloat16* __restrict__ h1out, int n_nodes)
{
    __shared__ unsigned int sW[64 * 64];   // lo16 = W1 bf16, hi16 = W2 bf16
    __shared__ float sb[64];
    for (int i = threadIdx.x; i < 64 * 64; i += 256) {
        unsigned a = f32_to_bf16_bits(W1[i]);
        unsigned b = f32_to_bf16_bits(W2[i]);
        sW[i] = (b << 16) | a;
    }
    if (threadIdx.x < 64) sb[threadIdx.x] = b1[threadIdx.x] + b2[threadIdx.x];
    __syncthreads();

    int wave = threadIdx.x >> 6;
    int lane = threadIdx.x & 63;
    int node = blockIdx.x * 4 + wave;
    if (node >= n_nodes) return;

    int es = row_ptr[node];
    int ee = row_ptr[node + 1];

    float hn = 0.f;
    for (int base = es; base < ee; base += 64) {
        int cnt = min(64, ee - base);
        int2 ev = (lane < cnt) ? edges[base + lane] : make_int2(0, 0);
        int j = 0;
        for (; j + 4 <= cnt; j += 4) {
            int   nb0 = __shfl(ev.x, j);     float v0 = __shfl(__int_as_float(ev.y), j);
            int   nb1 = __shfl(ev.x, j + 1); float v1 = __shfl(__int_as_float(ev.y), j + 1);
            int   nb2 = __shfl(ev.x, j + 2); float v2 = __shfl(__int_as_float(ev.y), j + 2);
            int   nb3 = __shfl(ev.x, j + 3); float v3 = __shfl(__int_as_float(ev.y), j + 3);
            float f0 = feat0_at(uw, ew, nb0, lane);
            float f1 = feat0_at(uw, ew, nb1, lane);
            float f2 = feat0_at(uw, ew, nb2, lane);
            float f3 = feat0_at(uw, ew, nb3, lane);
            hn += v0 * f0 + v1 * f1 + v2 * f2 + v3 * f3;
        }
        for (; j < cnt; j++) {
            int   nb = __shfl(ev.x, j);
            float v  = __shfl(__int_as_float(ev.y), j);
            hn += v * feat0_at(uw, ew, nb, lane);
        }
    }

    float f = feat0_at(uw, ew, node, lane);
    float s = f + hn;
    float p = f * hn;

    float acc = sb[lane];
    #pragma unroll
    for (int k = 0; k < 64; k++) {
        float sk = __shfl(s, k);
        float pk = __shfl(p, k);
        unsigned wpk = sW[k * 64 + lane];
        float w1 = __uint_as_float(wpk << 16);
        float w2 = __uint_as_float(wpk & 0xffff0000u);
        acc += sk * w1 + pk * w2;
    }
    acc = (acc > 0.f) ? acc : 0.01f * acc;

    float sq = acc * acc;
    #pragma unroll
    for (int m = 1; m < 64; m <<= 1) sq += __shfl_xor(sq, m);
    float nrm = fmaxf(sqrtf(sq), 1e-12f);
    h1out[(size_t)node * 64 + lane] = __float2bfloat16(acc / nrm);
}

// ---------- inline layer2 (64->32) for one node, aggregation pulled on the fly ----------
__device__ __forceinline__ float layer2_row(
    const __hip_bfloat16* __restrict__ h1,
    const int* __restrict__ row_ptr, const int2* __restrict__ edges,
    const float* sW1, const float* sW2, const float* sb,
    int node, int lane)
{
    int es = row_ptr[node];
    int ee = row_ptr[node + 1];
    float g = 0.f;
    for (int base = es; base < ee; base += 64) {
        int cnt = min(64, ee - base);
        int2 ev = (lane < cnt) ? edges[base + lane] : make_int2(0, 0);
        int j = 0;
        for (; j + 4 <= cnt; j += 4) {
            int   nb0 = __shfl(ev.x, j);     float v0 = __shfl(__int_as_float(ev.y), j);
            int   nb1 = __shfl(ev.x, j + 1); float v1 = __shfl(__int_as_float(ev.y), j + 1);
            int   nb2 = __shfl(ev.x, j + 2); float v2 = __shfl(__int_as_float(ev.y), j + 2);
            int   nb3 = __shfl(ev.x, j + 3); float v3 = __shfl(__int_as_float(ev.y), j + 3);
            float f0 = __bfloat162float(h1[(size_t)nb0 * 64 + lane]);
            float f1 = __bfloat162float(h1[(size_t)nb1 * 64 + lane]);
            float f2 = __bfloat162float(h1[(size_t)nb2 * 64 + lane]);
            float f3 = __bfloat162float(h1[(size_t)nb3 * 64 + lane]);
            g += v0 * f0 + v1 * f1 + v2 * f2 + v3 * f3;
        }
        for (; j < cnt; j++) {
            int   nb = __shfl(ev.x, j);
            float v  = __shfl(__int_as_float(ev.y), j);
            g += v * __bfloat162float(h1[(size_t)nb * 64 + lane]);
        }
    }
    float f = __bfloat162float(h1[(size_t)node * 64 + lane]);
    float s = f + g;
    float p = f * g;
    int j = lane & 31;
    float acc = sb[j];
    #pragma unroll
    for (int k = 0; k < 64; k++) {
        float sk = __shfl(s, k);
        float pk = __shfl(p, k);
        acc += sk * sW1[k * 32 + j] + pk * sW2[k * 32 + j];
    }
    acc = (acc > 0.f) ? acc : 0.01f * acc;
    float sq = acc * acc;
    #pragma unroll
    for (int m = 1; m < 32; m <<= 1) sq += __shfl_xor(sq, m);  // within 32-half
    return acc / fmaxf(sqrtf(sq), 1e-12f);
}

__global__ __launch_bounds__(256) void score_k(
    const float* __restrict__ uw, const float* __restrict__ ew,
    const __hip_bfloat16* __restrict__ h1,
    const int* __restrict__ row_ptr, const int2* __restrict__ edges,
    const float* __restrict__ W1b, const float* __restrict__ b1b,
    const float* __restrict__ W2b, const float* __restrict__ b2b,
    const int* __restrict__ uid, const int* __restrict__ pid,
    const int* __restrict__ nid, float* __restrict__ out)
{
    __shared__ float sW1[64 * 32];
    __shared__ float sW2[64 * 32];
    __shared__ float sb[32];
    for (int i = threadIdx.x; i < 64 * 32; i += 256) { sW1[i] = W1b[i]; sW2[i] = W2b[i]; }
    if (threadIdx.x < 32) sb[threadIdx.x] = b1b[threadIdx.x] + b2b[threadIdx.x];
    __syncthreads();

    int wave = threadIdx.x >> 6;
    int lane = threadIdx.x & 63;
    int i = blockIdx.x * 4 + wave;
    if (i >= BATCH_C) return;

    int un = uid[i];
    int pe = pid[i];
    int ne = nid[i];
    int pn = N_USERS + pe;
    int nn = N_USERS + ne;

    float acc01p, acc01n;
    {
        float u  = uw[(size_t)un * 64 + lane];
        float pv = ew[(size_t)pe * 64 + lane];
        float nv = ew[(size_t)ne * 64 + lane];
        acc01p = u * pv;
        acc01n = u * nv;
        float u1 = __bfloat162float(h1[(size_t)un * 64 + lane]);
        acc01p += u1 * __bfloat162float(h1[(size_t)pn * 64 + lane]);
        acc01n += u1 * __bfloat162float(h1[(size_t)nn * 64 + lane]);
    }

    float h2u = layer2_row(h1, row_ptr, edges, sW1, sW2, sb, un, lane);
    float h2p = layer2_row(h1, row_ptr, edges, sW1, sW2, sb, pn, lane);
    float h2n = layer2_row(h1, row_ptr, edges, sW1, sW2, sb, nn, lane);
    float p2 = h2u * h2p;
    float n2 = h2u * h2n;
    #pragma unroll
    for (int m = 1; m < 32; m <<= 1) { p2 += __shfl_xor(p2, m); n2 += __shfl_xor(n2, m); }

    #pragma unroll
    for (int m = 1; m < 64; m <<= 1) { acc01p += __shfl_xor(acc01p, m); acc01n += __shfl_xor(acc01n, m); }

    if (lane == 0) {
        out[i]           = acc01p + p2;
        out[BATCH_C + i] = acc01n + n2;
    }
}

extern "C" void kernel_launch(void* const* d_in, const int* in_sizes, int n_in,
                              void* d_out, int out_size, void* d_ws, size_t ws_size,
                              hipStream_t stream) {
    const float* uw   = (const float*)d_in[0];
    const float* ew   = (const float*)d_in[1];
    const float* W1a  = (const float*)d_in[2];
    const float* b1a  = (const float*)d_in[3];
    const float* W2a  = (const float*)d_in[4];
    const float* b2a  = (const float*)d_in[5];
    const float* W1b  = (const float*)d_in[6];
    const float* b1b  = (const float*)d_in[7];
    const float* W2b  = (const float*)d_in[8];
    const float* b2b  = (const float*)d_in[9];
    const float* values   = (const float*)d_in[10];
    const int*   target   = (const int*)d_in[11];
    const int*   neighbor = (const int*)d_in[12];
    const int*   uid  = (const int*)d_in[13];
    const int*   pid  = (const int*)d_in[14];
    const int*   nid  = (const int*)d_in[15];

    const int n_edges = in_sizes[10];

    char* ws = (char*)d_ws;
    int*  counts     = (int*)ws;   ws += 801792;          // 200192*4 padded
    int*  row_ptr    = (int*)ws;   ws += 801792;
    int*  cursor     = (int*)ws;   ws += 801792;
    int*  block_sums = (int*)ws;   ws += 4096;
    int*  block_offs = (int*)ws;   ws += 4096;
    int2* edges      = (int2*)ws;  ws += (size_t)N_EDGES_C * 8;
    __hip_bfloat16* h1 = (__hip_bfloat16*)ws;             // 25.6 MB

    const int edge_blocks  = (n_edges + 255) / 256;
    const int layer_blocks = (N_NODES_C + 3) / 4;

    // ----- CSR build (shared by both layers) -----
    hipMemsetAsync(counts, 0, (size_t)N_NODES_C * sizeof(int), stream);
    hist_k<<<edge_blocks, 256, 0, stream>>>(target, counts, n_edges);
    partial_k<<<SCAN_BLK, 256, 0, stream>>>(counts, block_sums);
    scansums_k<<<1, 1024, 0, stream>>>(block_sums, block_offs);
    finalize_k<<<SCAN_BLK, 256, 0, stream>>>(counts, block_offs, row_ptr, cursor, n_edges);
    scatter_k<<<edge_blocks, 256, 0, stream>>>(target, neighbor, values, cursor, edges, n_edges);

    // ----- layer 1 (pull + transform fused) -----
    layer1_pull_k<<<layer_blocks, 256, 0, stream>>>(uw, ew, row_ptr, edges,
                                                    W1a, b1a, W2a, b2a, h1, N_NODES_C);

    // ----- scoring (layer-2 aggregation + transform inline, only ~12K nodes) -----
    score_k<<<BATCH_C / 4, 256, 0, stream>>>(uw, ew, h1, row_ptr, edges,
                                             W1b, b1b, W2b, b2b,
                                             uid, pid, nid, (float*)d_out);
}

// Round 6
// 922.146 us; speedup vs baseline: 2.1163x; 1.0156x over previous
//
#include <hip/hip_runtime.h>
#include <hip/hip_bf16.h>

#define N_USERS    50000
#define N_ENTITIES 150000
#define N_NODES_C  200000
#define BATCH_C    4096
#define N_EDGES_C  3200000
#define SCAN_BLK   782          // ceil(200000/256)

// Workspace layout (~66 MB; proven safe < 76.8 MB; overrun corrupts harness
// pristine copies => first call right, replays wrong):
//   counts     : int    [200192]       0.8 MB
//   row_ptr    : int    [200001+pad]   0.8 MB
//   cursor     : int    [200192]       0.8 MB
//   block_sums : int    [1024]         4 KB
//   block_offs : int    [1024]         4 KB
//   edges      : uint   [3.2M]        12.8 MB  (nb<<14 | val_q14, sorted by target)
//   fb16       : ushort [200000*64]   25.6 MB  (bf16 bits of concat(uw,ew))
//   h1         : bf16   [200000*64]   25.6 MB

__device__ __forceinline__ float feat0_at(const float* __restrict__ uw,
                                          const float* __restrict__ ew,
                                          int node, int k) {
    return (node < N_USERS) ? uw[node * 64 + k] : ew[(node - N_USERS) * 64 + k];
}

__device__ __forceinline__ unsigned short f32_to_bf16_bits(float x) {
    unsigned u = __float_as_uint(x);
    unsigned r = (u + 0x7fffu + ((u >> 16) & 1u)) >> 16;   // RNE
    return (unsigned short)r;
}

__device__ __forceinline__ float bf16bits_to_f32(unsigned short b) {
    return __uint_as_float(((unsigned)b) << 16);
}

// ---------- bf16 node-feature table ----------
__global__ __launch_bounds__(256) void tobf16_k(const float* __restrict__ uw,
                                                const float* __restrict__ ew,
                                                unsigned short* __restrict__ fb)
{
    int idx = blockIdx.x * 256 + threadIdx.x;      // 12.8M elements
    if (idx >= N_NODES_C * 64) return;
    const int split = N_USERS * 64;
    float x = (idx < split) ? uw[idx] : ew[idx - split];
    fb[idx] = f32_to_bf16_bits(x);
}

// ---------- CSR build ----------
__global__ __launch_bounds__(256) void hist_k(const int* __restrict__ target,
                                              int* __restrict__ counts, int n_edges)
{
    int e = blockIdx.x * 256 + threadIdx.x;
    if (e < n_edges) atomicAdd(&counts[target[e]], 1);
}

__global__ __launch_bounds__(256) void partial_k(const int* __restrict__ counts,
                                                 int* __restrict__ block_sums)
{
    __shared__ int red[256];
    int gid = blockIdx.x * 256 + threadIdx.x;
    int c = (gid < N_NODES_C) ? counts[gid] : 0;
    red[threadIdx.x] = c;
    __syncthreads();
    for (int off = 128; off > 0; off >>= 1) {
        if (threadIdx.x < off) red[threadIdx.x] += red[threadIdx.x + off];
        __syncthreads();
    }
    if (threadIdx.x == 0) block_sums[blockIdx.x] = red[0];
}

__global__ __launch_bounds__(1024) void scansums_k(const int* __restrict__ block_sums,
                                                   int* __restrict__ block_offs)
{
    __shared__ int part[1024];
    int t = threadIdx.x;
    int v = (t < SCAN_BLK) ? block_sums[t] : 0;
    part[t] = v;
    __syncthreads();
    for (int off = 1; off < 1024; off <<= 1) {
        int w = (t >= off) ? part[t - off] : 0;
        __syncthreads();
        part[t] += w;
        __syncthreads();
    }
    if (t < SCAN_BLK) block_offs[t] = part[t] - v;   // exclusive
}

__global__ __launch_bounds__(256) void finalize_k(const int* __restrict__ counts,
                                                  const int* __restrict__ block_offs,
                                                  int* __restrict__ row_ptr,
                                                  int* __restrict__ cursor, int n_edges)
{
    __shared__ int wsum[4];
    int gid  = blockIdx.x * 256 + threadIdx.x;
    int lane = threadIdx.x & 63;
    int wave = threadIdx.x >> 6;
    int c = (gid < N_NODES_C) ? counts[gid] : 0;

    int s = c;
    #pragma unroll
    for (int off = 1; off < 64; off <<= 1) {
        int v = __shfl_up(s, off);
        if (lane >= off) s += v;
    }
    if (lane == 63) wsum[wave] = s;
    __syncthreads();
    int woff = 0;
    #pragma unroll
    for (int w = 0; w < 4; w++) woff += (w < wave) ? wsum[w] : 0;

    int excl = block_offs[blockIdx.x] + woff + (s - c);
    if (gid < N_NODES_C) {
        row_ptr[gid] = excl;
        cursor[gid]  = excl;
    }
    if (gid == 0) row_ptr[N_NODES_C] = n_edges;
}

// packed edge: nb (18 bits) << 14 | val quantized to 14-bit fixed point.
// val in [0,1): abs quant err 3e-5 -> negligible in the 16-edge sums.
__global__ __launch_bounds__(256) void scatter_k(
    const int* __restrict__ target, const int* __restrict__ neighbor,
    const float* __restrict__ values, int* __restrict__ cursor,
    unsigned int* __restrict__ edges, int n_edges)
{
    int e = blockIdx.x * 256 + threadIdx.x;
    if (e >= n_edges) return;
    int t   = target[e];
    int pos = atomicAdd(&cursor[t], 1);
    unsigned q = (unsigned)fminf(values[e] * 16384.f + 0.5f, 16383.f);
    edges[pos] = ((unsigned)neighbor[e] << 14) | q;
}

// ---------- layer 1: CSR pull (bf16 gathers) + dense transform fused ----------
__global__ __launch_bounds__(256, 8) void layer1_pull_k(
    const float* __restrict__ uw, const float* __restrict__ ew,
    const unsigned short* __restrict__ fb,
    const int* __restrict__ row_ptr, const unsigned int* __restrict__ edges,
    const float* __restrict__ W1, const float* __restrict__ b1,
    const float* __restrict__ W2, const float* __restrict__ b2,
    __hip_bfloat16* __restrict__ h1out, int n_nodes)
{
    __shared__ unsigned int sW[64 * 64];   // lo16 = W1 bf16, hi16 = W2 bf16
    __shared__ float sb[64];
    for (int i = threadIdx.x; i < 64 * 64; i += 256) {
        unsigned a = f32_to_bf16_bits(W1[i]);
        unsigned b = f32_to_bf16_bits(W2[i]);
        sW[i] = (b << 16) | a;
    }
    if (threadIdx.x < 64) sb[threadIdx.x] = b1[threadIdx.x] + b2[threadIdx.x];
    __syncthreads();

    int wave = threadIdx.x >> 6;
    int lane = threadIdx.x & 63;
    int node = blockIdx.x * 4 + wave;
    if (node >= n_nodes) return;

    int es = row_ptr[node];
    int ee = row_ptr[node + 1];

    const float QS = 1.f / 16384.f;
    float hn = 0.f;
    for (int base = es; base < ee; base += 64) {
        int cnt = min(64, ee - base);
        unsigned ev = (lane < cnt) ? edges[base + lane] : 0u;
        int j = 0;
        for (; j + 4 <= cnt; j += 4) {
            unsigned e0 = (unsigned)__shfl((int)ev, j);
            unsigned e1 = (unsigned)__shfl((int)ev, j + 1);
            unsigned e2 = (unsigned)__shfl((int)ev, j + 2);
            unsigned e3 = (unsigned)__shfl((int)ev, j + 3);
            float f0 = bf16bits_to_f32(fb[(size_t)(e0 >> 14) * 64 + lane]);
            float f1 = bf16bits_to_f32(fb[(size_t)(e1 >> 14) * 64 + lane]);
            float f2 = bf16bits_to_f32(fb[(size_t)(e2 >> 14) * 64 + lane]);
            float f3 = bf16bits_to_f32(fb[(size_t)(e3 >> 14) * 64 + lane]);
            hn += (float)(e0 & 16383u) * QS * f0 + (float)(e1 & 16383u) * QS * f1
                + (float)(e2 & 16383u) * QS * f2 + (float)(e3 & 16383u) * QS * f3;
        }
        for (; j < cnt; j++) {
            unsigned e0 = (unsigned)__shfl((int)ev, j);
            float f0 = bf16bits_to_f32(fb[(size_t)(e0 >> 14) * 64 + lane]);
            hn += (float)(e0 & 16383u) * QS * f0;
        }
    }

    float f = feat0_at(uw, ew, node, lane);   // self feature in f32
    float s = f + hn;
    float p = f * hn;

    float acc = sb[lane];
    #pragma unroll
    for (int k = 0; k < 64; k++) {
        float sk = __shfl(s, k);
        float pk = __shfl(p, k);
        unsigned wpk = sW[k * 64 + lane];
        float w1 = __uint_as_float(wpk << 16);
        float w2 = __uint_as_float(wpk & 0xffff0000u);
        acc += sk * w1 + pk * w2;
    }
    acc = (acc > 0.f) ? acc : 0.01f * acc;

    float sq = acc * acc;
    #pragma unroll
    for (int m = 1; m < 64; m <<= 1) sq += __shfl_xor(sq, m);
    float nrm = fmaxf(sqrtf(sq), 1e-12f);
    h1out[(size_t)node * 64 + lane] = __float2bfloat16(acc / nrm);
}

// ---------- inline layer2 (64->32) for one node, aggregation pulled on the fly ----------
__device__ __forceinline__ float layer2_row(
    const __hip_bfloat16* __restrict__ h1,
    const int* __restrict__ row_ptr, const unsigned int* __restrict__ edges,
    const float* sW1, const float* sW2, const float* sb,
    int node, int lane)
{
    int es = row_ptr[node];
    int ee = row_ptr[node + 1];
    const float QS = 1.f / 16384.f;
    float g = 0.f;
    for (int base = es; base < ee; base += 64) {
        int cnt = min(64, ee - base);
        unsigned ev = (lane < cnt) ? edges[base + lane] : 0u;
        int j = 0;
        for (; j + 4 <= cnt; j += 4) {
            unsigned e0 = (unsigned)__shfl((int)ev, j);
            unsigned e1 = (unsigned)__shfl((int)ev, j + 1);
            unsigned e2 = (unsigned)__shfl((int)ev, j + 2);
            unsigned e3 = (unsigned)__shfl((int)ev, j + 3);
            float f0 = __bfloat162float(h1[(size_t)(e0 >> 14) * 64 + lane]);
            float f1 = __bfloat162float(h1[(size_t)(e1 >> 14) * 64 + lane]);
            float f2 = __bfloat162float(h1[(size_t)(e2 >> 14) * 64 + lane]);
            float f3 = __bfloat162float(h1[(size_t)(e3 >> 14) * 64 + lane]);
            g += (float)(e0 & 16383u) * QS * f0 + (float)(e1 & 16383u) * QS * f1
               + (float)(e2 & 16383u) * QS * f2 + (float)(e3 & 16383u) * QS * f3;
        }
        for (; j < cnt; j++) {
            unsigned e0 = (unsigned)__shfl((int)ev, j);
            float f0 = __bfloat162float(h1[(size_t)(e0 >> 14) * 64 + lane]);
            g += (float)(e0 & 16383u) * QS * f0;
        }
    }
    float f = __bfloat162float(h1[(size_t)node * 64 + lane]);
    float s = f + g;
    float p = f * g;
    int j = lane & 31;
    float acc = sb[j];
    #pragma unroll
    for (int k = 0; k < 64; k++) {
        float sk = __shfl(s, k);
        float pk = __shfl(p, k);
        acc += sk * sW1[k * 32 + j] + pk * sW2[k * 32 + j];
    }
    acc = (acc > 0.f) ? acc : 0.01f * acc;
    float sq = acc * acc;
    #pragma unroll
    for (int m = 1; m < 32; m <<= 1) sq += __shfl_xor(sq, m);  // within 32-half
    return acc / fmaxf(sqrtf(sq), 1e-12f);
}

__global__ __launch_bounds__(256) void score_k(
    const float* __restrict__ uw, const float* __restrict__ ew,
    const __hip_bfloat16* __restrict__ h1,
    const int* __restrict__ row_ptr, const unsigned int* __restrict__ edges,
    const float* __restrict__ W1b, const float* __restrict__ b1b,
    const float* __restrict__ W2b, const float* __restrict__ b2b,
    const int* __restrict__ uid, const int* __restrict__ pid,
    const int* __restrict__ nid, float* __restrict__ out)
{
    __shared__ float sW1[64 * 32];
    __shared__ float sW2[64 * 32];
    __shared__ float sb[32];
    for (int i = threadIdx.x; i < 64 * 32; i += 256) { sW1[i] = W1b[i]; sW2[i] = W2b[i]; }
    if (threadIdx.x < 32) sb[threadIdx.x] = b1b[threadIdx.x] + b2b[threadIdx.x];
    __syncthreads();

    int wave = threadIdx.x >> 6;
    int lane = threadIdx.x & 63;
    int i = blockIdx.x * 4 + wave;
    if (i >= BATCH_C) return;

    int un = uid[i];
    int pe = pid[i];
    int ne = nid[i];
    int pn = N_USERS + pe;
    int nn = N_USERS + ne;

    float acc01p, acc01n;
    {
        float u  = uw[(size_t)un * 64 + lane];
        float pv = ew[(size_t)pe * 64 + lane];
        float nv = ew[(size_t)ne * 64 + lane];
        acc01p = u * pv;
        acc01n = u * nv;
        float u1 = __bfloat162float(h1[(size_t)un * 64 + lane]);
        acc01p += u1 * __bfloat162float(h1[(size_t)pn * 64 + lane]);
        acc01n += u1 * __bfloat162float(h1[(size_t)nn * 64 + lane]);
    }

    float h2u = layer2_row(h1, row_ptr, edges, sW1, sW2, sb, un, lane);
    float h2p = layer2_row(h1, row_ptr, edges, sW1, sW2, sb, pn, lane);
    float h2n = layer2_row(h1, row_ptr, edges, sW1, sW2, sb, nn, lane);
    float p2 = h2u * h2p;
    float n2 = h2u * h2n;
    #pragma unroll
    for (int m = 1; m < 32; m <<= 1) { p2 += __shfl_xor(p2, m); n2 += __shfl_xor(n2, m); }

    #pragma unroll
    for (int m = 1; m < 64; m <<= 1) { acc01p += __shfl_xor(acc01p, m); acc01n += __shfl_xor(acc01n, m); }

    if (lane == 0) {
        out[i]           = acc01p + p2;
        out[BATCH_C + i] = acc01n + n2;
    }
}

extern "C" void kernel_launch(void* const* d_in, const int* in_sizes, int n_in,
                              void* d_out, int out_size, void* d_ws, size_t ws_size,
                              hipStream_t stream) {
    const float* uw   = (const float*)d_in[0];
    const float* ew   = (const float*)d_in[1];
    const float* W1a  = (const float*)d_in[2];
    const float* b1a  = (const float*)d_in[3];
    const float* W2a  = (const float*)d_in[4];
    const float* b2a  = (const float*)d_in[5];
    const float* W1b  = (const float*)d_in[6];
    const float* b1b  = (const float*)d_in[7];
    const float* W2b  = (const float*)d_in[8];
    const float* b2b  = (const float*)d_in[9];
    const float* values   = (const float*)d_in[10];
    const int*   target   = (const int*)d_in[11];
    const int*   neighbor = (const int*)d_in[12];
    const int*   uid  = (const int*)d_in[13];
    const int*   pid  = (const int*)d_in[14];
    const int*   nid  = (const int*)d_in[15];

    const int n_edges = in_sizes[10];

    char* ws = (char*)d_ws;
    int*  counts     = (int*)ws;   ws += 801792;          // 200192*4 padded
    int*  row_ptr    = (int*)ws;   ws += 801792;
    int*  cursor     = (int*)ws;   ws += 801792;
    int*  block_sums = (int*)ws;   ws += 4096;
    int*  block_offs = (int*)ws;   ws += 4096;
    unsigned int*   edges = (unsigned int*)ws;   ws += (size_t)N_EDGES_C * 4;   // 12.8 MB
    unsigned short* fb    = (unsigned short*)ws; ws += (size_t)N_NODES_C * 64 * 2; // 25.6 MB
    __hip_bfloat16* h1    = (__hip_bfloat16*)ws;          // 25.6 MB

    const int edge_blocks  = (n_edges + 255) / 256;
    const int layer_blocks = (N_NODES_C + 3) / 4;
    const int conv_blocks  = (N_NODES_C * 64 + 255) / 256;

    // ----- bf16 feature table + CSR build (shared by both layers) -----
    hipMemsetAsync(counts, 0, (size_t)N_NODES_C * sizeof(int), stream);
    tobf16_k<<<conv_blocks, 256, 0, stream>>>(uw, ew, fb);
    hist_k<<<edge_blocks, 256, 0, stream>>>(target, counts, n_edges);
    partial_k<<<SCAN_BLK, 256, 0, stream>>>(counts, block_sums);
    scansums_k<<<1, 1024, 0, stream>>>(block_sums, block_offs);
    finalize_k<<<SCAN_BLK, 256, 0, stream>>>(counts, block_offs, row_ptr, cursor, n_edges);
    scatter_k<<<edge_blocks, 256, 0, stream>>>(target, neighbor, values, cursor, edges, n_edges);

    // ----- layer 1 (pull + transform fused, bf16 gathers) -----
    layer1_pull_k<<<layer_blocks, 256, 0, stream>>>(uw, ew, fb, row_ptr, edges,
                                                    W1a, b1a, W2a, b2a, h1, N_NODES_C);

    // ----- scoring (layer-2 aggregation + transform inline, only ~12K nodes) -----
    score_k<<<BATCH_C / 4, 256, 0, stream>>>(uw, ew, h1, row_ptr, edges,
                                             W1b, b1b, W2b, b2b,
                                             uid, pid, nid, (float*)d_out);
}

// Round 7
// 756.589 us; speedup vs baseline: 2.5794x; 1.2188x over previous
//
#include <hip/hip_runtime.h>
#include <hip/hip_bf16.h>

#define N_USERS    50000
#define N_ENTITIES 150000
#define N_NODES_C  200000
#define BATCH_C    4096
#define N_EDGES_C  3200000
#define SCAN_BLK   782          // ceil(200000/256)

// Workspace layout (~66 MB; proven safe; overrun corrupts harness pristine
// copies => first call right, replays wrong):
//   counts     : int    [200192]       0.8 MB
//   row_ptr    : int    [200001+pad]   0.8 MB
//   cursor     : int    [200192]       0.8 MB
//   block_sums : int    [1024]         4 KB
//   block_offs : int    [1024]         4 KB
//   edges      : uint   [3.2M]        12.8 MB  (nb<<14 | val_q14, sorted by target)
//   fb16       : ushort [200000*64]   25.6 MB  (bf16 bits of concat(uw,ew))
//   h1         : bf16   [200000*64]   25.6 MB

__device__ __forceinline__ float feat0_at(const float* __restrict__ uw,
                                          const float* __restrict__ ew,
                                          int node, int k) {
    return (node < N_USERS) ? uw[node * 64 + k] : ew[(node - N_USERS) * 64 + k];
}

__device__ __forceinline__ unsigned short f32_to_bf16_bits(float x) {
    unsigned u = __float_as_uint(x);
    unsigned r = (u + 0x7fffu + ((u >> 16) & 1u)) >> 16;   // RNE
    return (unsigned short)r;
}

__device__ __forceinline__ float bf16bits_to_f32(unsigned short b) {
    return __uint_as_float(((unsigned)b) << 16);
}

// pack two f32 -> (bf16(p)<<16)|bf16(s)
__device__ __forceinline__ unsigned pack_sp(float s, float p) {
    return ((unsigned)f32_to_bf16_bits(p) << 16) | (unsigned)f32_to_bf16_bits(s);
}

// ---------- bf16 node-feature table ----------
__global__ __launch_bounds__(256) void tobf16_k(const float* __restrict__ uw,
                                                const float* __restrict__ ew,
                                                unsigned short* __restrict__ fb)
{
    int idx = blockIdx.x * 256 + threadIdx.x;      // 12.8M elements
    if (idx >= N_NODES_C * 64) return;
    const int split = N_USERS * 64;
    float x = (idx < split) ? uw[idx] : ew[idx - split];
    fb[idx] = f32_to_bf16_bits(x);
}

// ---------- CSR build ----------
__global__ __launch_bounds__(256) void hist_k(const int* __restrict__ target,
                                              int* __restrict__ counts, int n_edges)
{
    int e = blockIdx.x * 256 + threadIdx.x;
    if (e < n_edges) atomicAdd(&counts[target[e]], 1);
}

__global__ __launch_bounds__(256) void partial_k(const int* __restrict__ counts,
                                                 int* __restrict__ block_sums)
{
    __shared__ int red[256];
    int gid = blockIdx.x * 256 + threadIdx.x;
    int c = (gid < N_NODES_C) ? counts[gid] : 0;
    red[threadIdx.x] = c;
    __syncthreads();
    for (int off = 128; off > 0; off >>= 1) {
        if (threadIdx.x < off) red[threadIdx.x] += red[threadIdx.x + off];
        __syncthreads();
    }
    if (threadIdx.x == 0) block_sums[blockIdx.x] = red[0];
}

__global__ __launch_bounds__(1024) void scansums_k(const int* __restrict__ block_sums,
                                                   int* __restrict__ block_offs)
{
    __shared__ int part[1024];
    int t = threadIdx.x;
    int v = (t < SCAN_BLK) ? block_sums[t] : 0;
    part[t] = v;
    __syncthreads();
    for (int off = 1; off < 1024; off <<= 1) {
        int w = (t >= off) ? part[t - off] : 0;
        __syncthreads();
        part[t] += w;
        __syncthreads();
    }
    if (t < SCAN_BLK) block_offs[t] = part[t] - v;   // exclusive
}

__global__ __launch_bounds__(256) void finalize_k(const int* __restrict__ counts,
                                                  const int* __restrict__ block_offs,
                                                  int* __restrict__ row_ptr,
                                                  int* __restrict__ cursor, int n_edges)
{
    __shared__ int wsum[4];
    int gid  = blockIdx.x * 256 + threadIdx.x;
    int lane = threadIdx.x & 63;
    int wave = threadIdx.x >> 6;
    int c = (gid < N_NODES_C) ? counts[gid] : 0;

    int s = c;
    #pragma unroll
    for (int off = 1; off < 64; off <<= 1) {
        int v = __shfl_up(s, off);
        if (lane >= off) s += v;
    }
    if (lane == 63) wsum[wave] = s;
    __syncthreads();
    int woff = 0;
    #pragma unroll
    for (int w = 0; w < 4; w++) woff += (w < wave) ? wsum[w] : 0;

    int excl = block_offs[blockIdx.x] + woff + (s - c);
    if (gid < N_NODES_C) {
        row_ptr[gid] = excl;
        cursor[gid]  = excl;
    }
    if (gid == 0) row_ptr[N_NODES_C] = n_edges;
}

// packed edge: nb (18 bits) << 14 | val quantized to 14-bit fixed point.
__global__ __launch_bounds__(256) void scatter_k(
    const int* __restrict__ target, const int* __restrict__ neighbor,
    const float* __restrict__ values, int* __restrict__ cursor,
    unsigned int* __restrict__ edges, int n_edges)
{
    int e = blockIdx.x * 256 + threadIdx.x;
    if (e >= n_edges) return;
    int t   = target[e];
    int pos = atomicAdd(&cursor[t], 1);
    unsigned q = (unsigned)fminf(values[e] * 16384.f + 0.5f, 16383.f);
    edges[pos] = ((unsigned)neighbor[e] << 14) | q;
}

// ---------- layer 1: quad-gather CSR pull + dense transform fused ----------
// one wave per node. Edge loop: 4 groups of 16 lanes; each group handles one
// edge per iteration, each lane gathering 4 bf16 dims via one uint2 load
// (64 lanes x 8B = 512B = 4 full rows per load instruction).
// Zero-padded edge words (val=0) make tail groups contribute exactly 0.
__global__ __launch_bounds__(256, 8) void layer1_pull_k(
    const unsigned short* __restrict__ fb,
    const int* __restrict__ row_ptr, const unsigned int* __restrict__ edges,
    const float* __restrict__ W1, const float* __restrict__ b1,
    const float* __restrict__ W2, const float* __restrict__ b2,
    __hip_bfloat16* __restrict__ h1out, int n_nodes)
{
    __shared__ unsigned int sW[64 * 64];   // lo16 = W1 bf16, hi16 = W2 bf16
    __shared__ float sb[64];
    for (int i = threadIdx.x; i < 64 * 64; i += 256) {
        unsigned a = f32_to_bf16_bits(W1[i]);
        unsigned b = f32_to_bf16_bits(W2[i]);
        sW[i] = (b << 16) | a;
    }
    if (threadIdx.x < 64) sb[threadIdx.x] = b1[threadIdx.x] + b2[threadIdx.x];
    __syncthreads();

    int wave = threadIdx.x >> 6;
    int lane = threadIdx.x & 63;
    int node = blockIdx.x * 4 + wave;
    if (node >= n_nodes) return;

    int g = lane >> 4;          // edge group 0..3
    int q = lane & 15;          // dim-quad index: dims 4q..4q+3
    const uint2* fb2 = (const uint2*)fb;

    int es = row_ptr[node];
    int ee = row_ptr[node + 1];

    const float QS = 1.f / 16384.f;
    float h0 = 0.f, h1a = 0.f, h2a = 0.f, h3a = 0.f;
    for (int base = es; base < ee; base += 64) {
        int cnt = min(64, ee - base);
        unsigned ev = (lane < cnt) ? edges[base + lane] : 0u;   // 0 => val 0
        int jmax = (cnt + 3) >> 2;
        #pragma unroll 4
        for (int j = 0; j < jmax; j++) {
            unsigned w = (unsigned)__shfl((int)ev, j * 4 + g);
            float v = (float)(w & 16383u) * QS;
            uint2 d = fb2[(size_t)(w >> 14) * 16 + q];
            h0  += v * __uint_as_float(d.x << 16);
            h1a += v * __uint_as_float(d.x & 0xffff0000u);
            h2a += v * __uint_as_float(d.y << 16);
            h3a += v * __uint_as_float(d.y & 0xffff0000u);
        }
    }
    // reduce the 4 edge-groups (lanes l, l^16, l^32, l^48 share dim-quad q)
    #pragma unroll
    for (int m = 16; m < 64; m <<= 1) {
        h0  += __shfl_xor(h0, m);
        h1a += __shfl_xor(h1a, m);
        h2a += __shfl_xor(h2a, m);
        h3a += __shfl_xor(h3a, m);
    }

    // self feature (bf16 table) in the same quad layout
    uint2 dself = fb2[(size_t)node * 16 + q];
    float f0 = __uint_as_float(dself.x << 16);
    float f1 = __uint_as_float(dself.x & 0xffff0000u);
    float f2 = __uint_as_float(dself.y << 16);
    float f3 = __uint_as_float(dself.y & 0xffff0000u);
    unsigned spq0 = pack_sp(f0 + h0,  f0 * h0);
    unsigned spq1 = pack_sp(f1 + h1a, f1 * h1a);
    unsigned spq2 = pack_sp(f2 + h2a, f2 * h2a);
    unsigned spq3 = pack_sp(f3 + h3a, f3 * h3a);

    // dense: dim k lives in reg k&3 (compile-time under unroll) of lane k>>2
    float acc = sb[lane];
    #pragma unroll
    for (int k = 0; k < 64; k++) {
        unsigned spsel = (k & 3) == 0 ? spq0 : (k & 3) == 1 ? spq1
                       : (k & 3) == 2 ? spq2 : spq3;
        unsigned sp = (unsigned)__shfl((int)spsel, k >> 2);
        float sk = __uint_as_float(sp << 16);
        float pk = __uint_as_float(sp & 0xffff0000u);
        unsigned wpk = sW[k * 64 + lane];
        acc += sk * __uint_as_float(wpk << 16)
             + pk * __uint_as_float(wpk & 0xffff0000u);
    }
    acc = (acc > 0.f) ? acc : 0.01f * acc;

    float sq = acc * acc;
    #pragma unroll
    for (int m = 1; m < 64; m <<= 1) sq += __shfl_xor(sq, m);
    float nrm = fmaxf(sqrtf(sq), 1e-12f);
    h1out[(size_t)node * 64 + lane] = __float2bfloat16(acc / nrm);
}

// ---------- inline layer2 (64->32) for one node, aggregation pulled on the fly ----------
__device__ __forceinline__ float layer2_row(
    const __hip_bfloat16* __restrict__ h1,
    const int* __restrict__ row_ptr, const unsigned int* __restrict__ edges,
    const float* sW1, const float* sW2, const float* sb,
    int node, int lane)
{
    int es = row_ptr[node];
    int ee = row_ptr[node + 1];
    const float QS = 1.f / 16384.f;
    float g = 0.f;
    for (int base = es; base < ee; base += 64) {
        int cnt = min(64, ee - base);
        unsigned ev = (lane < cnt) ? edges[base + lane] : 0u;
        int j = 0;
        for (; j + 4 <= cnt; j += 4) {
            unsigned e0 = (unsigned)__shfl((int)ev, j);
            unsigned e1 = (unsigned)__shfl((int)ev, j + 1);
            unsigned e2 = (unsigned)__shfl((int)ev, j + 2);
            unsigned e3 = (unsigned)__shfl((int)ev, j + 3);
            float f0 = __bfloat162float(h1[(size_t)(e0 >> 14) * 64 + lane]);
            float f1 = __bfloat162float(h1[(size_t)(e1 >> 14) * 64 + lane]);
            float f2 = __bfloat162float(h1[(size_t)(e2 >> 14) * 64 + lane]);
            float f3 = __bfloat162float(h1[(size_t)(e3 >> 14) * 64 + lane]);
            g += (float)(e0 & 16383u) * QS * f0 + (float)(e1 & 16383u) * QS * f1
               + (float)(e2 & 16383u) * QS * f2 + (float)(e3 & 16383u) * QS * f3;
        }
        for (; j < cnt; j++) {
            unsigned e0 = (unsigned)__shfl((int)ev, j);
            float f0 = __bfloat162float(h1[(size_t)(e0 >> 14) * 64 + lane]);
            g += (float)(e0 & 16383u) * QS * f0;
        }
    }
    float f = __bfloat162float(h1[(size_t)node * 64 + lane]);
    float s = f + g;
    float p = f * g;
    int j = lane & 31;
    float acc = sb[j];
    #pragma unroll
    for (int k = 0; k < 64; k++) {
        float sk = __shfl(s, k);
        float pk = __shfl(p, k);
        acc += sk * sW1[k * 32 + j] + pk * sW2[k * 32 + j];
    }
    acc = (acc > 0.f) ? acc : 0.01f * acc;
    float sq = acc * acc;
    #pragma unroll
    for (int m = 1; m < 32; m <<= 1) sq += __shfl_xor(sq, m);  // within 32-half
    return acc / fmaxf(sqrtf(sq), 1e-12f);
}

__global__ __launch_bounds__(256) void score_k(
    const float* __restrict__ uw, const float* __restrict__ ew,
    const __hip_bfloat16* __restrict__ h1,
    const int* __restrict__ row_ptr, const unsigned int* __restrict__ edges,
    const float* __restrict__ W1b, const float* __restrict__ b1b,
    const float* __restrict__ W2b, const float* __restrict__ b2b,
    const int* __restrict__ uid, const int* __restrict__ pid,
    const int* __restrict__ nid, float* __restrict__ out)
{
    __shared__ float sW1[64 * 32];
    __shared__ float sW2[64 * 32];
    __shared__ float sb[32];
    for (int i = threadIdx.x; i < 64 * 32; i += 256) { sW1[i] = W1b[i]; sW2[i] = W2b[i]; }
    if (threadIdx.x < 32) sb[threadIdx.x] = b1b[threadIdx.x] + b2b[threadIdx.x];
    __syncthreads();

    int wave = threadIdx.x >> 6;
    int lane = threadIdx.x & 63;
    int i = blockIdx.x * 4 + wave;
    if (i >= BATCH_C) return;

    int un = uid[i];
    int pe = pid[i];
    int ne = nid[i];
    int pn = N_USERS + pe;
    int nn = N_USERS + ne;

    float acc01p, acc01n;
    {
        float u  = uw[(size_t)un * 64 + lane];
        float pv = ew[(size_t)pe * 64 + lane];
        float nv = ew[(size_t)ne * 64 + lane];
        acc01p = u * pv;
        acc01n = u * nv;
        float u1 = __bfloat162float(h1[(size_t)un * 64 + lane]);
        acc01p += u1 * __bfloat162float(h1[(size_t)pn * 64 + lane]);
        acc01n += u1 * __bfloat162float(h1[(size_t)nn * 64 + lane]);
    }

    float h2u = layer2_row(h1, row_ptr, edges, sW1, sW2, sb, un, lane);
    float h2p = layer2_row(h1, row_ptr, edges, sW1, sW2, sb, pn, lane);
    float h2n = layer2_row(h1, row_ptr, edges, sW1, sW2, sb, nn, lane);
    float p2 = h2u * h2p;
    float n2 = h2u * h2n;
    #pragma unroll
    for (int m = 1; m < 32; m <<= 1) { p2 += __shfl_xor(p2, m); n2 += __shfl_xor(n2, m); }

    #pragma unroll
    for (int m = 1; m < 64; m <<= 1) { acc01p += __shfl_xor(acc01p, m); acc01n += __shfl_xor(acc01n, m); }

    if (lane == 0) {
        out[i]           = acc01p + p2;
        out[BATCH_C + i] = acc01n + n2;
    }
}

extern "C" void kernel_launch(void* const* d_in, const int* in_sizes, int n_in,
                              void* d_out, int out_size, void* d_ws, size_t ws_size,
                              hipStream_t stream) {
    const float* uw   = (const float*)d_in[0];
    const float* ew   = (const float*)d_in[1];
    const float* W1a  = (const float*)d_in[2];
    const float* b1a  = (const float*)d_in[3];
    const float* W2a  = (const float*)d_in[4];
    const float* b2a  = (const float*)d_in[5];
    const float* W1b  = (const float*)d_in[6];
    const float* b1b  = (const float*)d_in[7];
    const float* W2b  = (const float*)d_in[8];
    const float* b2b  = (const float*)d_in[9];
    const float* values   = (const float*)d_in[10];
    const int*   target   = (const int*)d_in[11];
    const int*   neighbor = (const int*)d_in[12];
    const int*   uid  = (const int*)d_in[13];
    const int*   pid  = (const int*)d_in[14];
    const int*   nid  = (const int*)d_in[15];

    const int n_edges = in_sizes[10];

    char* ws = (char*)d_ws;
    int*  counts     = (int*)ws;   ws += 801792;          // 200192*4 padded
    int*  row_ptr    = (int*)ws;   ws += 801792;
    int*  cursor     = (int*)ws;   ws += 801792;
    int*  block_sums = (int*)ws;   ws += 4096;
    int*  block_offs = (int*)ws;   ws += 4096;
    unsigned int*   edges = (unsigned int*)ws;   ws += (size_t)N_EDGES_C * 4;      // 12.8 MB
    unsigned short* fb    = (unsigned short*)ws; ws += (size_t)N_NODES_C * 64 * 2; // 25.6 MB
    __hip_bfloat16* h1    = (__hip_bfloat16*)ws;          // 25.6 MB

    const int edge_blocks  = (n_edges + 255) / 256;
    const int layer_blocks = (N_NODES_C + 3) / 4;
    const int conv_blocks  = (N_NODES_C * 64 + 255) / 256;

    // ----- bf16 feature table + CSR build (shared by both layers) -----
    hipMemsetAsync(counts, 0, (size_t)N_NODES_C * sizeof(int), stream);
    tobf16_k<<<conv_blocks, 256, 0, stream>>>(uw, ew, fb);
    hist_k<<<edge_blocks, 256, 0, stream>>>(target, counts, n_edges);
    partial_k<<<SCAN_BLK, 256, 0, stream>>>(counts, block_sums);
    scansums_k<<<1, 1024, 0, stream>>>(block_sums, block_offs);
    finalize_k<<<SCAN_BLK, 256, 0, stream>>>(counts, block_offs, row_ptr, cursor, n_edges);
    scatter_k<<<edge_blocks, 256, 0, stream>>>(target, neighbor, values, cursor, edges, n_edges);

    // ----- layer 1 (quad-gather pull + transform fused) -----
    layer1_pull_k<<<layer_blocks, 256, 0, stream>>>(fb, row_ptr, edges,
                                                    W1a, b1a, W2a, b2a, h1, N_NODES_C);

    // ----- scoring (layer-2 aggregation + transform inline, only ~12K nodes) -----
    score_k<<<BATCH_C / 4, 256, 0, stream>>>(uw, ew, h1, row_ptr, edges,
                                             W1b, b1b, W2b, b2b,
                                             uid, pid, nid, (float*)d_out);
}

// Round 8
// 737.134 us; speedup vs baseline: 2.6475x; 1.0264x over previous
//
#include <hip/hip_runtime.h>
#include <hip/hip_bf16.h>

#define N_USERS    50000
#define N_ENTITIES 150000
#define N_NODES_C  200000
#define BATCH_C    4096
#define N_EDGES_C  3200000
#define SCAN_BLK   782          // ceil(200000/256)

typedef __attribute__((ext_vector_type(8))) short short8;
typedef __attribute__((ext_vector_type(4))) float float4v;

// Workspace layout (~66 MB; proven safe; overrun corrupts harness pristine
// copies => first call right, replays wrong):
//   counts     : int    [200192]       0.8 MB
//   row_ptr    : int    [200001+pad]   0.8 MB
//   cursor     : int    [200192]       0.8 MB
//   block_sums : int    [1024]         4 KB
//   block_offs : int    [1024]         4 KB
//   edges      : uint   [3.2M]        12.8 MB  (nb<<14 | val_q14, sorted by target)
//   fb16       : ushort [200000*64]   25.6 MB  (bf16 bits of concat(uw,ew))
//   h1         : bf16   [200000*64]   25.6 MB

__device__ __forceinline__ unsigned short f32_to_bf16_bits(float x) {
    unsigned u = __float_as_uint(x);
    unsigned r = (u + 0x7fffu + ((u >> 16) & 1u)) >> 16;   // RNE
    return (unsigned short)r;
}

// ---------- bf16 node-feature table ----------
__global__ __launch_bounds__(256) void tobf16_k(const float* __restrict__ uw,
                                                const float* __restrict__ ew,
                                                unsigned short* __restrict__ fb)
{
    int idx = blockIdx.x * 256 + threadIdx.x;      // 12.8M elements
    if (idx >= N_NODES_C * 64) return;
    const int split = N_USERS * 64;
    float x = (idx < split) ? uw[idx] : ew[idx - split];
    fb[idx] = f32_to_bf16_bits(x);
}

// ---------- CSR build ----------
__global__ __launch_bounds__(256) void hist_k(const int* __restrict__ target,
                                              int* __restrict__ counts, int n_edges)
{
    int e = blockIdx.x * 256 + threadIdx.x;
    if (e < n_edges) atomicAdd(&counts[target[e]], 1);
}

__global__ __launch_bounds__(256) void partial_k(const int* __restrict__ counts,
                                                 int* __restrict__ block_sums)
{
    __shared__ int red[256];
    int gid = blockIdx.x * 256 + threadIdx.x;
    int c = (gid < N_NODES_C) ? counts[gid] : 0;
    red[threadIdx.x] = c;
    __syncthreads();
    for (int off = 128; off > 0; off >>= 1) {
        if (threadIdx.x < off) red[threadIdx.x] += red[threadIdx.x + off];
        __syncthreads();
    }
    if (threadIdx.x == 0) block_sums[blockIdx.x] = red[0];
}

__global__ __launch_bounds__(1024) void scansums_k(const int* __restrict__ block_sums,
                                                   int* __restrict__ block_offs)
{
    __shared__ int part[1024];
    int t = threadIdx.x;
    int v = (t < SCAN_BLK) ? block_sums[t] : 0;
    part[t] = v;
    __syncthreads();
    for (int off = 1; off < 1024; off <<= 1) {
        int w = (t >= off) ? part[t - off] : 0;
        __syncthreads();
        part[t] += w;
        __syncthreads();
    }
    if (t < SCAN_BLK) block_offs[t] = part[t] - v;   // exclusive
}

__global__ __launch_bounds__(256) void finalize_k(const int* __restrict__ counts,
                                                  const int* __restrict__ block_offs,
                                                  int* __restrict__ row_ptr,
                                                  int* __restrict__ cursor, int n_edges)
{
    __shared__ int wsum[4];
    int gid  = blockIdx.x * 256 + threadIdx.x;
    int lane = threadIdx.x & 63;
    int wave = threadIdx.x >> 6;
    int c = (gid < N_NODES_C) ? counts[gid] : 0;

    int s = c;
    #pragma unroll
    for (int off = 1; off < 64; off <<= 1) {
        int v = __shfl_up(s, off);
        if (lane >= off) s += v;
    }
    if (lane == 63) wsum[wave] = s;
    __syncthreads();
    int woff = 0;
    #pragma unroll
    for (int w = 0; w < 4; w++) woff += (w < wave) ? wsum[w] : 0;

    int excl = block_offs[blockIdx.x] + woff + (s - c);
    if (gid < N_NODES_C) {
        row_ptr[gid] = excl;
        cursor[gid]  = excl;
    }
    if (gid == 0) row_ptr[N_NODES_C] = n_edges;
}

// packed edge: nb (18 bits) << 14 | val quantized to 14-bit fixed point.
__global__ __launch_bounds__(256) void scatter_k(
    const int* __restrict__ target, const int* __restrict__ neighbor,
    const float* __restrict__ values, int* __restrict__ cursor,
    unsigned int* __restrict__ edges, int n_edges)
{
    int e = blockIdx.x * 256 + threadIdx.x;
    if (e >= n_edges) return;
    int t   = target[e];
    int pos = atomicAdd(&cursor[t], 1);
    unsigned q = (unsigned)fminf(values[e] * 16384.f + 0.5f, 16383.f);
    edges[pos] = ((unsigned)neighbor[e] << 14) | q;
}

// ---------- layer 1: quad-gather CSR pull + MFMA dense transform ----------
// Block = 4 waves = 64 nodes. Wave w owns nodes [w*16, w*16+16):
//  phase A: per node, quad-gather pull (4 edges per uint2 load inst), then
//           write the packed [s(64) | p(64)] bf16 row into LDS sp[m][k].
//  phase B: strip GEMM C[16x64] = sp_strip[16x128] @ Wcat[128x64] + bias
//           via 16x mfma_f32_16x16x32_bf16 (A from sp, B from transposed
//           Wt[n][k] in LDS), then leaky + row-l2norm epilogue.
// Layouts (HW-verified per guide): A[m=lane&15][k=(lane>>4)*8+j],
// B[k=(lane>>4)*8+j][n=lane&15], C/D col=lane&15, row=(lane>>4)*4+reg.
// Stride 136 shorts keeps b128 reads 16B-aligned, same-quad lanes 2-way max.
#define SPS 136
__global__ __launch_bounds__(256, 4) void layer1_pull_k(
    const unsigned short* __restrict__ fb,
    const int* __restrict__ row_ptr, const unsigned int* __restrict__ edges,
    const float* __restrict__ W1, const float* __restrict__ b1,
    const float* __restrict__ W2, const float* __restrict__ b2,
    __hip_bfloat16* __restrict__ h1out, int n_nodes)
{
    __shared__ __align__(16) short wt[64 * SPS];   // Wt[n][k]: k<64 W1, k>=64 W2
    __shared__ __align__(16) short sp[64 * SPS];   // sp[m][k]: k<64 s, k>=64 p
    __shared__ float sbias[64];

    // build transposed bf16 weight tile (coalesced global reads)
    for (int idx = threadIdx.x; idx < 64 * 64; idx += 256) {
        int kp = idx >> 6;            // k-pair: k = 2kp, 2kp+1
        int n  = idx & 63;
        int k0 = kp * 2, k1 = k0 + 1;
        float w0 = (k0 < 64) ? W1[k0 * 64 + n] : W2[(k0 - 64) * 64 + n];
        float w1 = (k1 < 64) ? W1[k1 * 64 + n] : W2[(k1 - 64) * 64 + n];
        *(unsigned*)&wt[n * SPS + k0] =
            ((unsigned)f32_to_bf16_bits(w1) << 16) | f32_to_bf16_bits(w0);
    }
    if (threadIdx.x < 64) sbias[threadIdx.x] = b1[threadIdx.x] + b2[threadIdx.x];
    __syncthreads();

    int wv   = threadIdx.x >> 6;
    int lane = threadIdx.x & 63;
    int g    = lane >> 4;           // quad / edge-group 0..3
    int q    = lane & 15;           // dim-quad (dims 4q..4q+3) / tile col
    const uint2* fb2 = (const uint2*)fb;

    int nb0 = blockIdx.x * 64;      // 3125 blocks x 64 = exactly 200000

    // ----- phase A: pull 16 nodes, write sp rows (same-wave consume later) -----
    const float QS = 1.f / 16384.f;
    for (int i = 0; i < 16; i++) {
        int m    = wv * 16 + i;
        int node = nb0 + m;
        int es = row_ptr[node];
        int ee = row_ptr[node + 1];

        float h0 = 0.f, h1a = 0.f, h2a = 0.f, h3a = 0.f;
        for (int base = es; base < ee; base += 64) {
            int cnt = min(64, ee - base);
            unsigned ev = (lane < cnt) ? edges[base + lane] : 0u;   // 0 => val 0
            int jmax = (cnt + 3) >> 2;
            #pragma unroll 4
            for (int j = 0; j < jmax; j++) {
                unsigned w = (unsigned)__shfl((int)ev, j * 4 + g);
                float v = (float)(w & 16383u) * QS;
                uint2 d = fb2[(size_t)(w >> 14) * 16 + q];
                h0  += v * __uint_as_float(d.x << 16);
                h1a += v * __uint_as_float(d.x & 0xffff0000u);
                h2a += v * __uint_as_float(d.y << 16);
                h3a += v * __uint_as_float(d.y & 0xffff0000u);
            }
        }
        #pragma unroll
        for (int mm = 16; mm < 64; mm <<= 1) {
            h0  += __shfl_xor(h0, mm);
            h1a += __shfl_xor(h1a, mm);
            h2a += __shfl_xor(h2a, mm);
            h3a += __shfl_xor(h3a, mm);
        }

        uint2 dself = fb2[(size_t)node * 16 + q];
        float f0 = __uint_as_float(dself.x << 16);
        float f1 = __uint_as_float(dself.x & 0xffff0000u);
        float f2 = __uint_as_float(dself.y << 16);
        float f3 = __uint_as_float(dself.y & 0xffff0000u);

        if (g < 2) {   // g0 writes s-quad, g1 writes p-quad (values replicated)
            float a0 = (g == 0) ? f0 + h0  : f0 * h0;
            float a1 = (g == 0) ? f1 + h1a : f1 * h1a;
            float a2 = (g == 0) ? f2 + h2a : f2 * h2a;
            float a3 = (g == 0) ? f3 + h3a : f3 * h3a;
            uint2 pk;
            pk.x = ((unsigned)f32_to_bf16_bits(a1) << 16) | f32_to_bf16_bits(a0);
            pk.y = ((unsigned)f32_to_bf16_bits(a3) << 16) | f32_to_bf16_bits(a2);
            *(uint2*)&sp[m * SPS + g * 64 + q * 4] = pk;
        }
    }

    // ----- phase B: strip GEMM (16 nodes x 64 outs, K=128) -----
    float4v c0, c1, c2, c3;
    {
        float bv0 = sbias[q];
        float bv1 = sbias[16 + q];
        float bv2 = sbias[32 + q];
        float bv3 = sbias[48 + q];
        c0 = (float4v){bv0, bv0, bv0, bv0};
        c1 = (float4v){bv1, bv1, bv1, bv1};
        c2 = (float4v){bv2, bv2, bv2, bv2};
        c3 = (float4v){bv3, bv3, bv3, bv3};
    }
    #pragma unroll
    for (int kk = 0; kk < 4; kk++) {
        int ko = kk * 32 + g * 8;
        short8 a = *(const short8*)&sp[(wv * 16 + q) * SPS + ko];
        short8 bb0 = *(const short8*)&wt[(q)      * SPS + ko];
        short8 bb1 = *(const short8*)&wt[(16 + q) * SPS + ko];
        short8 bb2 = *(const short8*)&wt[(32 + q) * SPS + ko];
        short8 bb3 = *(const short8*)&wt[(48 + q) * SPS + ko];
        c0 = __builtin_amdgcn_mfma_f32_16x16x32_bf16(a, bb0, c0, 0, 0, 0);
        c1 = __builtin_amdgcn_mfma_f32_16x16x32_bf16(a, bb1, c1, 0, 0, 0);
        c2 = __builtin_amdgcn_mfma_f32_16x16x32_bf16(a, bb2, c2, 0, 0, 0);
        c3 = __builtin_amdgcn_mfma_f32_16x16x32_bf16(a, bb3, c3, 0, 0, 0);
    }

    // epilogue: leaky, per-row l2norm (row = g*4 + r, cols spread over 16 lanes x 4 tiles)
    float ss[4];
    #pragma unroll
    for (int r = 0; r < 4; r++) {
        c0[r] = (c0[r] > 0.f) ? c0[r] : 0.01f * c0[r];
        c1[r] = (c1[r] > 0.f) ? c1[r] : 0.01f * c1[r];
        c2[r] = (c2[r] > 0.f) ? c2[r] : 0.01f * c2[r];
        c3[r] = (c3[r] > 0.f) ? c3[r] : 0.01f * c3[r];
        ss[r] = c0[r]*c0[r] + c1[r]*c1[r] + c2[r]*c2[r] + c3[r]*c3[r];
        #pragma unroll
        for (int mm = 1; mm < 16; mm <<= 1) ss[r] += __shfl_xor(ss[r], mm);
        ss[r] = 1.f / fmaxf(sqrtf(ss[r]), 1e-12f);
    }
    #pragma unroll
    for (int r = 0; r < 4; r++) {
        size_t row = (size_t)(nb0 + wv * 16 + g * 4 + r) * 64;
        h1out[row +      q] = __float2bfloat16(c0[r] * ss[r]);
        h1out[row + 16 + q] = __float2bfloat16(c1[r] * ss[r]);
        h1out[row + 32 + q] = __float2bfloat16(c2[r] * ss[r]);
        h1out[row + 48 + q] = __float2bfloat16(c3[r] * ss[r]);
    }
}

// ---------- inline layer2 (64->32) for one node, aggregation pulled on the fly ----------
__device__ __forceinline__ float layer2_row(
    const __hip_bfloat16* __restrict__ h1,
    const int* __restrict__ row_ptr, const unsigned int* __restrict__ edges,
    const float* sW1, const float* sW2, const float* sb,
    int node, int lane)
{
    int es = row_ptr[node];
    int ee = row_ptr[node + 1];
    const float QS = 1.f / 16384.f;
    float g = 0.f;
    for (int base = es; base < ee; base += 64) {
        int cnt = min(64, ee - base);
        unsigned ev = (lane < cnt) ? edges[base + lane] : 0u;
        int j = 0;
        for (; j + 4 <= cnt; j += 4) {
            unsigned e0 = (unsigned)__shfl((int)ev, j);
            unsigned e1 = (unsigned)__shfl((int)ev, j + 1);
            unsigned e2 = (unsigned)__shfl((int)ev, j + 2);
            unsigned e3 = (unsigned)__shfl((int)ev, j + 3);
            float f0 = __bfloat162float(h1[(size_t)(e0 >> 14) * 64 + lane]);
            float f1 = __bfloat162float(h1[(size_t)(e1 >> 14) * 64 + lane]);
            float f2 = __bfloat162float(h1[(size_t)(e2 >> 14) * 64 + lane]);
            float f3 = __bfloat162float(h1[(size_t)(e3 >> 14) * 64 + lane]);
            g += (float)(e0 & 16383u) * QS * f0 + (float)(e1 & 16383u) * QS * f1
               + (float)(e2 & 16383u) * QS * f2 + (float)(e3 & 16383u) * QS * f3;
        }
        for (; j < cnt; j++) {
            unsigned e0 = (unsigned)__shfl((int)ev, j);
            float f0 = __bfloat162float(h1[(size_t)(e0 >> 14) * 64 + lane]);
            g += (float)(e0 & 16383u) * QS * f0;
        }
    }
    float f = __bfloat162float(h1[(size_t)node * 64 + lane]);
    float s = f + g;
    float p = f * g;
    int j = lane & 31;
    float acc = sb[j];
    #pragma unroll
    for (int k = 0; k < 64; k++) {
        float sk = __shfl(s, k);
        float pk = __shfl(p, k);
        acc += sk * sW1[k * 32 + j] + pk * sW2[k * 32 + j];
    }
    acc = (acc > 0.f) ? acc : 0.01f * acc;
    float sq = acc * acc;
    #pragma unroll
    for (int m = 1; m < 32; m <<= 1) sq += __shfl_xor(sq, m);  // within 32-half
    return acc / fmaxf(sqrtf(sq), 1e-12f);
}

__global__ __launch_bounds__(256) void score_k(
    const float* __restrict__ uw, const float* __restrict__ ew,
    const __hip_bfloat16* __restrict__ h1,
    const int* __restrict__ row_ptr, const unsigned int* __restrict__ edges,
    const float* __restrict__ W1b, const float* __restrict__ b1b,
    const float* __restrict__ W2b, const float* __restrict__ b2b,
    const int* __restrict__ uid, const int* __restrict__ pid,
    const int* __restrict__ nid, float* __restrict__ out)
{
    __shared__ float sW1[64 * 32];
    __shared__ float sW2[64 * 32];
    __shared__ float sb[32];
    for (int i = threadIdx.x; i < 64 * 32; i += 256) { sW1[i] = W1b[i]; sW2[i] = W2b[i]; }
    if (threadIdx.x < 32) sb[threadIdx.x] = b1b[threadIdx.x] + b2b[threadIdx.x];
    __syncthreads();

    int wave = threadIdx.x >> 6;
    int lane = threadIdx.x & 63;
    int i = blockIdx.x * 4 + wave;
    if (i >= BATCH_C) return;

    int un = uid[i];
    int pe = pid[i];
    int ne = nid[i];
    int pn = N_USERS + pe;
    int nn = N_USERS + ne;

    float acc01p, acc01n;
    {
        float u  = uw[(size_t)un * 64 + lane];
        float pv = ew[(size_t)pe * 64 + lane];
        float nv = ew[(size_t)ne * 64 + lane];
        acc01p = u * pv;
        acc01n = u * nv;
        float u1 = __bfloat162float(h1[(size_t)un * 64 + lane]);
        acc01p += u1 * __bfloat162float(h1[(size_t)pn * 64 + lane]);
        acc01n += u1 * __bfloat162float(h1[(size_t)nn * 64 + lane]);
    }

    float h2u = layer2_row(h1, row_ptr, edges, sW1, sW2, sb, un, lane);
    float h2p = layer2_row(h1, row_ptr, edges, sW1, sW2, sb, pn, lane);
    float h2n = layer2_row(h1, row_ptr, edges, sW1, sW2, sb, nn, lane);
    float p2 = h2u * h2p;
    float n2 = h2u * h2n;
    #pragma unroll
    for (int m = 1; m < 32; m <<= 1) { p2 += __shfl_xor(p2, m); n2 += __shfl_xor(n2, m); }

    #pragma unroll
    for (int m = 1; m < 64; m <<= 1) { acc01p += __shfl_xor(acc01p, m); acc01n += __shfl_xor(acc01n, m); }

    if (lane == 0) {
        out[i]           = acc01p + p2;
        out[BATCH_C + i] = acc01n + n2;
    }
}

extern "C" void kernel_launch(void* const* d_in, const int* in_sizes, int n_in,
                              void* d_out, int out_size, void* d_ws, size_t ws_size,
                              hipStream_t stream) {
    const float* uw   = (const float*)d_in[0];
    const float* ew   = (const float*)d_in[1];
    const float* W1a  = (const float*)d_in[2];
    const float* b1a  = (const float*)d_in[3];
    const float* W2a  = (const float*)d_in[4];
    const float* b2a  = (const float*)d_in[5];
    const float* W1b  = (const float*)d_in[6];
    const float* b1b  = (const float*)d_in[7];
    const float* W2b  = (const float*)d_in[8];
    const float* b2b  = (const float*)d_in[9];
    const float* values   = (const float*)d_in[10];
    const int*   target   = (const int*)d_in[11];
    const int*   neighbor = (const int*)d_in[12];
    const int*   uid  = (const int*)d_in[13];
    const int*   pid  = (const int*)d_in[14];
    const int*   nid  = (const int*)d_in[15];

    const int n_edges = in_sizes[10];

    char* ws = (char*)d_ws;
    int*  counts     = (int*)ws;   ws += 801792;          // 200192*4 padded
    int*  row_ptr    = (int*)ws;   ws += 801792;
    int*  cursor     = (int*)ws;   ws += 801792;
    int*  block_sums = (int*)ws;   ws += 4096;
    int*  block_offs = (int*)ws;   ws += 4096;
    unsigned int*   edges = (unsigned int*)ws;   ws += (size_t)N_EDGES_C * 4;      // 12.8 MB
    unsigned short* fb    = (unsigned short*)ws; ws += (size_t)N_NODES_C * 64 * 2; // 25.6 MB
    __hip_bfloat16* h1    = (__hip_bfloat16*)ws;          // 25.6 MB

    const int edge_blocks  = (n_edges + 255) / 256;
    const int layer_blocks = N_NODES_C / 64;              // 3125, exact
    const int conv_blocks  = (N_NODES_C * 64 + 255) / 256;

    // ----- bf16 feature table + CSR build (shared by both layers) -----
    hipMemsetAsync(counts, 0, (size_t)N_NODES_C * sizeof(int), stream);
    tobf16_k<<<conv_blocks, 256, 0, stream>>>(uw, ew, fb);
    hist_k<<<edge_blocks, 256, 0, stream>>>(target, counts, n_edges);
    partial_k<<<SCAN_BLK, 256, 0, stream>>>(counts, block_sums);
    scansums_k<<<1, 1024, 0, stream>>>(block_sums, block_offs);
    finalize_k<<<SCAN_BLK, 256, 0, stream>>>(counts, block_offs, row_ptr, cursor, n_edges);
    scatter_k<<<edge_blocks, 256, 0, stream>>>(target, neighbor, values, cursor, edges, n_edges);

    // ----- layer 1 (quad-gather pull + MFMA transform fused) -----
    layer1_pull_k<<<layer_blocks, 256, 0, stream>>>(fb, row_ptr, edges,
                                                    W1a, b1a, W2a, b2a, h1, N_NODES_C);

    // ----- scoring (layer-2 aggregation + transform inline, only ~12K nodes) -----
    score_k<<<BATCH_C / 4, 256, 0, stream>>>(uw, ew, h1, row_ptr, edges,
                                             W1b, b1b, W2b, b2b,
                                             uid, pid, nid, (float*)d_out);
}

// Round 9
// 704.398 us; speedup vs baseline: 2.7705x; 1.0465x over previous
//
#include <hip/hip_runtime.h>
#include <hip/hip_bf16.h>

#define N_USERS    50000
#define N_ENTITIES 150000
#define N_NODES_C  200000
#define BATCH_C    4096
#define N_EDGES_C  3200000
#define SCAN_BLK   782          // ceil(200000/256)
#define SCAT_PASS  8            // range passes; write span/pass ~1.6 MB (L2-resident)

typedef __attribute__((ext_vector_type(8))) short short8;
typedef __attribute__((ext_vector_type(4))) float float4v;

// Workspace layout (~66 MB; proven safe; overrun corrupts harness pristine
// copies => first call right, replays wrong):
//   counts     : int    [200192]       0.8 MB
//   row_ptr    : int    [200001+pad]   0.8 MB
//   cursor     : int    [200192]       0.8 MB
//   block_sums : int    [1024]         4 KB
//   block_offs : int    [1024]         4 KB
//   edges      : uint   [3.2M]        12.8 MB  (nb<<14 | val_q14, sorted by target)
//   fb16       : ushort [200000*64]   25.6 MB  (bf16 bits of concat(uw,ew))
//   h1         : bf16   [200000*64]   25.6 MB

__device__ __forceinline__ unsigned short f32_to_bf16_bits(float x) {
    unsigned u = __float_as_uint(x);
    unsigned r = (u + 0x7fffu + ((u >> 16) & 1u)) >> 16;   // RNE
    return (unsigned short)r;
}

// ---------- bf16 node-feature table ----------
__global__ __launch_bounds__(256) void tobf16_k(const float* __restrict__ uw,
                                                const float* __restrict__ ew,
                                                unsigned short* __restrict__ fb)
{
    int idx = blockIdx.x * 256 + threadIdx.x;      // 12.8M elements
    if (idx >= N_NODES_C * 64) return;
    const int split = N_USERS * 64;
    float x = (idx < split) ? uw[idx] : ew[idx - split];
    fb[idx] = f32_to_bf16_bits(x);
}

// ---------- CSR build ----------
__global__ __launch_bounds__(256) void hist_k(const int* __restrict__ target,
                                              int* __restrict__ counts, int n_edges)
{
    int e = blockIdx.x * 256 + threadIdx.x;
    if (e < n_edges) atomicAdd(&counts[target[e]], 1);
}

__global__ __launch_bounds__(256) void partial_k(const int* __restrict__ counts,
                                                 int* __restrict__ block_sums)
{
    __shared__ int red[256];
    int gid = blockIdx.x * 256 + threadIdx.x;
    int c = (gid < N_NODES_C) ? counts[gid] : 0;
    red[threadIdx.x] = c;
    __syncthreads();
    for (int off = 128; off > 0; off >>= 1) {
        if (threadIdx.x < off) red[threadIdx.x] += red[threadIdx.x + off];
        __syncthreads();
    }
    if (threadIdx.x == 0) block_sums[blockIdx.x] = red[0];
}

__global__ __launch_bounds__(1024) void scansums_k(const int* __restrict__ block_sums,
                                                   int* __restrict__ block_offs)
{
    __shared__ int part[1024];
    int t = threadIdx.x;
    int v = (t < SCAN_BLK) ? block_sums[t] : 0;
    part[t] = v;
    __syncthreads();
    for (int off = 1; off < 1024; off <<= 1) {
        int w = (t >= off) ? part[t - off] : 0;
        __syncthreads();
        part[t] += w;
        __syncthreads();
    }
    if (t < SCAN_BLK) block_offs[t] = part[t] - v;   // exclusive
}

__global__ __launch_bounds__(256) void finalize_k(const int* __restrict__ counts,
                                                  const int* __restrict__ block_offs,
                                                  int* __restrict__ row_ptr,
                                                  int* __restrict__ cursor, int n_edges)
{
    __shared__ int wsum[4];
    int gid  = blockIdx.x * 256 + threadIdx.x;
    int lane = threadIdx.x & 63;
    int wave = threadIdx.x >> 6;
    int c = (gid < N_NODES_C) ? counts[gid] : 0;

    int s = c;
    #pragma unroll
    for (int off = 1; off < 64; off <<= 1) {
        int v = __shfl_up(s, off);
        if (lane >= off) s += v;
    }
    if (lane == 63) wsum[wave] = s;
    __syncthreads();
    int woff = 0;
    #pragma unroll
    for (int w = 0; w < 4; w++) woff += (w < wave) ? wsum[w] : 0;

    int excl = block_offs[blockIdx.x] + woff + (s - c);
    if (gid < N_NODES_C) {
        row_ptr[gid] = excl;
        cursor[gid]  = excl;
    }
    if (gid == 0) row_ptr[N_NODES_C] = n_edges;
}

// packed edge: nb (18 bits) << 14 | val quantized to 14-bit fixed point.
// Range pass [lo,hi): only scatter edges targeting this node range, so the
// active write window is ~1.6 MB (L2-resident -> lines fill before eviction).
__global__ __launch_bounds__(256) void scatter_k(
    const int* __restrict__ target, const int* __restrict__ neighbor,
    const float* __restrict__ values, int* __restrict__ cursor,
    unsigned int* __restrict__ edges, int n_edges, int lo, int hi)
{
    int e = blockIdx.x * 256 + threadIdx.x;
    if (e >= n_edges) return;
    int t = target[e];
    if (t < lo || t >= hi) return;
    int pos = atomicAdd(&cursor[t], 1);
    unsigned q = (unsigned)fminf(values[e] * 16384.f + 0.5f, 16383.f);
    edges[pos] = ((unsigned)neighbor[e] << 14) | q;
}

// ---------- layer 1: quad-gather CSR pull + MFMA dense transform ----------
// Block = 4 waves = 64 nodes. Wave w owns nodes [w*16, w*16+16):
//  phase A: per node, quad-gather pull (4 edges per uint2 load inst), then
//           write the packed [s(64) | p(64)] bf16 row into LDS sp[m][k].
//  phase B: strip GEMM C[16x64] = sp_strip[16x128] @ Wcat[128x64] + bias
//           via 16x mfma_f32_16x16x32_bf16, then leaky + row-l2norm epilogue.
// Layouts (HW-verified per guide): A[m=lane&15][k=(lane>>4)*8+j],
// B[k=(lane>>4)*8+j][n=lane&15], C/D col=lane&15, row=(lane>>4)*4+reg.
#define SPS 136
__global__ __launch_bounds__(256, 4) void layer1_pull_k(
    const unsigned short* __restrict__ fb,
    const int* __restrict__ row_ptr, const unsigned int* __restrict__ edges,
    const float* __restrict__ W1, const float* __restrict__ b1,
    const float* __restrict__ W2, const float* __restrict__ b2,
    __hip_bfloat16* __restrict__ h1out, int n_nodes)
{
    __shared__ __align__(16) short wt[64 * SPS];   // Wt[n][k]: k<64 W1, k>=64 W2
    __shared__ __align__(16) short sp[64 * SPS];   // sp[m][k]: k<64 s, k>=64 p
    __shared__ float sbias[64];

    for (int idx = threadIdx.x; idx < 64 * 64; idx += 256) {
        int kp = idx >> 6;
        int n  = idx & 63;
        int k0 = kp * 2, k1 = k0 + 1;
        float w0 = (k0 < 64) ? W1[k0 * 64 + n] : W2[(k0 - 64) * 64 + n];
        float w1 = (k1 < 64) ? W1[k1 * 64 + n] : W2[(k1 - 64) * 64 + n];
        *(unsigned*)&wt[n * SPS + k0] =
            ((unsigned)f32_to_bf16_bits(w1) << 16) | f32_to_bf16_bits(w0);
    }
    if (threadIdx.x < 64) sbias[threadIdx.x] = b1[threadIdx.x] + b2[threadIdx.x];
    __syncthreads();

    int wv   = threadIdx.x >> 6;
    int lane = threadIdx.x & 63;
    int g    = lane >> 4;
    int q    = lane & 15;
    const uint2* fb2 = (const uint2*)fb;

    int nb0 = blockIdx.x * 64;

    const float QS = 1.f / 16384.f;
    for (int i = 0; i < 16; i++) {
        int m    = wv * 16 + i;
        int node = nb0 + m;
        int es = row_ptr[node];
        int ee = row_ptr[node + 1];

        float h0 = 0.f, h1a = 0.f, h2a = 0.f, h3a = 0.f;
        for (int base = es; base < ee; base += 64) {
            int cnt = min(64, ee - base);
            unsigned ev = (lane < cnt) ? edges[base + lane] : 0u;
            int jmax = (cnt + 3) >> 2;
            #pragma unroll 4
            for (int j = 0; j < jmax; j++) {
                unsigned w = (unsigned)__shfl((int)ev, j * 4 + g);
                float v = (float)(w & 16383u) * QS;
                uint2 d = fb2[(size_t)(w >> 14) * 16 + q];
                h0  += v * __uint_as_float(d.x << 16);
                h1a += v * __uint_as_float(d.x & 0xffff0000u);
                h2a += v * __uint_as_float(d.y << 16);
                h3a += v * __uint_as_float(d.y & 0xffff0000u);
            }
        }
        #pragma unroll
        for (int mm = 16; mm < 64; mm <<= 1) {
            h0  += __shfl_xor(h0, mm);
            h1a += __shfl_xor(h1a, mm);
            h2a += __shfl_xor(h2a, mm);
            h3a += __shfl_xor(h3a, mm);
        }

        uint2 dself = fb2[(size_t)node * 16 + q];
        float f0 = __uint_as_float(dself.x << 16);
        float f1 = __uint_as_float(dself.x & 0xffff0000u);
        float f2 = __uint_as_float(dself.y << 16);
        float f3 = __uint_as_float(dself.y & 0xffff0000u);

        if (g < 2) {
            float a0 = (g == 0) ? f0 + h0  : f0 * h0;
            float a1 = (g == 0) ? f1 + h1a : f1 * h1a;
            float a2 = (g == 0) ? f2 + h2a : f2 * h2a;
            float a3 = (g == 0) ? f3 + h3a : f3 * h3a;
            uint2 pk;
            pk.x = ((unsigned)f32_to_bf16_bits(a1) << 16) | f32_to_bf16_bits(a0);
            pk.y = ((unsigned)f32_to_bf16_bits(a3) << 16) | f32_to_bf16_bits(a2);
            *(uint2*)&sp[m * SPS + g * 64 + q * 4] = pk;
        }
    }

    float4v c0, c1, c2, c3;
    {
        float bv0 = sbias[q];
        float bv1 = sbias[16 + q];
        float bv2 = sbias[32 + q];
        float bv3 = sbias[48 + q];
        c0 = (float4v){bv0, bv0, bv0, bv0};
        c1 = (float4v){bv1, bv1, bv1, bv1};
        c2 = (float4v){bv2, bv2, bv2, bv2};
        c3 = (float4v){bv3, bv3, bv3, bv3};
    }
    #pragma unroll
    for (int kk = 0; kk < 4; kk++) {
        int ko = kk * 32 + g * 8;
        short8 a = *(const short8*)&sp[(wv * 16 + q) * SPS + ko];
        short8 bb0 = *(const short8*)&wt[(q)      * SPS + ko];
        short8 bb1 = *(const short8*)&wt[(16 + q) * SPS + ko];
        short8 bb2 = *(const short8*)&wt[(32 + q) * SPS + ko];
        short8 bb3 = *(const short8*)&wt[(48 + q) * SPS + ko];
        c0 = __builtin_amdgcn_mfma_f32_16x16x32_bf16(a, bb0, c0, 0, 0, 0);
        c1 = __builtin_amdgcn_mfma_f32_16x16x32_bf16(a, bb1, c1, 0, 0, 0);
        c2 = __builtin_amdgcn_mfma_f32_16x16x32_bf16(a, bb2, c2, 0, 0, 0);
        c3 = __builtin_amdgcn_mfma_f32_16x16x32_bf16(a, bb3, c3, 0, 0, 0);
    }

    float ss[4];
    #pragma unroll
    for (int r = 0; r < 4; r++) {
        c0[r] = (c0[r] > 0.f) ? c0[r] : 0.01f * c0[r];
        c1[r] = (c1[r] > 0.f) ? c1[r] : 0.01f * c1[r];
        c2[r] = (c2[r] > 0.f) ? c2[r] : 0.01f * c2[r];
        c3[r] = (c3[r] > 0.f) ? c3[r] : 0.01f * c3[r];
        ss[r] = c0[r]*c0[r] + c1[r]*c1[r] + c2[r]*c2[r] + c3[r]*c3[r];
        #pragma unroll
        for (int mm = 1; mm < 16; mm <<= 1) ss[r] += __shfl_xor(ss[r], mm);
        ss[r] = 1.f / fmaxf(sqrtf(ss[r]), 1e-12f);
    }
    #pragma unroll
    for (int r = 0; r < 4; r++) {
        size_t row = (size_t)(nb0 + wv * 16 + g * 4 + r) * 64;
        h1out[row +      q] = __float2bfloat16(c0[r] * ss[r]);
        h1out[row + 16 + q] = __float2bfloat16(c1[r] * ss[r]);
        h1out[row + 32 + q] = __float2bfloat16(c2[r] * ss[r]);
        h1out[row + 48 + q] = __float2bfloat16(c3[r] * ss[r]);
    }
}

// ---------- inline layer2 (64->32) for one node, aggregation pulled on the fly ----------
__device__ __forceinline__ float layer2_row(
    const __hip_bfloat16* __restrict__ h1,
    const int* __restrict__ row_ptr, const unsigned int* __restrict__ edges,
    const float* sW1, const float* sW2, const float* sb,
    int node, int lane)
{
    int es = row_ptr[node];
    int ee = row_ptr[node + 1];
    const float QS = 1.f / 16384.f;
    float g = 0.f;
    for (int base = es; base < ee; base += 64) {
        int cnt = min(64, ee - base);
        unsigned ev = (lane < cnt) ? edges[base + lane] : 0u;
        int j = 0;
        for (; j + 4 <= cnt; j += 4) {
            unsigned e0 = (unsigned)__shfl((int)ev, j);
            unsigned e1 = (unsigned)__shfl((int)ev, j + 1);
            unsigned e2 = (unsigned)__shfl((int)ev, j + 2);
            unsigned e3 = (unsigned)__shfl((int)ev, j + 3);
            float f0 = __bfloat162float(h1[(size_t)(e0 >> 14) * 64 + lane]);
            float f1 = __bfloat162float(h1[(size_t)(e1 >> 14) * 64 + lane]);
            float f2 = __bfloat162float(h1[(size_t)(e2 >> 14) * 64 + lane]);
            float f3 = __bfloat162float(h1[(size_t)(e3 >> 14) * 64 + lane]);
            g += (float)(e0 & 16383u) * QS * f0 + (float)(e1 & 16383u) * QS * f1
               + (float)(e2 & 16383u) * QS * f2 + (float)(e3 & 16383u) * QS * f3;
        }
        for (; j < cnt; j++) {
            unsigned e0 = (unsigned)__shfl((int)ev, j);
            float f0 = __bfloat162float(h1[(size_t)(e0 >> 14) * 64 + lane]);
            g += (float)(e0 & 16383u) * QS * f0;
        }
    }
    float f = __bfloat162float(h1[(size_t)node * 64 + lane]);
    float s = f + g;
    float p = f * g;
    int j = lane & 31;
    float acc = sb[j];
    #pragma unroll
    for (int k = 0; k < 64; k++) {
        float sk = __shfl(s, k);
        float pk = __shfl(p, k);
        acc += sk * sW1[k * 32 + j] + pk * sW2[k * 32 + j];
    }
    acc = (acc > 0.f) ? acc : 0.01f * acc;
    float sq = acc * acc;
    #pragma unroll
    for (int m = 1; m < 32; m <<= 1) sq += __shfl_xor(sq, m);  // within 32-half
    return acc / fmaxf(sqrtf(sq), 1e-12f);
}

__global__ __launch_bounds__(256) void score_k(
    const float* __restrict__ uw, const float* __restrict__ ew,
    const __hip_bfloat16* __restrict__ h1,
    const int* __restrict__ row_ptr, const unsigned int* __restrict__ edges,
    const float* __restrict__ W1b, const float* __restrict__ b1b,
    const float* __restrict__ W2b, const float* __restrict__ b2b,
    const int* __restrict__ uid, const int* __restrict__ pid,
    const int* __restrict__ nid, float* __restrict__ out)
{
    __shared__ float sW1[64 * 32];
    __shared__ float sW2[64 * 32];
    __shared__ float sb[32];
    for (int i = threadIdx.x; i < 64 * 32; i += 256) { sW1[i] = W1b[i]; sW2[i] = W2b[i]; }
    if (threadIdx.x < 32) sb[threadIdx.x] = b1b[threadIdx.x] + b2b[threadIdx.x];
    __syncthreads();

    int wave = threadIdx.x >> 6;
    int lane = threadIdx.x & 63;
    int i = blockIdx.x * 4 + wave;
    if (i >= BATCH_C) return;

    int un = uid[i];
    int pe = pid[i];
    int ne = nid[i];
    int pn = N_USERS + pe;
    int nn = N_USERS + ne;

    float acc01p, acc01n;
    {
        float u  = uw[(size_t)un * 64 + lane];
        float pv = ew[(size_t)pe * 64 + lane];
        float nv = ew[(size_t)ne * 64 + lane];
        acc01p = u * pv;
        acc01n = u * nv;
        float u1 = __bfloat162float(h1[(size_t)un * 64 + lane]);
        acc01p += u1 * __bfloat162float(h1[(size_t)pn * 64 + lane]);
        acc01n += u1 * __bfloat162float(h1[(size_t)nn * 64 + lane]);
    }

    float h2u = layer2_row(h1, row_ptr, edges, sW1, sW2, sb, un, lane);
    float h2p = layer2_row(h1, row_ptr, edges, sW1, sW2, sb, pn, lane);
    float h2n = layer2_row(h1, row_ptr, edges, sW1, sW2, sb, nn, lane);
    float p2 = h2u * h2p;
    float n2 = h2u * h2n;
    #pragma unroll
    for (int m = 1; m < 32; m <<= 1) { p2 += __shfl_xor(p2, m); n2 += __shfl_xor(n2, m); }

    #pragma unroll
    for (int m = 1; m < 64; m <<= 1) { acc01p += __shfl_xor(acc01p, m); acc01n += __shfl_xor(acc01n, m); }

    if (lane == 0) {
        out[i]           = acc01p + p2;
        out[BATCH_C + i] = acc01n + n2;
    }
}

extern "C" void kernel_launch(void* const* d_in, const int* in_sizes, int n_in,
                              void* d_out, int out_size, void* d_ws, size_t ws_size,
                              hipStream_t stream) {
    const float* uw   = (const float*)d_in[0];
    const float* ew   = (const float*)d_in[1];
    const float* W1a  = (const float*)d_in[2];
    const float* b1a  = (const float*)d_in[3];
    const float* W2a  = (const float*)d_in[4];
    const float* b2a  = (const float*)d_in[5];
    const float* W1b  = (const float*)d_in[6];
    const float* b1b  = (const float*)d_in[7];
    const float* W2b  = (const float*)d_in[8];
    const float* b2b  = (const float*)d_in[9];
    const float* values   = (const float*)d_in[10];
    const int*   target   = (const int*)d_in[11];
    const int*   neighbor = (const int*)d_in[12];
    const int*   uid  = (const int*)d_in[13];
    const int*   pid  = (const int*)d_in[14];
    const int*   nid  = (const int*)d_in[15];

    const int n_edges = in_sizes[10];

    char* ws = (char*)d_ws;
    int*  counts     = (int*)ws;   ws += 801792;          // 200192*4 padded
    int*  row_ptr    = (int*)ws;   ws += 801792;
    int*  cursor     = (int*)ws;   ws += 801792;
    int*  block_sums = (int*)ws;   ws += 4096;
    int*  block_offs = (int*)ws;   ws += 4096;
    unsigned int*   edges = (unsigned int*)ws;   ws += (size_t)N_EDGES_C * 4;      // 12.8 MB
    unsigned short* fb    = (unsigned short*)ws; ws += (size_t)N_NODES_C * 64 * 2; // 25.6 MB
    __hip_bfloat16* h1    = (__hip_bfloat16*)ws;          // 25.6 MB

    const int edge_blocks  = (n_edges + 255) / 256;
    const int layer_blocks = N_NODES_C / 64;              // 3125, exact
    const int conv_blocks  = (N_NODES_C * 64 + 255) / 256;

    // ----- bf16 feature table + CSR build (shared by both layers) -----
    hipMemsetAsync(counts, 0, (size_t)N_NODES_C * sizeof(int), stream);
    tobf16_k<<<conv_blocks, 256, 0, stream>>>(uw, ew, fb);
    hist_k<<<edge_blocks, 256, 0, stream>>>(target, counts, n_edges);
    partial_k<<<SCAN_BLK, 256, 0, stream>>>(counts, block_sums);
    scansums_k<<<1, 1024, 0, stream>>>(block_sums, block_offs);
    finalize_k<<<SCAN_BLK, 256, 0, stream>>>(counts, block_offs, row_ptr, cursor, n_edges);
    // range-pass scatter: each pass's writes confined to ~1.6 MB (L2-resident)
    const int range = N_NODES_C / SCAT_PASS;              // 25000, exact
    for (int r = 0; r < SCAT_PASS; r++) {
        scatter_k<<<edge_blocks, 256, 0, stream>>>(target, neighbor, values, cursor,
                                                   edges, n_edges,
                                                   r * range, (r + 1) * range);
    }

    // ----- layer 1 (quad-gather pull + MFMA transform fused) -----
    layer1_pull_k<<<layer_blocks, 256, 0, stream>>>(fb, row_ptr, edges,
                                                    W1a, b1a, W2a, b2a, h1, N_NODES_C);

    // ----- scoring (layer-2 aggregation + transform inline, only ~12K nodes) -----
    score_k<<<BATCH_C / 4, 256, 0, stream>>>(uw, ew, h1, row_ptr, edges,
                                             W1b, b1b, W2b, b2b,
                                             uid, pid, nid, (float*)d_out);
}

// Round 10
// 614.116 us; speedup vs baseline: 3.1778x; 1.1470x over previous
//
#include <hip/hip_runtime.h>
#include <hip/hip_bf16.h>

#define N_USERS    50000
#define N_ENTITIES 150000
#define N_NODES_C  200000
#define BATCH_C    4096
#define N_EDGES_C  3200000
#define SCAN_BLK   782          // ceil(200000/256)

// two-stage edge sort params
#define CHUNK   7168            // edges per sort1 block (LDS 57.3 KB buf)
#define SG_SH   9               // supergroup = 512 nodes
#define NSG     391             // ceil(200000/512)
#define MAXCHK  448             // max chunks (3.2M/7168 = 447)
#define S2CAP   12288           // sort2 LDS word capacity (expected 8192/sg)

typedef __attribute__((ext_vector_type(8))) short short8;
typedef __attribute__((ext_vector_type(4))) float float4v;

// Workspace (~67 MB; proven safe < 76.8 MB):
//   counts  : int [200192]          0.80 MB
//   row_ptr : int [200001+pad]      0.80 MB
//   bsums   : int [1024]            4 KB
//   boffs   : int [1024]            4 KB
//   cntarr  : int [448*391]         0.70 MB
//   offarr  : int [448*391]         0.70 MB
//   edges   : uint [3.2M]          12.8 MB   (nb<<14 | val_q14, node-sorted CSR)
//   fb16    : ushort[200000*64]    25.6 MB   (bf16 node features)
//   region  : 25.69 MB — tmp (uint2 sorted runs) then h1 (bf16 layer-1 out);
//             tmp consumed by sort2 before layer1 writes h1.

__device__ __forceinline__ unsigned short f32_to_bf16_bits(float x) {
    unsigned u = __float_as_uint(x);
    unsigned r = (u + 0x7fffu + ((u >> 16) & 1u)) >> 16;   // RNE
    return (unsigned short)r;
}

// ---------- bf16 node-feature table ----------
__global__ __launch_bounds__(256) void tobf16_k(const float* __restrict__ uw,
                                                const float* __restrict__ ew,
                                                unsigned short* __restrict__ fb)
{
    int idx = blockIdx.x * 256 + threadIdx.x;
    if (idx >= N_NODES_C * 64) return;
    const int split = N_USERS * 64;
    float x = (idx < split) ? uw[idx] : ew[idx - split];
    fb[idx] = f32_to_bf16_bits(x);
}

// ---------- CSR row_ptr build ----------
__global__ __launch_bounds__(256) void hist_k(const int* __restrict__ target,
                                              int* __restrict__ counts, int n_edges)
{
    int e = blockIdx.x * 256 + threadIdx.x;
    if (e < n_edges) atomicAdd(&counts[target[e]], 1);
}

__global__ __launch_bounds__(256) void partial_k(const int* __restrict__ counts,
                                                 int* __restrict__ block_sums)
{
    __shared__ int red[256];
    int gid = blockIdx.x * 256 + threadIdx.x;
    int c = (gid < N_NODES_C) ? counts[gid] : 0;
    red[threadIdx.x] = c;
    __syncthreads();
    for (int off = 128; off > 0; off >>= 1) {
        if (threadIdx.x < off) red[threadIdx.x] += red[threadIdx.x + off];
        __syncthreads();
    }
    if (threadIdx.x == 0) block_sums[blockIdx.x] = red[0];
}

__global__ __launch_bounds__(1024) void scansums_k(const int* __restrict__ block_sums,
                                                   int* __restrict__ block_offs)
{
    __shared__ int part[1024];
    int t = threadIdx.x;
    int v = (t < SCAN_BLK) ? block_sums[t] : 0;
    part[t] = v;
    __syncthreads();
    for (int off = 1; off < 1024; off <<= 1) {
        int w = (t >= off) ? part[t - off] : 0;
        __syncthreads();
        part[t] += w;
        __syncthreads();
    }
    if (t < SCAN_BLK) block_offs[t] = part[t] - v;
}

__global__ __launch_bounds__(256) void finalize_k(const int* __restrict__ counts,
                                                  const int* __restrict__ block_offs,
                                                  int* __restrict__ row_ptr, int n_edges)
{
    __shared__ int wsum[4];
    int gid  = blockIdx.x * 256 + threadIdx.x;
    int lane = threadIdx.x & 63;
    int wave = threadIdx.x >> 6;
    int c = (gid < N_NODES_C) ? counts[gid] : 0;

    int s = c;
    #pragma unroll
    for (int off = 1; off < 64; off <<= 1) {
        int v = __shfl_up(s, off);
        if (lane >= off) s += v;
    }
    if (lane == 63) wsum[wave] = s;
    __syncthreads();
    int woff = 0;
    #pragma unroll
    for (int w = 0; w < 4; w++) woff += (w < wave) ? wsum[w] : 0;

    int excl = block_offs[blockIdx.x] + woff + (s - c);
    if (gid < N_NODES_C) row_ptr[gid] = excl;
    if (gid == 0) row_ptr[N_NODES_C] = n_edges;
}

// ---------- stage 1: chunk-local counting sort by supergroup ----------
// Block-private sequential output => every global write is a full line from
// one writer (no cross-XCD line sharing).
__global__ __launch_bounds__(256) void sort1_k(
    const int* __restrict__ target, const int* __restrict__ neighbor,
    const float* __restrict__ values,
    uint2* __restrict__ tmp, int* __restrict__ cntarr, int* __restrict__ offarr,
    int n_edges)
{
    __shared__ uint2 buf[CHUNK];            // 57.3 KB
    __shared__ int cnt[NSG], off[NSG], pos[NSG];
    int c = blockIdx.x;
    int base = c * CHUNK;
    int ccount = min(CHUNK, n_edges - base);
    for (int i = threadIdx.x; i < NSG; i += 256) { cnt[i] = 0; pos[i] = 0; }
    __syncthreads();
    for (int i = threadIdx.x; i < ccount; i += 256)
        atomicAdd(&cnt[target[base + i] >> SG_SH], 1);
    __syncthreads();
    if (threadIdx.x < 64) {                 // wave-0 exclusive scan of cnt
        int l = threadIdx.x;
        const int PER = (NSG + 63) / 64;    // 7
        int s0 = l * PER, s1 = min(s0 + PER, NSG);
        int sum = 0;
        for (int i = s0; i < s1; i++) sum += cnt[i];
        int run = sum;
        #pragma unroll
        for (int o = 1; o < 64; o <<= 1) { int v = __shfl_up(run, o); if (l >= o) run += v; }
        int excl = run - sum;
        for (int i = s0; i < s1; i++) { off[i] = excl; excl += cnt[i]; }
    }
    __syncthreads();
    for (int i = threadIdx.x; i < ccount; i += 256) {
        int t  = target[base + i];
        int sg = t >> SG_SH;
        unsigned q = (unsigned)fminf(values[base + i] * 16384.f + 0.5f, 16383.f);
        unsigned w = ((unsigned)neighbor[base + i] << 14) | q;
        int p = off[sg] + atomicAdd(&pos[sg], 1);
        buf[p] = make_uint2(w, (unsigned)t);
    }
    __syncthreads();
    for (int i = threadIdx.x; i < ccount; i += 256)
        tmp[(size_t)c * CHUNK + i] = buf[i];
    for (int i = threadIdx.x; i < NSG; i += 256) {
        cntarr[c * NSG + i] = cnt[i];
        offarr[c * NSG + i] = off[i];
    }
}

// ---------- stage 2: per-supergroup node-exact placement ----------
__global__ __launch_bounds__(256) void sort2_k(
    const uint2* __restrict__ tmp, const int* __restrict__ cntarr,
    const int* __restrict__ offarr, const int* __restrict__ row_ptr,
    unsigned* __restrict__ edges, int nchunks)
{
    __shared__ unsigned words[S2CAP];       // 49.2 KB write-combine buffer
    __shared__ int rp[513];
    __shared__ int cur[512];
    int s = blockIdx.x;
    int node0 = s << SG_SH;
    int nn = min(512, N_NODES_C - node0);
    int sgstart = row_ptr[node0];
    for (int i = threadIdx.x; i <= nn; i += 256) rp[i] = row_ptr[node0 + i] - sgstart;
    for (int i = threadIdx.x; i < nn; i += 256) cur[i] = 0;
    __syncthreads();
    int sgcnt = rp[nn];
    int wv = threadIdx.x >> 6, lane = threadIdx.x & 63;
    for (int c = wv; c < nchunks; c += 4) {
        int cnt = cntarr[c * NSG + s];
        int off = offarr[c * NSG + s];
        for (int i = lane; i < cnt; i += 64) {
            uint2 e = tmp[(size_t)c * CHUNK + off + i];
            int tl  = (int)e.y - node0;
            int old = atomicAdd(&cur[tl], 1);
            int li  = rp[tl] + old;
            if (li < S2CAP) words[li] = e.x;
            else edges[sgstart + li] = e.x;     // rare overflow: exact position known
        }
    }
    __syncthreads();
    int lim = min(sgcnt, S2CAP);
    for (int i = threadIdx.x; i < lim; i += 256) edges[sgstart + i] = words[i];
}

// ---------- layer 1: quad-gather CSR pull + MFMA dense transform ----------
// Block = 8 waves = 128 nodes (512 threads). One shared 17.4 KB weight tile;
// LDS 52.5 KB -> 3 blocks/CU = 24 waves/CU (was 4x256thr @ 35 KB -> 16 waves).
#define SPS 136
__global__ __launch_bounds__(512, 6) void layer1_pull_k(
    const unsigned short* __restrict__ fb,
    const int* __restrict__ row_ptr, const unsigned int* __restrict__ edges,
    const float* __restrict__ W1, const float* __restrict__ b1,
    const float* __restrict__ W2, const float* __restrict__ b2,
    __hip_bfloat16* __restrict__ h1out, int n_nodes)
{
    __shared__ __align__(16) short wt[64 * SPS];    // 17.4 KB, shared by 8 waves
    __shared__ __align__(16) short sp[128 * SPS];   // 34.8 KB
    __shared__ float sbias[64];

    for (int idx = threadIdx.x; idx < 64 * 64; idx += 512) {
        int kp = idx >> 6;
        int n  = idx & 63;
        int k0 = kp * 2, k1 = k0 + 1;
        float w0 = (k0 < 64) ? W1[k0 * 64 + n] : W2[(k0 - 64) * 64 + n];
        float w1 = (k1 < 64) ? W1[k1 * 64 + n] : W2[(k1 - 64) * 64 + n];
        *(unsigned*)&wt[n * SPS + k0] =
            ((unsigned)f32_to_bf16_bits(w1) << 16) | f32_to_bf16_bits(w0);
    }
    if (threadIdx.x < 64) sbias[threadIdx.x] = b1[threadIdx.x] + b2[threadIdx.x];
    __syncthreads();

    int wv   = threadIdx.x >> 6;        // 0..7
    int lane = threadIdx.x & 63;
    int g    = lane >> 4;
    int q    = lane & 15;
    const uint2* fb2 = (const uint2*)fb;

    int nb0 = blockIdx.x * 128;

    const float QS = 1.f / 16384.f;
    for (int i = 0; i < 16; i++) {
        int m    = wv * 16 + i;
        int node = nb0 + m;
        int es = 0, ee = 0;
        if (node < n_nodes) { es = row_ptr[node]; ee = row_ptr[node + 1]; }

        float h0 = 0.f, h1a = 0.f, h2a = 0.f, h3a = 0.f;
        for (int base = es; base < ee; base += 64) {
            int cnt = min(64, ee - base);
            unsigned ev = (lane < cnt) ? edges[base + lane] : 0u;
            int jmax = (cnt + 3) >> 2;
            #pragma unroll 4
            for (int j = 0; j < jmax; j++) {
                unsigned w = (unsigned)__shfl((int)ev, j * 4 + g);
                float v = (float)(w & 16383u) * QS;
                uint2 d = fb2[(size_t)(w >> 14) * 16 + q];
                h0  += v * __uint_as_float(d.x << 16);
                h1a += v * __uint_as_float(d.x & 0xffff0000u);
                h2a += v * __uint_as_float(d.y << 16);
                h3a += v * __uint_as_float(d.y & 0xffff0000u);
            }
        }
        #pragma unroll
        for (int mm = 16; mm < 64; mm <<= 1) {
            h0  += __shfl_xor(h0, mm);
            h1a += __shfl_xor(h1a, mm);
            h2a += __shfl_xor(h2a, mm);
            h3a += __shfl_xor(h3a, mm);
        }

        uint2 dself = make_uint2(0u, 0u);
        if (node < n_nodes) dself = fb2[(size_t)node * 16 + q];
        float f0 = __uint_as_float(dself.x << 16);
        float f1 = __uint_as_float(dself.x & 0xffff0000u);
        float f2 = __uint_as_float(dself.y << 16);
        float f3 = __uint_as_float(dself.y & 0xffff0000u);

        if (g < 2) {
            float a0 = (g == 0) ? f0 + h0  : f0 * h0;
            float a1 = (g == 0) ? f1 + h1a : f1 * h1a;
            float a2 = (g == 0) ? f2 + h2a : f2 * h2a;
            float a3 = (g == 0) ? f3 + h3a : f3 * h3a;
            uint2 pk;
            pk.x = ((unsigned)f32_to_bf16_bits(a1) << 16) | f32_to_bf16_bits(a0);
            pk.y = ((unsigned)f32_to_bf16_bits(a3) << 16) | f32_to_bf16_bits(a2);
            *(uint2*)&sp[m * SPS + g * 64 + q * 4] = pk;
        }
    }
    __syncthreads();   // sp rows complete for this block (same-wave, but cheap + safe)

    float4v c0, c1, c2, c3;
    {
        float bv0 = sbias[q];
        float bv1 = sbias[16 + q];
        float bv2 = sbias[32 + q];
        float bv3 = sbias[48 + q];
        c0 = (float4v){bv0, bv0, bv0, bv0};
        c1 = (float4v){bv1, bv1, bv1, bv1};
        c2 = (float4v){bv2, bv2, bv2, bv2};
        c3 = (float4v){bv3, bv3, bv3, bv3};
    }
    #pragma unroll
    for (int kk = 0; kk < 4; kk++) {
        int ko = kk * 32 + g * 8;
        short8 a = *(const short8*)&sp[(wv * 16 + q) * SPS + ko];
        short8 bb0 = *(const short8*)&wt[(q)      * SPS + ko];
        short8 bb1 = *(const short8*)&wt[(16 + q) * SPS + ko];
        short8 bb2 = *(const short8*)&wt[(32 + q) * SPS + ko];
        short8 bb3 = *(const short8*)&wt[(48 + q) * SPS + ko];
        c0 = __builtin_amdgcn_mfma_f32_16x16x32_bf16(a, bb0, c0, 0, 0, 0);
        c1 = __builtin_amdgcn_mfma_f32_16x16x32_bf16(a, bb1, c1, 0, 0, 0);
        c2 = __builtin_amdgcn_mfma_f32_16x16x32_bf16(a, bb2, c2, 0, 0, 0);
        c3 = __builtin_amdgcn_mfma_f32_16x16x32_bf16(a, bb3, c3, 0, 0, 0);
    }

    float ss[4];
    #pragma unroll
    for (int r = 0; r < 4; r++) {
        c0[r] = (c0[r] > 0.f) ? c0[r] : 0.01f * c0[r];
        c1[r] = (c1[r] > 0.f) ? c1[r] : 0.01f * c1[r];
        c2[r] = (c2[r] > 0.f) ? c2[r] : 0.01f * c2[r];
        c3[r] = (c3[r] > 0.f) ? c3[r] : 0.01f * c3[r];
        ss[r] = c0[r]*c0[r] + c1[r]*c1[r] + c2[r]*c2[r] + c3[r]*c3[r];
        #pragma unroll
        for (int mm = 1; mm < 16; mm <<= 1) ss[r] += __shfl_xor(ss[r], mm);
        ss[r] = 1.f / fmaxf(sqrtf(ss[r]), 1e-12f);
    }
    #pragma unroll
    for (int r = 0; r < 4; r++) {
        int node_r = nb0 + wv * 16 + g * 4 + r;
        if (node_r >= n_nodes) continue;
        size_t row = (size_t)node_r * 64;
        h1out[row +      q] = __float2bfloat16(c0[r] * ss[r]);
        h1out[row + 16 + q] = __float2bfloat16(c1[r] * ss[r]);
        h1out[row + 32 + q] = __float2bfloat16(c2[r] * ss[r]);
        h1out[row + 48 + q] = __float2bfloat16(c3[r] * ss[r]);
    }
}

// ---------- inline layer2 (64->32) for one node, aggregation pulled on the fly ----------
__device__ __forceinline__ float layer2_row(
    const __hip_bfloat16* __restrict__ h1,
    const int* __restrict__ row_ptr, const unsigned int* __restrict__ edges,
    const float* sW1, const float* sW2, const float* sb,
    int node, int lane)
{
    int es = row_ptr[node];
    int ee = row_ptr[node + 1];
    const float QS = 1.f / 16384.f;
    float g = 0.f;
    for (int base = es; base < ee; base += 64) {
        int cnt = min(64, ee - base);
        unsigned ev = (lane < cnt) ? edges[base + lane] : 0u;
        int j = 0;
        for (; j + 4 <= cnt; j += 4) {
            unsigned e0 = (unsigned)__shfl((int)ev, j);
            unsigned e1 = (unsigned)__shfl((int)ev, j + 1);
            unsigned e2 = (unsigned)__shfl((int)ev, j + 2);
            unsigned e3 = (unsigned)__shfl((int)ev, j + 3);
            float f0 = __bfloat162float(h1[(size_t)(e0 >> 14) * 64 + lane]);
            float f1 = __bfloat162float(h1[(size_t)(e1 >> 14) * 64 + lane]);
            float f2 = __bfloat162float(h1[(size_t)(e2 >> 14) * 64 + lane]);
            float f3 = __bfloat162float(h1[(size_t)(e3 >> 14) * 64 + lane]);
            g += (float)(e0 & 16383u) * QS * f0 + (float)(e1 & 16383u) * QS * f1
               + (float)(e2 & 16383u) * QS * f2 + (float)(e3 & 16383u) * QS * f3;
        }
        for (; j < cnt; j++) {
            unsigned e0 = (unsigned)__shfl((int)ev, j);
            float f0 = __bfloat162float(h1[(size_t)(e0 >> 14) * 64 + lane]);
            g += (float)(e0 & 16383u) * QS * f0;
        }
    }
    float f = __bfloat162float(h1[(size_t)node * 64 + lane]);
    float s = f + g;
    float p = f * g;
    int j = lane & 31;
    float acc = sb[j];
    #pragma unroll
    for (int k = 0; k < 64; k++) {
        float sk = __shfl(s, k);
        float pk = __shfl(p, k);
        acc += sk * sW1[k * 32 + j] + pk * sW2[k * 32 + j];
    }
    acc = (acc > 0.f) ? acc : 0.01f * acc;
    float sq = acc * acc;
    #pragma unroll
    for (int m = 1; m < 32; m <<= 1) sq += __shfl_xor(sq, m);
    return acc / fmaxf(sqrtf(sq), 1e-12f);
}

__global__ __launch_bounds__(256) void score_k(
    const float* __restrict__ uw, const float* __restrict__ ew,
    const __hip_bfloat16* __restrict__ h1,
    const int* __restrict__ row_ptr, const unsigned int* __restrict__ edges,
    const float* __restrict__ W1b, const float* __restrict__ b1b,
    const float* __restrict__ W2b, const float* __restrict__ b2b,
    const int* __restrict__ uid, const int* __restrict__ pid,
    const int* __restrict__ nid, float* __restrict__ out)
{
    __shared__ float sW1[64 * 32];
    __shared__ float sW2[64 * 32];
    __shared__ float sb[32];
    for (int i = threadIdx.x; i < 64 * 32; i += 256) { sW1[i] = W1b[i]; sW2[i] = W2b[i]; }
    if (threadIdx.x < 32) sb[threadIdx.x] = b1b[threadIdx.x] + b2b[threadIdx.x];
    __syncthreads();

    int wave = threadIdx.x >> 6;
    int lane = threadIdx.x & 63;
    int i = blockIdx.x * 4 + wave;
    if (i >= BATCH_C) return;

    int un = uid[i];
    int pe = pid[i];
    int ne = nid[i];
    int pn = N_USERS + pe;
    int nn = N_USERS + ne;

    float acc01p, acc01n;
    {
        float u  = uw[(size_t)un * 64 + lane];
        float pv = ew[(size_t)pe * 64 + lane];
        float nv = ew[(size_t)ne * 64 + lane];
        acc01p = u * pv;
        acc01n = u * nv;
        float u1 = __bfloat162float(h1[(size_t)un * 64 + lane]);
        acc01p += u1 * __bfloat162float(h1[(size_t)pn * 64 + lane]);
        acc01n += u1 * __bfloat162float(h1[(size_t)nn * 64 + lane]);
    }

    float h2u = layer2_row(h1, row_ptr, edges, sW1, sW2, sb, un, lane);
    float h2p = layer2_row(h1, row_ptr, edges, sW1, sW2, sb, pn, lane);
    float h2n = layer2_row(h1, row_ptr, edges, sW1, sW2, sb, nn, lane);
    float p2 = h2u * h2p;
    float n2 = h2u * h2n;
    #pragma unroll
    for (int m = 1; m < 32; m <<= 1) { p2 += __shfl_xor(p2, m); n2 += __shfl_xor(n2, m); }

    #pragma unroll
    for (int m = 1; m < 64; m <<= 1) { acc01p += __shfl_xor(acc01p, m); acc01n += __shfl_xor(acc01n, m); }

    if (lane == 0) {
        out[i]           = acc01p + p2;
        out[BATCH_C + i] = acc01n + n2;
    }
}

extern "C" void kernel_launch(void* const* d_in, const int* in_sizes, int n_in,
                              void* d_out, int out_size, void* d_ws, size_t ws_size,
                              hipStream_t stream) {
    const float* uw   = (const float*)d_in[0];
    const float* ew   = (const float*)d_in[1];
    const float* W1a  = (const float*)d_in[2];
    const float* b1a  = (const float*)d_in[3];
    const float* W2a  = (const float*)d_in[4];
    const float* b2a  = (const float*)d_in[5];
    const float* W1b  = (const float*)d_in[6];
    const float* b1b  = (const float*)d_in[7];
    const float* W2b  = (const float*)d_in[8];
    const float* b2b  = (const float*)d_in[9];
    const float* values   = (const float*)d_in[10];
    const int*   target   = (const int*)d_in[11];
    const int*   neighbor = (const int*)d_in[12];
    const int*   uid  = (const int*)d_in[13];
    const int*   pid  = (const int*)d_in[14];
    const int*   nid  = (const int*)d_in[15];

    const int n_edges = in_sizes[10];

    char* ws = (char*)d_ws;
    int*  counts     = (int*)ws;   ws += 801792;
    int*  row_ptr    = (int*)ws;   ws += 801792;
    int*  block_sums = (int*)ws;   ws += 4096;
    int*  block_offs = (int*)ws;   ws += 4096;
    int*  cntarr     = (int*)ws;   ws += 704512;          // 448*391*4 = 700672
    int*  offarr     = (int*)ws;   ws += 704512;
    unsigned int*   edges = (unsigned int*)ws;   ws += (size_t)N_EDGES_C * 4;      // 12.8 MB
    unsigned short* fb    = (unsigned short*)ws; ws += (size_t)N_NODES_C * 64 * 2; // 25.6 MB
    // shared region: tmp (sort runs) then h1 — tmp consumed before h1 written
    uint2*          tmp   = (uint2*)ws;
    __hip_bfloat16* h1    = (__hip_bfloat16*)ws;          // region 25.69 MB

    const int edge_blocks  = (n_edges + 255) / 256;
    const int layer_blocks = (N_NODES_C + 127) / 128;     // 1563
    const int conv_blocks  = (N_NODES_C * 64 + 255) / 256;
    const int nchunks      = (n_edges + CHUNK - 1) / CHUNK;   // 447

    // ----- bf16 feature table + row_ptr -----
    hipMemsetAsync(counts, 0, (size_t)N_NODES_C * sizeof(int), stream);
    tobf16_k<<<conv_blocks, 256, 0, stream>>>(uw, ew, fb);
    hist_k<<<edge_blocks, 256, 0, stream>>>(target, counts, n_edges);
    partial_k<<<SCAN_BLK, 256, 0, stream>>>(counts, block_sums);
    scansums_k<<<1, 1024, 0, stream>>>(block_sums, block_offs);
    finalize_k<<<SCAN_BLK, 256, 0, stream>>>(counts, block_offs, row_ptr, n_edges);

    // ----- two-stage edge sort (all writes block-private + coalesced) -----
    sort1_k<<<nchunks, 256, 0, stream>>>(target, neighbor, values, tmp, cntarr, offarr, n_edges);
    sort2_k<<<NSG, 256, 0, stream>>>(tmp, cntarr, offarr, row_ptr, edges, nchunks);

    // ----- layer 1 (quad-gather pull + MFMA transform, 8-wave blocks) -----
    layer1_pull_k<<<layer_blocks, 512, 0, stream>>>(fb, row_ptr, edges,
                                                    W1a, b1a, W2a, b2a, h1, N_NODES_C);

    // ----- scoring (layer-2 aggregation + transform inline, ~12K nodes) -----
    score_k<<<BATCH_C / 4, 256, 0, stream>>>(uw, ew, h1, row_ptr, edges,
                                             W1b, b1b, W2b, b2b,
                                             uid, pid, nid, (float*)d_out);
}

// Round 11
// 514.144 us; speedup vs baseline: 3.7958x; 1.1944x over previous
//
#include <hip/hip_runtime.h>
#include <hip/hip_bf16.h>

#define N_USERS    50000
#define N_ENTITIES 150000
#define N_NODES_C  200000
#define BATCH_C    4096
#define N_EDGES_C  3200000
#define SCAN_BLK   782          // ceil(200000/256)

// two-stage edge sort params
#define CHUNK   7168            // edges per sort1 block (LDS 57.3 KB buf)
#define SG_SH   9               // supergroup = 512 nodes
#define NSG     391             // ceil(200000/512)
#define MAXCHK  448             // max chunks (3.2M/7168 = 447)
#define S2CAP   12288           // sort2 LDS word capacity (expected 8192/sg)

typedef __attribute__((ext_vector_type(8))) short short8;
typedef __attribute__((ext_vector_type(4))) float float4v;

// Workspace (~67 MB; proven safe < 76.8 MB):
//   counts  : int [200192]          0.80 MB
//   row_ptr : int [200001+pad]      0.80 MB
//   bsums   : int [1024]            4 KB
//   boffs   : int [1024]            4 KB
//   cntarr  : int [448*391]         0.70 MB
//   offarr  : int [448*391]         0.70 MB
//   edges   : uint [3.2M]          12.8 MB   (nb<<14 | val_q14, node-sorted CSR)
//   fb16    : ushort[200000*64]    25.6 MB   (bf16 node features)
//   region  : 25.69 MB — tmp (uint2 sorted runs) then h1 (bf16 layer-1 out)

__device__ __forceinline__ unsigned short f32_to_bf16_bits(float x) {
    unsigned u = __float_as_uint(x);
    unsigned r = (u + 0x7fffu + ((u >> 16) & 1u)) >> 16;   // RNE
    return (unsigned short)r;
}

// ---------- bf16 node-feature table ----------
__global__ __launch_bounds__(256) void tobf16_k(const float* __restrict__ uw,
                                                const float* __restrict__ ew,
                                                unsigned short* __restrict__ fb)
{
    int idx = blockIdx.x * 256 + threadIdx.x;
    if (idx >= N_NODES_C * 64) return;
    const int split = N_USERS * 64;
    float x = (idx < split) ? uw[idx] : ew[idx - split];
    fb[idx] = f32_to_bf16_bits(x);
}

// ---------- CSR row_ptr build ----------
__global__ __launch_bounds__(256) void hist_k(const int* __restrict__ target,
                                              int* __restrict__ counts, int n_edges)
{
    int e = blockIdx.x * 256 + threadIdx.x;
    if (e < n_edges) atomicAdd(&counts[target[e]], 1);
}

__global__ __launch_bounds__(256) void partial_k(const int* __restrict__ counts,
                                                 int* __restrict__ block_sums)
{
    __shared__ int red[256];
    int gid = blockIdx.x * 256 + threadIdx.x;
    int c = (gid < N_NODES_C) ? counts[gid] : 0;
    red[threadIdx.x] = c;
    __syncthreads();
    for (int off = 128; off > 0; off >>= 1) {
        if (threadIdx.x < off) red[threadIdx.x] += red[threadIdx.x + off];
        __syncthreads();
    }
    if (threadIdx.x == 0) block_sums[blockIdx.x] = red[0];
}

__global__ __launch_bounds__(1024) void scansums_k(const int* __restrict__ block_sums,
                                                   int* __restrict__ block_offs)
{
    __shared__ int part[1024];
    int t = threadIdx.x;
    int v = (t < SCAN_BLK) ? block_sums[t] : 0;
    part[t] = v;
    __syncthreads();
    for (int off = 1; off < 1024; off <<= 1) {
        int w = (t >= off) ? part[t - off] : 0;
        __syncthreads();
        part[t] += w;
        __syncthreads();
    }
    if (t < SCAN_BLK) block_offs[t] = part[t] - v;
}

__global__ __launch_bounds__(256) void finalize_k(const int* __restrict__ counts,
                                                  const int* __restrict__ block_offs,
                                                  int* __restrict__ row_ptr, int n_edges)
{
    __shared__ int wsum[4];
    int gid  = blockIdx.x * 256 + threadIdx.x;
    int lane = threadIdx.x & 63;
    int wave = threadIdx.x >> 6;
    int c = (gid < N_NODES_C) ? counts[gid] : 0;

    int s = c;
    #pragma unroll
    for (int off = 1; off < 64; off <<= 1) {
        int v = __shfl_up(s, off);
        if (lane >= off) s += v;
    }
    if (lane == 63) wsum[wave] = s;
    __syncthreads();
    int woff = 0;
    #pragma unroll
    for (int w = 0; w < 4; w++) woff += (w < wave) ? wsum[w] : 0;

    int excl = block_offs[blockIdx.x] + woff + (s - c);
    if (gid < N_NODES_C) row_ptr[gid] = excl;
    if (gid == 0) row_ptr[N_NODES_C] = n_edges;
}

// ---------- stage 1: chunk-local counting sort by supergroup ----------
__global__ __launch_bounds__(256) void sort1_k(
    const int* __restrict__ target, const int* __restrict__ neighbor,
    const float* __restrict__ values,
    uint2* __restrict__ tmp, int* __restrict__ cntarr, int* __restrict__ offarr,
    int n_edges)
{
    __shared__ uint2 buf[CHUNK];            // 57.3 KB
    __shared__ int cnt[NSG], off[NSG], pos[NSG];
    int c = blockIdx.x;
    int base = c * CHUNK;
    int ccount = min(CHUNK, n_edges - base);
    for (int i = threadIdx.x; i < NSG; i += 256) { cnt[i] = 0; pos[i] = 0; }
    __syncthreads();
    for (int i = threadIdx.x; i < ccount; i += 256)
        atomicAdd(&cnt[target[base + i] >> SG_SH], 1);
    __syncthreads();
    if (threadIdx.x < 64) {                 // wave-0 exclusive scan of cnt
        int l = threadIdx.x;
        const int PER = (NSG + 63) / 64;    // 7
        int s0 = l * PER, s1 = min(s0 + PER, NSG);
        int sum = 0;
        for (int i = s0; i < s1; i++) sum += cnt[i];
        int run = sum;
        #pragma unroll
        for (int o = 1; o < 64; o <<= 1) { int v = __shfl_up(run, o); if (l >= o) run += v; }
        int excl = run - sum;
        for (int i = s0; i < s1; i++) { off[i] = excl; excl += cnt[i]; }
    }
    __syncthreads();
    for (int i = threadIdx.x; i < ccount; i += 256) {
        int t  = target[base + i];
        int sg = t >> SG_SH;
        unsigned q = (unsigned)fminf(values[base + i] * 16384.f + 0.5f, 16383.f);
        unsigned w = ((unsigned)neighbor[base + i] << 14) | q;
        int p = off[sg] + atomicAdd(&pos[sg], 1);
        buf[p] = make_uint2(w, (unsigned)t);
    }
    __syncthreads();
    for (int i = threadIdx.x; i < ccount; i += 256)
        tmp[(size_t)c * CHUNK + i] = buf[i];
    for (int i = threadIdx.x; i < NSG; i += 256) {
        cntarr[c * NSG + i] = cnt[i];
        offarr[c * NSG + i] = off[i];
    }
}

// ---------- stage 2: per-supergroup node-exact placement (dense/balanced) ----------
// All per-chunk metadata staged to LDS in one parallel round, scanned in-block;
// then 256 threads stride densely over the supergroup's edges (binary-search
// the chunk, coalesced tmp reads, independent loads -> deep MLP).
__global__ __launch_bounds__(256) void sort2_k(
    const uint2* __restrict__ tmp, const int* __restrict__ cntarr,
    const int* __restrict__ offarr, const int* __restrict__ row_ptr,
    unsigned* __restrict__ edges, int nchunks)
{
    __shared__ unsigned words[S2CAP];       // 49.2 KB write-combine buffer
    __shared__ int rp[513];
    __shared__ int cur[512];
    __shared__ int pre[MAXCHK + 1];
    __shared__ int soff[MAXCHK];
    int s = blockIdx.x;
    int node0 = s << SG_SH;
    int nn = min(512, N_NODES_C - node0);
    int sgstart = row_ptr[node0];
    for (int i = threadIdx.x; i <= nn; i += 256) rp[i] = row_ptr[node0 + i] - sgstart;
    for (int i = threadIdx.x; i < nn; i += 256) cur[i] = 0;
    for (int c = threadIdx.x; c < nchunks; c += 256) {
        pre[c]  = cntarr[c * NSG + s];
        soff[c] = offarr[c * NSG + s];
    }
    __syncthreads();
    if (threadIdx.x < 64) {                 // wave-0 exclusive scan of pre (in place)
        int l = threadIdx.x;
        int PER = (nchunks + 63) >> 6;      // 7
        int s0 = l * PER, s1 = min(s0 + PER, nchunks);
        int vals[8];
        int sum = 0;
        for (int i = s0; i < s1; i++) { vals[i - s0] = pre[i]; sum += vals[i - s0]; }
        int run = sum;
        #pragma unroll
        for (int o = 1; o < 64; o <<= 1) { int v = __shfl_up(run, o); if (l >= o) run += v; }
        int excl = run - sum;
        for (int i = s0; i < s1; i++) { int t = vals[i - s0]; pre[i] = excl; excl += t; }
        if (l == 63) pre[nchunks] = excl;
    }
    __syncthreads();
    int sgcnt = pre[nchunks];
    for (int e = threadIdx.x; e < sgcnt; e += 256) {
        int lo = 0, hi = nchunks;           // invariant: pre[lo] <= e < pre[hi]
        while (hi - lo > 1) {
            int mid = (lo + hi) >> 1;
            if (pre[mid] <= e) lo = mid; else hi = mid;
        }
        uint2 ed = tmp[(size_t)lo * CHUNK + soff[lo] + (e - pre[lo])];
        int tl  = (int)ed.y - node0;
        int old = atomicAdd(&cur[tl], 1);
        int li  = rp[tl] + old;
        if (li < S2CAP) words[li] = ed.x;
        else edges[sgstart + li] = ed.x;    // rare overflow: exact position known
    }
    __syncthreads();
    int lim = min(sgcnt, S2CAP);
    for (int i = threadIdx.x; i < lim; i += 256) edges[sgstart + i] = words[i];
}

// ---------- layer 1: dual-node quad-gather pull + MFMA dense transform ----------
// Block = 8 waves = 128 nodes (512 threads), shared 17.4 KB weight tile.
// Edge pull processes node PAIRS with independent accumulators: each j-iter
// issues 2 independent gathers (x4 unroll -> up to 8 loads in flight).
#define SPS 136
__global__ __launch_bounds__(512, 6) void layer1_pull_k(
    const unsigned short* __restrict__ fb,
    const int* __restrict__ row_ptr, const unsigned int* __restrict__ edges,
    const float* __restrict__ W1, const float* __restrict__ b1,
    const float* __restrict__ W2, const float* __restrict__ b2,
    __hip_bfloat16* __restrict__ h1out, int n_nodes)
{
    __shared__ __align__(16) short wt[64 * SPS];    // 17.4 KB
    __shared__ __align__(16) short sp[128 * SPS];   // 34.8 KB
    __shared__ float sbias[64];

    for (int idx = threadIdx.x; idx < 64 * 64; idx += 512) {
        int kp = idx >> 6;
        int n  = idx & 63;
        int k0 = kp * 2, k1 = k0 + 1;
        float w0 = (k0 < 64) ? W1[k0 * 64 + n] : W2[(k0 - 64) * 64 + n];
        float w1 = (k1 < 64) ? W1[k1 * 64 + n] : W2[(k1 - 64) * 64 + n];
        *(unsigned*)&wt[n * SPS + k0] =
            ((unsigned)f32_to_bf16_bits(w1) << 16) | f32_to_bf16_bits(w0);
    }
    if (threadIdx.x < 64) sbias[threadIdx.x] = b1[threadIdx.x] + b2[threadIdx.x];
    __syncthreads();

    int wv   = threadIdx.x >> 6;        // 0..7
    int lane = threadIdx.x & 63;
    int g    = lane >> 4;
    int q    = lane & 15;
    const uint2* fb2 = (const uint2*)fb;

    int nb0 = blockIdx.x * 128;
    const float QS = 1.f / 16384.f;

    for (int i = 0; i < 16; i += 2) {
        int mA = wv * 16 + i;
        int nodeA = nb0 + mA;
        int nodeB = nodeA + 1;
        int esA = 0, eeA = 0, esB = 0, eeB = 0;
        if (nodeA < n_nodes) { esA = row_ptr[nodeA]; eeA = row_ptr[nodeA + 1]; }
        if (nodeB < n_nodes) { esB = row_ptr[nodeB]; eeB = row_ptr[nodeB + 1]; }

        float a0 = 0.f, a1 = 0.f, a2 = 0.f, a3 = 0.f;
        float b0v = 0.f, b1v = 0.f, b2v = 0.f, b3v = 0.f;
        int baseA = esA, baseB = esB;
        while (baseA < eeA || baseB < eeB) {
            int cntA = eeA - baseA;  if (cntA > 64) cntA = 64;
            int cntB = eeB - baseB;  if (cntB > 64) cntB = 64;
            unsigned evA = (lane < cntA) ? edges[baseA + lane] : 0u;
            unsigned evB = (lane < cntB) ? edges[baseB + lane] : 0u;
            int jmA = (cntA > 0) ? ((cntA + 3) >> 2) : 0;
            int jmB = (cntB > 0) ? ((cntB + 3) >> 2) : 0;
            int jm = max(jmA, jmB);
            #pragma unroll 4
            for (int j = 0; j < jm; j++) {
                unsigned wA = (j < jmA) ? (unsigned)__shfl((int)evA, j * 4 + g) : 0u;
                unsigned wB = (j < jmB) ? (unsigned)__shfl((int)evB, j * 4 + g) : 0u;
                uint2 dA = fb2[(size_t)(wA >> 14) * 16 + q];   // wA=0 -> row0, v=0
                uint2 dB = fb2[(size_t)(wB >> 14) * 16 + q];
                float vA = (float)(wA & 16383u) * QS;
                float vB = (float)(wB & 16383u) * QS;
                a0  += vA * __uint_as_float(dA.x << 16);
                a1  += vA * __uint_as_float(dA.x & 0xffff0000u);
                a2  += vA * __uint_as_float(dA.y << 16);
                a3  += vA * __uint_as_float(dA.y & 0xffff0000u);
                b0v += vB * __uint_as_float(dB.x << 16);
                b1v += vB * __uint_as_float(dB.x & 0xffff0000u);
                b2v += vB * __uint_as_float(dB.y << 16);
                b3v += vB * __uint_as_float(dB.y & 0xffff0000u);
            }
            baseA += 64; baseB += 64;
        }
        #pragma unroll
        for (int mm = 16; mm < 64; mm <<= 1) {
            a0  += __shfl_xor(a0, mm);  a1  += __shfl_xor(a1, mm);
            a2  += __shfl_xor(a2, mm);  a3  += __shfl_xor(a3, mm);
            b0v += __shfl_xor(b0v, mm); b1v += __shfl_xor(b1v, mm);
            b2v += __shfl_xor(b2v, mm); b3v += __shfl_xor(b3v, mm);
        }

        uint2 dsA = make_uint2(0u, 0u), dsB = make_uint2(0u, 0u);
        if (nodeA < n_nodes) dsA = fb2[(size_t)nodeA * 16 + q];
        if (nodeB < n_nodes) dsB = fb2[(size_t)nodeB * 16 + q];

        if (g < 2) {
            float fA0 = __uint_as_float(dsA.x << 16);
            float fA1 = __uint_as_float(dsA.x & 0xffff0000u);
            float fA2 = __uint_as_float(dsA.y << 16);
            float fA3 = __uint_as_float(dsA.y & 0xffff0000u);
            float x0 = (g == 0) ? fA0 + a0 : fA0 * a0;
            float x1 = (g == 0) ? fA1 + a1 : fA1 * a1;
            float x2 = (g == 0) ? fA2 + a2 : fA2 * a2;
            float x3 = (g == 0) ? fA3 + a3 : fA3 * a3;
            uint2 pk;
            pk.x = ((unsigned)f32_to_bf16_bits(x1) << 16) | f32_to_bf16_bits(x0);
            pk.y = ((unsigned)f32_to_bf16_bits(x3) << 16) | f32_to_bf16_bits(x2);
            *(uint2*)&sp[mA * SPS + g * 64 + q * 4] = pk;

            float fB0 = __uint_as_float(dsB.x << 16);
            float fB1 = __uint_as_float(dsB.x & 0xffff0000u);
            float fB2 = __uint_as_float(dsB.y << 16);
            float fB3 = __uint_as_float(dsB.y & 0xffff0000u);
            float y0 = (g == 0) ? fB0 + b0v : fB0 * b0v;
            float y1 = (g == 0) ? fB1 + b1v : fB1 * b1v;
            float y2 = (g == 0) ? fB2 + b2v : fB2 * b2v;
            float y3 = (g == 0) ? fB3 + b3v : fB3 * b3v;
            pk.x = ((unsigned)f32_to_bf16_bits(y1) << 16) | f32_to_bf16_bits(y0);
            pk.y = ((unsigned)f32_to_bf16_bits(y3) << 16) | f32_to_bf16_bits(y2);
            *(uint2*)&sp[(mA + 1) * SPS + g * 64 + q * 4] = pk;
        }
    }
    __syncthreads();

    float4v c0, c1, c2, c3;
    {
        float bv0 = sbias[q];
        float bv1 = sbias[16 + q];
        float bv2 = sbias[32 + q];
        float bv3 = sbias[48 + q];
        c0 = (float4v){bv0, bv0, bv0, bv0};
        c1 = (float4v){bv1, bv1, bv1, bv1};
        c2 = (float4v){bv2, bv2, bv2, bv2};
        c3 = (float4v){bv3, bv3, bv3, bv3};
    }
    #pragma unroll
    for (int kk = 0; kk < 4; kk++) {
        int ko = kk * 32 + g * 8;
        short8 a = *(const short8*)&sp[(wv * 16 + q) * SPS + ko];
        short8 bb0 = *(const short8*)&wt[(q)      * SPS + ko];
        short8 bb1 = *(const short8*)&wt[(16 + q) * SPS + ko];
        short8 bb2 = *(const short8*)&wt[(32 + q) * SPS + ko];
        short8 bb3 = *(const short8*)&wt[(48 + q) * SPS + ko];
        c0 = __builtin_amdgcn_mfma_f32_16x16x32_bf16(a, bb0, c0, 0, 0, 0);
        c1 = __builtin_amdgcn_mfma_f32_16x16x32_bf16(a, bb1, c1, 0, 0, 0);
        c2 = __builtin_amdgcn_mfma_f32_16x16x32_bf16(a, bb2, c2, 0, 0, 0);
        c3 = __builtin_amdgcn_mfma_f32_16x16x32_bf16(a, bb3, c3, 0, 0, 0);
    }

    float ss[4];
    #pragma unroll
    for (int r = 0; r < 4; r++) {
        c0[r] = (c0[r] > 0.f) ? c0[r] : 0.01f * c0[r];
        c1[r] = (c1[r] > 0.f) ? c1[r] : 0.01f * c1[r];
        c2[r] = (c2[r] > 0.f) ? c2[r] : 0.01f * c2[r];
        c3[r] = (c3[r] > 0.f) ? c3[r] : 0.01f * c3[r];
        ss[r] = c0[r]*c0[r] + c1[r]*c1[r] + c2[r]*c2[r] + c3[r]*c3[r];
        #pragma unroll
        for (int mm = 1; mm < 16; mm <<= 1) ss[r] += __shfl_xor(ss[r], mm);
        ss[r] = 1.f / fmaxf(sqrtf(ss[r]), 1e-12f);
    }
    #pragma unroll
    for (int r = 0; r < 4; r++) {
        int node_r = nb0 + wv * 16 + g * 4 + r;
        if (node_r >= n_nodes) continue;
        size_t row = (size_t)node_r * 64;
        h1out[row +      q] = __float2bfloat16(c0[r] * ss[r]);
        h1out[row + 16 + q] = __float2bfloat16(c1[r] * ss[r]);
        h1out[row + 32 + q] = __float2bfloat16(c2[r] * ss[r]);
        h1out[row + 48 + q] = __float2bfloat16(c3[r] * ss[r]);
    }
}

// ---------- inline layer2 (64->32) for one node, aggregation pulled on the fly ----------
__device__ __forceinline__ float layer2_row(
    const __hip_bfloat16* __restrict__ h1,
    const int* __restrict__ row_ptr, const unsigned int* __restrict__ edges,
    const float* sW1, const float* sW2, const float* sb,
    int node, int lane)
{
    int es = row_ptr[node];
    int ee = row_ptr[node + 1];
    const float QS = 1.f / 16384.f;
    float g = 0.f;
    for (int base = es; base < ee; base += 64) {
        int cnt = min(64, ee - base);
        unsigned ev = (lane < cnt) ? edges[base + lane] : 0u;
        int j = 0;
        for (; j + 4 <= cnt; j += 4) {
            unsigned e0 = (unsigned)__shfl((int)ev, j);
            unsigned e1 = (unsigned)__shfl((int)ev, j + 1);
            unsigned e2 = (unsigned)__shfl((int)ev, j + 2);
            unsigned e3 = (unsigned)__shfl((int)ev, j + 3);
            float f0 = __bfloat162float(h1[(size_t)(e0 >> 14) * 64 + lane]);
            float f1 = __bfloat162float(h1[(size_t)(e1 >> 14) * 64 + lane]);
            float f2 = __bfloat162float(h1[(size_t)(e2 >> 14) * 64 + lane]);
            float f3 = __bfloat162float(h1[(size_t)(e3 >> 14) * 64 + lane]);
            g += (float)(e0 & 16383u) * QS * f0 + (float)(e1 & 16383u) * QS * f1
               + (float)(e2 & 16383u) * QS * f2 + (float)(e3 & 16383u) * QS * f3;
        }
        for (; j < cnt; j++) {
            unsigned e0 = (unsigned)__shfl((int)ev, j);
            float f0 = __bfloat162float(h1[(size_t)(e0 >> 14) * 64 + lane]);
            g += (float)(e0 & 16383u) * QS * f0;
        }
    }
    float f = __bfloat162float(h1[(size_t)node * 64 + lane]);
    float s = f + g;
    float p = f * g;
    int j = lane & 31;
    float acc = sb[j];
    #pragma unroll
    for (int k = 0; k < 64; k++) {
        float sk = __shfl(s, k);
        float pk = __shfl(p, k);
        acc += sk * sW1[k * 32 + j] + pk * sW2[k * 32 + j];
    }
    acc = (acc > 0.f) ? acc : 0.01f * acc;
    float sq = acc * acc;
    #pragma unroll
    for (int m = 1; m < 32; m <<= 1) sq += __shfl_xor(sq, m);
    return acc / fmaxf(sqrtf(sq), 1e-12f);
}

__global__ __launch_bounds__(256) void score_k(
    const float* __restrict__ uw, const float* __restrict__ ew,
    const __hip_bfloat16* __restrict__ h1,
    const int* __restrict__ row_ptr, const unsigned int* __restrict__ edges,
    const float* __restrict__ W1b, const float* __restrict__ b1b,
    const float* __restrict__ W2b, const float* __restrict__ b2b,
    const int* __restrict__ uid, const int* __restrict__ pid,
    const int* __restrict__ nid, float* __restrict__ out)
{
    __shared__ float sW1[64 * 32];
    __shared__ float sW2[64 * 32];
    __shared__ float sb[32];
    for (int i = threadIdx.x; i < 64 * 32; i += 256) { sW1[i] = W1b[i]; sW2[i] = W2b[i]; }
    if (threadIdx.x < 32) sb[threadIdx.x] = b1b[threadIdx.x] + b2b[threadIdx.x];
    __syncthreads();

    int wave = threadIdx.x >> 6;
    int lane = threadIdx.x & 63;
    int i = blockIdx.x * 4 + wave;
    if (i >= BATCH_C) return;

    int un = uid[i];
    int pe = pid[i];
    int ne = nid[i];
    int pn = N_USERS + pe;
    int nn = N_USERS + ne;

    float acc01p, acc01n;
    {
        float u  = uw[(size_t)un * 64 + lane];
        float pv = ew[(size_t)pe * 64 + lane];
        float nv = ew[(size_t)ne * 64 + lane];
        acc01p = u * pv;
        acc01n = u * nv;
        float u1 = __bfloat162float(h1[(size_t)un * 64 + lane]);
        acc01p += u1 * __bfloat162float(h1[(size_t)pn * 64 + lane]);
        acc01n += u1 * __bfloat162float(h1[(size_t)nn * 64 + lane]);
    }

    float h2u = layer2_row(h1, row_ptr, edges, sW1, sW2, sb, un, lane);
    float h2p = layer2_row(h1, row_ptr, edges, sW1, sW2, sb, pn, lane);
    float h2n = layer2_row(h1, row_ptr, edges, sW1, sW2, sb, nn, lane);
    float p2 = h2u * h2p;
    float n2 = h2u * h2n;
    #pragma unroll
    for (int m = 1; m < 32; m <<= 1) { p2 += __shfl_xor(p2, m); n2 += __shfl_xor(n2, m); }

    #pragma unroll
    for (int m = 1; m < 64; m <<= 1) { acc01p += __shfl_xor(acc01p, m); acc01n += __shfl_xor(acc01n, m); }

    if (lane == 0) {
        out[i]           = acc01p + p2;
        out[BATCH_C + i] = acc01n + n2;
    }
}

extern "C" void kernel_launch(void* const* d_in, const int* in_sizes, int n_in,
                              void* d_out, int out_size, void* d_ws, size_t ws_size,
                              hipStream_t stream) {
    const float* uw   = (const float*)d_in[0];
    const float* ew   = (const float*)d_in[1];
    const float* W1a  = (const float*)d_in[2];
    const float* b1a  = (const float*)d_in[3];
    const float* W2a  = (const float*)d_in[4];
    const float* b2a  = (const float*)d_in[5];
    const float* W1b  = (const float*)d_in[6];
    const float* b1b  = (const float*)d_in[7];
    const float* W2b  = (const float*)d_in[8];
    const float* b2b  = (const float*)d_in[9];
    const float* values   = (const float*)d_in[10];
    const int*   target   = (const int*)d_in[11];
    const int*   neighbor = (const int*)d_in[12];
    const int*   uid  = (const int*)d_in[13];
    const int*   pid  = (const int*)d_in[14];
    const int*   nid  = (const int*)d_in[15];

    const int n_edges = in_sizes[10];

    char* ws = (char*)d_ws;
    int*  counts     = (int*)ws;   ws += 801792;
    int*  row_ptr    = (int*)ws;   ws += 801792;
    int*  block_sums = (int*)ws;   ws += 4096;
    int*  block_offs = (int*)ws;   ws += 4096;
    int*  cntarr     = (int*)ws;   ws += 704512;          // 448*391*4 = 700672
    int*  offarr     = (int*)ws;   ws += 704512;
    unsigned int*   edges = (unsigned int*)ws;   ws += (size_t)N_EDGES_C * 4;      // 12.8 MB
    unsigned short* fb    = (unsigned short*)ws; ws += (size_t)N_NODES_C * 64 * 2; // 25.6 MB
    uint2*          tmp   = (uint2*)ws;                   // aliased with h1
    __hip_bfloat16* h1    = (__hip_bfloat16*)ws;          // region 25.69 MB

    const int edge_blocks  = (n_edges + 255) / 256;
    const int layer_blocks = (N_NODES_C + 127) / 128;     // 1563
    const int conv_blocks  = (N_NODES_C * 64 + 255) / 256;
    const int nchunks      = (n_edges + CHUNK - 1) / CHUNK;   // 447

    // ----- bf16 feature table + row_ptr -----
    hipMemsetAsync(counts, 0, (size_t)N_NODES_C * sizeof(int), stream);
    tobf16_k<<<conv_blocks, 256, 0, stream>>>(uw, ew, fb);
    hist_k<<<edge_blocks, 256, 0, stream>>>(target, counts, n_edges);
    partial_k<<<SCAN_BLK, 256, 0, stream>>>(counts, block_sums);
    scansums_k<<<1, 1024, 0, stream>>>(block_sums, block_offs);
    finalize_k<<<SCAN_BLK, 256, 0, stream>>>(counts, block_offs, row_ptr, n_edges);

    // ----- two-stage edge sort -----
    sort1_k<<<nchunks, 256, 0, stream>>>(target, neighbor, values, tmp, cntarr, offarr, n_edges);
    sort2_k<<<NSG, 256, 0, stream>>>(tmp, cntarr, offarr, row_ptr, edges, nchunks);

    // ----- layer 1 (dual-node pull + MFMA transform) -----
    layer1_pull_k<<<layer_blocks, 512, 0, stream>>>(fb, row_ptr, edges,
                                                    W1a, b1a, W2a, b2a, h1, N_NODES_C);

    // ----- scoring (layer-2 aggregation + transform inline, ~12K nodes) -----
    score_k<<<BATCH_C / 4, 256, 0, stream>>>(uw, ew, h1, row_ptr, edges,
                                             W1b, b1b, W2b, b2b,
                                             uid, pid, nid, (float*)d_out);
}

// Round 12
// 494.445 us; speedup vs baseline: 3.9470x; 1.0398x over previous
//
#include <hip/hip_runtime.h>
#include <hip/hip_bf16.h>

#define N_USERS    50000
#define N_ENTITIES 150000
#define N_NODES_C  200000
#define BATCH_C    4096
#define N_EDGES_C  3200000

// two-stage edge sort params
#define CHUNK   7168            // edges per sort1 block (LDS 57.3 KB buf)
#define SG_SH   9               // supergroup = 512 nodes
#define NSG     391             // ceil(200000/512)
#define MAXCHK  448             // max chunks (3.2M/7168 = 447)
#define S2CAP   12288           // sort2 LDS edge capacity (expected ~8192/sg)

typedef __attribute__((ext_vector_type(8))) short short8;
typedef __attribute__((ext_vector_type(4))) float float4v;

// Workspace (~67 MB; proven safe < 76.8 MB):
//   row_ptr : int [200001+pad]      0.80 MB   (written by sort2, coalesced)
//   cntarr  : int [448*391]         0.70 MB   (chunk-major per-sg counts)
//   offarr  : int [448*391]         0.70 MB
//   sgoff   : int [512]             2 KB      (supergroup global starts)
//   edges   : uint [3.2M]          12.8 MB    (nb<<14 | val_q14, node-sorted CSR)
//   fb16    : ushort[200000*64]    25.6 MB    (bf16 node features)
//   region  : 25.69 MB — tmp (uint2 sorted runs) then h1 (bf16 layer-1 out)
// NOTE: no global histogram / memset at all — sort1 counts per-chunk, sgscan
// prefixes supergroups, sort2 builds node-level row_ptr in LDS.

__device__ __forceinline__ unsigned short f32_to_bf16_bits(float x) {
    unsigned u = __float_as_uint(x);
    unsigned r = (u + 0x7fffu + ((u >> 16) & 1u)) >> 16;   // RNE
    return (unsigned short)r;
}

// ---------- bf16 node-feature table ----------
__global__ __launch_bounds__(256) void tobf16_k(const float* __restrict__ uw,
                                                const float* __restrict__ ew,
                                                unsigned short* __restrict__ fb)
{
    int idx = blockIdx.x * 256 + threadIdx.x;
    if (idx >= N_NODES_C * 64) return;
    const int split = N_USERS * 64;
    float x = (idx < split) ? uw[idx] : ew[idx - split];
    fb[idx] = f32_to_bf16_bits(x);
}

// ---------- stage 1: chunk-local counting sort by supergroup ----------
__global__ __launch_bounds__(256) void sort1_k(
    const int* __restrict__ target, const int* __restrict__ neighbor,
    const float* __restrict__ values,
    uint2* __restrict__ tmp, int* __restrict__ cntarr, int* __restrict__ offarr,
    int n_edges)
{
    __shared__ uint2 buf[CHUNK];            // 57.3 KB
    __shared__ int cnt[NSG], off[NSG], pos[NSG];
    int c = blockIdx.x;
    int base = c * CHUNK;
    int ccount = min(CHUNK, n_edges - base);
    for (int i = threadIdx.x; i < NSG; i += 256) { cnt[i] = 0; pos[i] = 0; }
    __syncthreads();
    for (int i = threadIdx.x; i < ccount; i += 256)
        atomicAdd(&cnt[target[base + i] >> SG_SH], 1);
    __syncthreads();
    if (threadIdx.x < 64) {                 // wave-0 exclusive scan of cnt
        int l = threadIdx.x;
        const int PER = (NSG + 63) / 64;    // 7
        int s0 = l * PER, s1 = min(s0 + PER, NSG);
        int sum = 0;
        for (int i = s0; i < s1; i++) sum += cnt[i];
        int run = sum;
        #pragma unroll
        for (int o = 1; o < 64; o <<= 1) { int v = __shfl_up(run, o); if (l >= o) run += v; }
        int excl = run - sum;
        for (int i = s0; i < s1; i++) { off[i] = excl; excl += cnt[i]; }
    }
    __syncthreads();
    for (int i = threadIdx.x; i < ccount; i += 256) {
        int t  = target[base + i];
        int sg = t >> SG_SH;
        unsigned q = (unsigned)fminf(values[base + i] * 16384.f + 0.5f, 16383.f);
        unsigned w = ((unsigned)neighbor[base + i] << 14) | q;
        int p = off[sg] + atomicAdd(&pos[sg], 1);
        buf[p] = make_uint2(w, (unsigned)t);
    }
    __syncthreads();
    for (int i = threadIdx.x; i < ccount; i += 256)
        tmp[(size_t)c * CHUNK + i] = buf[i];
    for (int i = threadIdx.x; i < NSG; i += 256) {
        cntarr[c * NSG + i] = cnt[i];
        offarr[c * NSG + i] = off[i];
    }
}

// ---------- supergroup prefix: sgoff[s] = global CSR start of supergroup s ----------
// One block. Column sums of cntarr are coalesced (consecutive t = consecutive addr).
__global__ __launch_bounds__(512) void sgscan_k(const int* __restrict__ cntarr,
                                                int* __restrict__ sgoff, int nchunks)
{
    __shared__ int part[512];
    int t = threadIdx.x;
    int sum = 0;
    if (t < NSG)
        for (int c = 0; c < nchunks; c++) sum += cntarr[c * NSG + t];
    part[t] = sum;
    __syncthreads();
    for (int off = 1; off < 512; off <<= 1) {
        int w = (t >= off) ? part[t - off] : 0;
        __syncthreads();
        part[t] += w;
        __syncthreads();
    }
    if (t < NSG) sgoff[t] = part[t] - sum;          // exclusive
    if (t == NSG - 1) sgoff[NSG] = part[t];          // total = n_edges
}

// ---------- stage 2: per-supergroup node-exact placement + row_ptr build ----------
// Pass 1: buffer supergroup edges in LDS while counting per-node; scan -> rp;
// write row_ptr coalesced. Pass 2: place edges into the block-private global
// segment. No global histogram needed anywhere.
__global__ __launch_bounds__(256) void sort2_k(
    const uint2* __restrict__ tmp, const int* __restrict__ cntarr,
    const int* __restrict__ offarr, const int* __restrict__ sgoff,
    int* __restrict__ row_ptr, unsigned* __restrict__ edges, int nchunks)
{
    __shared__ unsigned ebuf[S2CAP];        // 49.2 KB
    __shared__ unsigned short tbuf[S2CAP];  // 24.6 KB
    __shared__ int cnt[512];
    __shared__ int cur[512];
    __shared__ int rp[513];
    __shared__ int pre[MAXCHK + 1];
    __shared__ int soff[MAXCHK];
    int s = blockIdx.x;
    int node0 = s << SG_SH;
    int nn = min(512, N_NODES_C - node0);
    int sgstart = sgoff[s];
    for (int i = threadIdx.x; i < 512; i += 256) { cnt[i] = 0; cur[i] = 0; }
    for (int c = threadIdx.x; c < nchunks; c += 256) {
        pre[c]  = cntarr[c * NSG + s];
        soff[c] = offarr[c * NSG + s];
    }
    __syncthreads();
    if (threadIdx.x < 64) {                 // wave-0 exclusive scan of pre
        int l = threadIdx.x;
        int PER = (nchunks + 63) >> 6;      // 7
        int s0 = l * PER, s1 = min(s0 + PER, nchunks);
        int vals[8];
        int sum = 0;
        for (int i = s0; i < s1; i++) { vals[i - s0] = pre[i]; sum += vals[i - s0]; }
        int run = sum;
        #pragma unroll
        for (int o = 1; o < 64; o <<= 1) { int v = __shfl_up(run, o); if (l >= o) run += v; }
        int excl = run - sum;
        for (int i = s0; i < s1; i++) { int t = vals[i - s0]; pre[i] = excl; excl += t; }
        if (l == 63) pre[nchunks] = excl;
    }
    __syncthreads();
    int sgcnt = pre[nchunks];
    // pass 1: gather edges to LDS + count per node
    for (int e = threadIdx.x; e < sgcnt; e += 256) {
        int lo = 0, hi = nchunks;
        while (hi - lo > 1) {
            int mid = (lo + hi) >> 1;
            if (pre[mid] <= e) lo = mid; else hi = mid;
        }
        uint2 ed = tmp[(size_t)lo * CHUNK + soff[lo] + (e - pre[lo])];
        int tl = (int)ed.y - node0;
        atomicAdd(&cnt[tl], 1);
        if (e < S2CAP) { ebuf[e] = ed.x; tbuf[e] = (unsigned short)tl; }
    }
    __syncthreads();
    if (threadIdx.x < 64) {                 // wave-0 exclusive scan of cnt[512]
        int l = threadIdx.x;
        int s0 = l * 8, s1 = s0 + 8;
        int vals[8];
        int sum = 0;
        for (int i = s0; i < s1; i++) { vals[i - s0] = cnt[i]; sum += vals[i - s0]; }
        int run = sum;
        #pragma unroll
        for (int o = 1; o < 64; o <<= 1) { int v = __shfl_up(run, o); if (l >= o) run += v; }
        int excl = run - sum;
        for (int i = s0; i < s1; i++) { rp[i] = excl; excl += vals[i - s0]; }
        if (l == 63) rp[512] = excl;
    }
    __syncthreads();
    // write row_ptr (coalesced, block-private)
    for (int i = threadIdx.x; i < nn; i += 256) row_ptr[node0 + i] = sgstart + rp[i];
    if (s == NSG - 1 && threadIdx.x == 0) row_ptr[N_NODES_C] = sgstart + sgcnt;
    // pass 2: place edges into block-private global segment
    int lim = min(sgcnt, S2CAP);
    for (int e = threadIdx.x; e < lim; e += 256) {
        int tl  = tbuf[e];
        int old = atomicAdd(&cur[tl], 1);
        edges[sgstart + rp[tl] + old] = ebuf[e];
    }
    // rare overflow path: re-read tmp for e >= S2CAP
    for (int e = S2CAP + threadIdx.x; e < sgcnt; e += 256) {
        int lo = 0, hi = nchunks;
        while (hi - lo > 1) {
            int mid = (lo + hi) >> 1;
            if (pre[mid] <= e) lo = mid; else hi = mid;
        }
        uint2 ed = tmp[(size_t)lo * CHUNK + soff[lo] + (e - pre[lo])];
        int tl  = (int)ed.y - node0;
        int old = atomicAdd(&cur[tl], 1);
        edges[sgstart + rp[tl] + old] = ed.x;
    }
}

// ---------- layer 1: dual-node quad-gather pull + MFMA dense transform ----------
#define SPS 136
__global__ __launch_bounds__(512, 6) void layer1_pull_k(
    const unsigned short* __restrict__ fb,
    const int* __restrict__ row_ptr, const unsigned int* __restrict__ edges,
    const float* __restrict__ W1, const float* __restrict__ b1,
    const float* __restrict__ W2, const float* __restrict__ b2,
    __hip_bfloat16* __restrict__ h1out, int n_nodes)
{
    __shared__ __align__(16) short wt[64 * SPS];    // 17.4 KB
    __shared__ __align__(16) short sp[128 * SPS];   // 34.8 KB
    __shared__ float sbias[64];

    for (int idx = threadIdx.x; idx < 64 * 64; idx += 512) {
        int kp = idx >> 6;
        int n  = idx & 63;
        int k0 = kp * 2, k1 = k0 + 1;
        float w0 = (k0 < 64) ? W1[k0 * 64 + n] : W2[(k0 - 64) * 64 + n];
        float w1 = (k1 < 64) ? W1[k1 * 64 + n] : W2[(k1 - 64) * 64 + n];
        *(unsigned*)&wt[n * SPS + k0] =
            ((unsigned)f32_to_bf16_bits(w1) << 16) | f32_to_bf16_bits(w0);
    }
    if (threadIdx.x < 64) sbias[threadIdx.x] = b1[threadIdx.x] + b2[threadIdx.x];
    __syncthreads();

    int wv   = threadIdx.x >> 6;
    int lane = threadIdx.x & 63;
    int g    = lane >> 4;
    int q    = lane & 15;
    const uint2* fb2 = (const uint2*)fb;

    int nb0 = blockIdx.x * 128;
    const float QS = 1.f / 16384.f;

    for (int i = 0; i < 16; i += 2) {
        int mA = wv * 16 + i;
        int nodeA = nb0 + mA;
        int nodeB = nodeA + 1;
        int esA = 0, eeA = 0, esB = 0, eeB = 0;
        if (nodeA < n_nodes) { esA = row_ptr[nodeA]; eeA = row_ptr[nodeA + 1]; }
        if (nodeB < n_nodes) { esB = row_ptr[nodeB]; eeB = row_ptr[nodeB + 1]; }

        float a0 = 0.f, a1 = 0.f, a2 = 0.f, a3 = 0.f;
        float b0v = 0.f, b1v = 0.f, b2v = 0.f, b3v = 0.f;
        int baseA = esA, baseB = esB;
        while (baseA < eeA || baseB < eeB) {
            int cntA = eeA - baseA;  if (cntA > 64) cntA = 64;
            int cntB = eeB - baseB;  if (cntB > 64) cntB = 64;
            unsigned evA = (lane < cntA) ? edges[baseA + lane] : 0u;
            unsigned evB = (lane < cntB) ? edges[baseB + lane] : 0u;
            int jmA = (cntA > 0) ? ((cntA + 3) >> 2) : 0;
            int jmB = (cntB > 0) ? ((cntB + 3) >> 2) : 0;
            int jm = max(jmA, jmB);
            #pragma unroll 4
            for (int j = 0; j < jm; j++) {
                unsigned wA = (j < jmA) ? (unsigned)__shfl((int)evA, j * 4 + g) : 0u;
                unsigned wB = (j < jmB) ? (unsigned)__shfl((int)evB, j * 4 + g) : 0u;
                uint2 dA = fb2[(size_t)(wA >> 14) * 16 + q];   // wA=0 -> row0, v=0
                uint2 dB = fb2[(size_t)(wB >> 14) * 16 + q];
                float vA = (float)(wA & 16383u) * QS;
                float vB = (float)(wB & 16383u) * QS;
                a0  += vA * __uint_as_float(dA.x << 16);
                a1  += vA * __uint_as_float(dA.x & 0xffff0000u);
                a2  += vA * __uint_as_float(dA.y << 16);
                a3  += vA * __uint_as_float(dA.y & 0xffff0000u);
                b0v += vB * __uint_as_float(dB.x << 16);
                b1v += vB * __uint_as_float(dB.x & 0xffff0000u);
                b2v += vB * __uint_as_float(dB.y << 16);
                b3v += vB * __uint_as_float(dB.y & 0xffff0000u);
            }
            baseA += 64; baseB += 64;
        }
        #pragma unroll
        for (int mm = 16; mm < 64; mm <<= 1) {
            a0  += __shfl_xor(a0, mm);  a1  += __shfl_xor(a1, mm);
            a2  += __shfl_xor(a2, mm);  a3  += __shfl_xor(a3, mm);
            b0v += __shfl_xor(b0v, mm); b1v += __shfl_xor(b1v, mm);
            b2v += __shfl_xor(b2v, mm); b3v += __shfl_xor(b3v, mm);
        }

        uint2 dsA = make_uint2(0u, 0u), dsB = make_uint2(0u, 0u);
        if (nodeA < n_nodes) dsA = fb2[(size_t)nodeA * 16 + q];
        if (nodeB < n_nodes) dsB = fb2[(size_t)nodeB * 16 + q];

        if (g < 2) {
            float fA0 = __uint_as_float(dsA.x << 16);
            float fA1 = __uint_as_float(dsA.x & 0xffff0000u);
            float fA2 = __uint_as_float(dsA.y << 16);
            float fA3 = __uint_as_float(dsA.y & 0xffff0000u);
            float x0 = (g == 0) ? fA0 + a0 : fA0 * a0;
            float x1 = (g == 0) ? fA1 + a1 : fA1 * a1;
            float x2 = (g == 0) ? fA2 + a2 : fA2 * a2;
            float x3 = (g == 0) ? fA3 + a3 : fA3 * a3;
            uint2 pk;
            pk.x = ((unsigned)f32_to_bf16_bits(x1) << 16) | f32_to_bf16_bits(x0);
            pk.y = ((unsigned)f32_to_bf16_bits(x3) << 16) | f32_to_bf16_bits(x2);
            *(uint2*)&sp[mA * SPS + g * 64 + q * 4] = pk;

            float fB0 = __uint_as_float(dsB.x << 16);
            float fB1 = __uint_as_float(dsB.x & 0xffff0000u);
            float fB2 = __uint_as_float(dsB.y << 16);
            float fB3 = __uint_as_float(dsB.y & 0xffff0000u);
            float y0 = (g == 0) ? fB0 + b0v : fB0 * b0v;
            float y1 = (g == 0) ? fB1 + b1v : fB1 * b1v;
            float y2 = (g == 0) ? fB2 + b2v : fB2 * b2v;
            float y3 = (g == 0) ? fB3 + b3v : fB3 * b3v;
            pk.x = ((unsigned)f32_to_bf16_bits(y1) << 16) | f32_to_bf16_bits(y0);
            pk.y = ((unsigned)f32_to_bf16_bits(y3) << 16) | f32_to_bf16_bits(y2);
            *(uint2*)&sp[(mA + 1) * SPS + g * 64 + q * 4] = pk;
        }
    }
    __syncthreads();

    float4v c0, c1, c2, c3;
    {
        float bv0 = sbias[q];
        float bv1 = sbias[16 + q];
        float bv2 = sbias[32 + q];
        float bv3 = sbias[48 + q];
        c0 = (float4v){bv0, bv0, bv0, bv0};
        c1 = (float4v){bv1, bv1, bv1, bv1};
        c2 = (float4v){bv2, bv2, bv2, bv2};
        c3 = (float4v){bv3, bv3, bv3, bv3};
    }
    #pragma unroll
    for (int kk = 0; kk < 4; kk++) {
        int ko = kk * 32 + g * 8;
        short8 a = *(const short8*)&sp[(wv * 16 + q) * SPS + ko];
        short8 bb0 = *(const short8*)&wt[(q)      * SPS + ko];
        short8 bb1 = *(const short8*)&wt[(16 + q) * SPS + ko];
        short8 bb2 = *(const short8*)&wt[(32 + q) * SPS + ko];
        short8 bb3 = *(const short8*)&wt[(48 + q) * SPS + ko];
        c0 = __builtin_amdgcn_mfma_f32_16x16x32_bf16(a, bb0, c0, 0, 0, 0);
        c1 = __builtin_amdgcn_mfma_f32_16x16x32_bf16(a, bb1, c1, 0, 0, 0);
        c2 = __builtin_amdgcn_mfma_f32_16x16x32_bf16(a, bb2, c2, 0, 0, 0);
        c3 = __builtin_amdgcn_mfma_f32_16x16x32_bf16(a, bb3, c3, 0, 0, 0);
    }

    float ss[4];
    #pragma unroll
    for (int r = 0; r < 4; r++) {
        c0[r] = (c0[r] > 0.f) ? c0[r] : 0.01f * c0[r];
        c1[r] = (c1[r] > 0.f) ? c1[r] : 0.01f * c1[r];
        c2[r] = (c2[r] > 0.f) ? c2[r] : 0.01f * c2[r];
        c3[r] = (c3[r] > 0.f) ? c3[r] : 0.01f * c3[r];
        ss[r] = c0[r]*c0[r] + c1[r]*c1[r] + c2[r]*c2[r] + c3[r]*c3[r];
        #pragma unroll
        for (int mm = 1; mm < 16; mm <<= 1) ss[r] += __shfl_xor(ss[r], mm);
        ss[r] = 1.f / fmaxf(sqrtf(ss[r]), 1e-12f);
    }
    #pragma unroll
    for (int r = 0; r < 4; r++) {
        int node_r = nb0 + wv * 16 + g * 4 + r;
        if (node_r >= n_nodes) continue;
        size_t row = (size_t)node_r * 64;
        h1out[row +      q] = __float2bfloat16(c0[r] * ss[r]);
        h1out[row + 16 + q] = __float2bfloat16(c1[r] * ss[r]);
        h1out[row + 32 + q] = __float2bfloat16(c2[r] * ss[r]);
        h1out[row + 48 + q] = __float2bfloat16(c3[r] * ss[r]);
    }
}

// ---------- inline layer2 (64->32) for one node, aggregation pulled on the fly ----------
__device__ __forceinline__ float layer2_row(
    const __hip_bfloat16* __restrict__ h1,
    const int* __restrict__ row_ptr, const unsigned int* __restrict__ edges,
    const float* sW1, const float* sW2, const float* sb,
    int node, int lane)
{
    int es = row_ptr[node];
    int ee = row_ptr[node + 1];
    const float QS = 1.f / 16384.f;
    float g = 0.f;
    for (int base = es; base < ee; base += 64) {
        int cnt = min(64, ee - base);
        unsigned ev = (lane < cnt) ? edges[base + lane] : 0u;
        int j = 0;
        for (; j + 4 <= cnt; j += 4) {
            unsigned e0 = (unsigned)__shfl((int)ev, j);
            unsigned e1 = (unsigned)__shfl((int)ev, j + 1);
            unsigned e2 = (unsigned)__shfl((int)ev, j + 2);
            unsigned e3 = (unsigned)__shfl((int)ev, j + 3);
            float f0 = __bfloat162float(h1[(size_t)(e0 >> 14) * 64 + lane]);
            float f1 = __bfloat162float(h1[(size_t)(e1 >> 14) * 64 + lane]);
            float f2 = __bfloat162float(h1[(size_t)(e2 >> 14) * 64 + lane]);
            float f3 = __bfloat162float(h1[(size_t)(e3 >> 14) * 64 + lane]);
            g += (float)(e0 & 16383u) * QS * f0 + (float)(e1 & 16383u) * QS * f1
               + (float)(e2 & 16383u) * QS * f2 + (float)(e3 & 16383u) * QS * f3;
        }
        for (; j < cnt; j++) {
            unsigned e0 = (unsigned)__shfl((int)ev, j);
            float f0 = __bfloat162float(h1[(size_t)(e0 >> 14) * 64 + lane]);
            g += (float)(e0 & 16383u) * QS * f0;
        }
    }
    float f = __bfloat162float(h1[(size_t)node * 64 + lane]);
    float s = f + g;
    float p = f * g;
    int j = lane & 31;
    float acc = sb[j];
    #pragma unroll
    for (int k = 0; k < 64; k++) {
        float sk = __shfl(s, k);
        float pk = __shfl(p, k);
        acc += sk * sW1[k * 32 + j] + pk * sW2[k * 32 + j];
    }
    acc = (acc > 0.f) ? acc : 0.01f * acc;
    float sq = acc * acc;
    #pragma unroll
    for (int m = 1; m < 32; m <<= 1) sq += __shfl_xor(sq, m);
    return acc / fmaxf(sqrtf(sq), 1e-12f);
}

__global__ __launch_bounds__(256) void score_k(
    const float* __restrict__ uw, const float* __restrict__ ew,
    const __hip_bfloat16* __restrict__ h1,
    const int* __restrict__ row_ptr, const unsigned int* __restrict__ edges,
    const float* __restrict__ W1b, const float* __restrict__ b1b,
    const float* __restrict__ W2b, const float* __restrict__ b2b,
    const int* __restrict__ uid, const int* __restrict__ pid,
    const int* __restrict__ nid, float* __restrict__ out)
{
    __shared__ float sW1[64 * 32];
    __shared__ float sW2[64 * 32];
    __shared__ float sb[32];
    for (int i = threadIdx.x; i < 64 * 32; i += 256) { sW1[i] = W1b[i]; sW2[i] = W2b[i]; }
    if (threadIdx.x < 32) sb[threadIdx.x] = b1b[threadIdx.x] + b2b[threadIdx.x];
    __syncthreads();

    int wave = threadIdx.x >> 6;
    int lane = threadIdx.x & 63;
    int i = blockIdx.x * 4 + wave;
    if (i >= BATCH_C) return;

    int un = uid[i];
    int pe = pid[i];
    int ne = nid[i];
    int pn = N_USERS + pe;
    int nn = N_USERS + ne;

    float acc01p, acc01n;
    {
        float u  = uw[(size_t)un * 64 + lane];
        float pv = ew[(size_t)pe * 64 + lane];
        float nv = ew[(size_t)ne * 64 + lane];
        acc01p = u * pv;
        acc01n = u * nv;
        float u1 = __bfloat162float(h1[(size_t)un * 64 + lane]);
        acc01p += u1 * __bfloat162float(h1[(size_t)pn * 64 + lane]);
        acc01n += u1 * __bfloat162float(h1[(size_t)nn * 64 + lane]);
    }

    float h2u = layer2_row(h1, row_ptr, edges, sW1, sW2, sb, un, lane);
    float h2p = layer2_row(h1, row_ptr, edges, sW1, sW2, sb, pn, lane);
    float h2n = layer2_row(h1, row_ptr, edges, sW1, sW2, sb, nn, lane);
    float p2 = h2u * h2p;
    float n2 = h2u * h2n;
    #pragma unroll
    for (int m = 1; m < 32; m <<= 1) { p2 += __shfl_xor(p2, m); n2 += __shfl_xor(n2, m); }

    #pragma unroll
    for (int m = 1; m < 64; m <<= 1) { acc01p += __shfl_xor(acc01p, m); acc01n += __shfl_xor(acc01n, m); }

    if (lane == 0) {
        out[i]           = acc01p + p2;
        out[BATCH_C + i] = acc01n + n2;
    }
}

extern "C" void kernel_launch(void* const* d_in, const int* in_sizes, int n_in,
                              void* d_out, int out_size, void* d_ws, size_t ws_size,
                              hipStream_t stream) {
    const float* uw   = (const float*)d_in[0];
    const float* ew   = (const float*)d_in[1];
    const float* W1a  = (const float*)d_in[2];
    const float* b1a  = (const float*)d_in[3];
    const float* W2a  = (const float*)d_in[4];
    const float* b2a  = (const float*)d_in[5];
    const float* W1b  = (const float*)d_in[6];
    const float* b1b  = (const float*)d_in[7];
    const float* W2b  = (const float*)d_in[8];
    const float* b2b  = (const float*)d_in[9];
    const float* values   = (const float*)d_in[10];
    const int*   target   = (const int*)d_in[11];
    const int*   neighbor = (const int*)d_in[12];
    const int*   uid  = (const int*)d_in[13];
    const int*   pid  = (const int*)d_in[14];
    const int*   nid  = (const int*)d_in[15];

    const int n_edges = in_sizes[10];

    char* ws = (char*)d_ws;
    int*  row_ptr    = (int*)ws;   ws += 801792;
    int*  cntarr     = (int*)ws;   ws += 704512;          // 448*391*4 = 700672
    int*  offarr     = (int*)ws;   ws += 704512;
    int*  sgoff      = (int*)ws;   ws += 4096;
    unsigned int*   edges = (unsigned int*)ws;   ws += (size_t)N_EDGES_C * 4;      // 12.8 MB
    unsigned short* fb    = (unsigned short*)ws; ws += (size_t)N_NODES_C * 64 * 2; // 25.6 MB
    uint2*          tmp   = (uint2*)ws;                   // aliased with h1
    __hip_bfloat16* h1    = (__hip_bfloat16*)ws;          // region 25.69 MB

    const int layer_blocks = (N_NODES_C + 127) / 128;     // 1563
    const int conv_blocks  = (N_NODES_C * 64 + 255) / 256;
    const int nchunks      = (n_edges + CHUNK - 1) / CHUNK;   // 447

    // ----- bf16 feature table -----
    tobf16_k<<<conv_blocks, 256, 0, stream>>>(uw, ew, fb);

    // ----- edge sort + CSR build (no global histogram at all) -----
    sort1_k<<<nchunks, 256, 0, stream>>>(target, neighbor, values, tmp, cntarr, offarr, n_edges);
    sgscan_k<<<1, 512, 0, stream>>>(cntarr, sgoff, nchunks);
    sort2_k<<<NSG, 256, 0, stream>>>(tmp, cntarr, offarr, sgoff, row_ptr, edges, nchunks);

    // ----- layer 1 (dual-node pull + MFMA transform) -----
    layer1_pull_k<<<layer_blocks, 512, 0, stream>>>(fb, row_ptr, edges,
                                                    W1a, b1a, W2a, b2a, h1, N_NODES_C);

    // ----- scoring (layer-2 aggregation + transform inline, ~12K nodes) -----
    score_k<<<BATCH_C / 4, 256, 0, stream>>>(uw, ew, h1, row_ptr, edges,
                                             W1b, b1b, W2b, b2b,
                                             uid, pid, nid, (float*)d_out);
}